// Round 1
// baseline (5982.426 us; speedup 1.0000x reference)
//
#include <hip/hip_runtime.h>

#define DD 64

// ---- monotonic float<->uint encoding for atomicMax on floats ----
__device__ __forceinline__ unsigned int enc_f(float f) {
  unsigned int u = __float_as_uint(f);
  return (u & 0x80000000u) ? ~u : (u | 0x80000000u);
}
__device__ __forceinline__ float dec_f(unsigned int k) {
  unsigned int u = (k & 0x80000000u) ? (k ^ 0x80000000u) : ~k;
  return __uint_as_float(u);
}

// acc[64] += W[0:64, 0:64] * src[0:64]; W row-major with row stride ldw.
// W accesses are wave-uniform -> scalar loads; src is per-lane float4 loads.
__device__ __forceinline__ void gemv_seg(float* acc, const float* __restrict__ src,
                                         const float* __restrict__ W, const int ldw) {
  #pragma unroll 1
  for (int ic = 0; ic < DD; ic += 8) {
    const float4 a = *reinterpret_cast<const float4*>(src + ic);
    const float4 b = *reinterpret_cast<const float4*>(src + ic + 4);
    #pragma unroll
    for (int o = 0; o < DD; ++o) {
      const float* wr = W + o * ldw + ic;
      float t = acc[o];
      t = fmaf(a.x, wr[0], t); t = fmaf(a.y, wr[1], t);
      t = fmaf(a.z, wr[2], t); t = fmaf(a.w, wr[3], t);
      t = fmaf(b.x, wr[4], t); t = fmaf(b.y, wr[5], t);
      t = fmaf(b.z, wr[6], t);
      acc[o] = fmaf(b.w, wr[7], t);
    }
  }
}

// ---- K1a: edge_new = relu(W_edge * [ea; x[row]; x[col]; u[ebatch]] + b_edge) ----
__global__ void __launch_bounds__(256) k_edge(
    const float* __restrict__ x, const float* __restrict__ ea, const float* __restrict__ u,
    const float* __restrict__ We, const float* __restrict__ be,
    const int* __restrict__ row, const int* __restrict__ col, const int* __restrict__ ebat,
    float* __restrict__ edge_out, int E) {
  int e = blockIdx.x * 256 + threadIdx.x;
  if (e >= E) return;
  int r = row[e], c = col[e], g = ebat[e];
  float acc[DD];
  #pragma unroll
  for (int o = 0; o < DD; ++o) acc[o] = be[o];
  #pragma unroll 1
  for (int s = 0; s < 4; ++s) {
    const float* src = (s == 0) ? ea + (size_t)e * DD
                     : (s == 1) ? x + (size_t)r * DD
                     : (s == 2) ? x + (size_t)c * DD
                                : u + (size_t)g * DD;
    gemv_seg(acc, src, We + s * DD, 4 * DD);
  }
  float* dst = edge_out + (size_t)e * DD;
  #pragma unroll
  for (int o = 0; o < DD; o += 4) {
    float4 v;
    v.x = fmaxf(acc[o + 0], 0.f); v.y = fmaxf(acc[o + 1], 0.f);
    v.z = fmaxf(acc[o + 2], 0.f); v.w = fmaxf(acc[o + 3], 0.f);
    *reinterpret_cast<float4*>(dst + o) = v;
  }
}

// ---- K1b: attention logits w_sent/w_recv + segment max via atomicMax ----
__global__ void __launch_bounds__(256) k_attnw(
    const float* __restrict__ x, const float* __restrict__ edge_new,
    const float* __restrict__ W1, const float* __restrict__ b1, const float* __restrict__ w2,
    const int* __restrict__ row, const int* __restrict__ col,
    float* __restrict__ w_s, float* __restrict__ w_r,
    unsigned int* __restrict__ mk_s, unsigned int* __restrict__ mk_r, int E) {
  int e = blockIdx.x * 256 + threadIdx.x;
  if (e >= E) return;
  int r = row[e], c = col[e];
  const float* xr = x + (size_t)r * DD;
  const float* xc = x + (size_t)c * DD;
  const float* en = edge_new + (size_t)e * DD;
  #pragma unroll 1
  for (int dir = 0; dir < 2; ++dir) {
    float acc[DD];
    #pragma unroll
    for (int o = 0; o < DD; ++o) acc[o] = b1[o];
    const float* q  = dir ? xc : xr;
    const float* kv = dir ? xr : xc;
    gemv_seg(acc, q,  W1 + 0 * DD, 3 * DD);
    gemv_seg(acc, kv, W1 + 1 * DD, 3 * DD);
    gemv_seg(acc, en, W1 + 2 * DD, 3 * DD);
    float wsum = 0.f;
    #pragma unroll
    for (int o = 0; o < DD; ++o) {
      float h = acc[o];
      h = (h >= 0.f) ? h : 0.01f * h;   // leaky_relu slope 0.01
      wsum = fmaf(h, w2[o], wsum);
    }
    if (dir == 0) { w_s[e] = wsum; atomicMax(mk_s + r, enc_f(wsum)); }
    else          { w_r[e] = wsum; atomicMax(mk_r + c, enc_f(wsum)); }
  }
}

// ---- K2: sm = segment_sum(exp(w - m)) ----
__global__ void __launch_bounds__(256) k_expsum(
    const float* __restrict__ w_s, const float* __restrict__ w_r,
    const unsigned int* __restrict__ mk_s, const unsigned int* __restrict__ mk_r,
    const int* __restrict__ row, const int* __restrict__ col,
    float* __restrict__ sm_s, float* __restrict__ sm_r, int E) {
  int e = blockIdx.x * 256 + threadIdx.x;
  if (e >= E) return;
  int r = row[e], c = col[e];
  atomicAdd(sm_s + r, __expf(w_s[e] - dec_f(mk_s[r])));
  atomicAdd(sm_r + c, __expf(w_r[e] - dec_f(mk_r[c])));
}

// ---- K3: v = W3*[kv; en]+b3; scatter p*v into sent/recv ----
__global__ void __launch_bounds__(256) k_scatter(
    const float* __restrict__ x, const float* __restrict__ edge_new,
    const float* __restrict__ W3, const float* __restrict__ b3,
    const float* __restrict__ w_s, const float* __restrict__ w_r,
    const unsigned int* __restrict__ mk_s, const unsigned int* __restrict__ mk_r,
    const float* __restrict__ sm_s, const float* __restrict__ sm_r,
    const int* __restrict__ row, const int* __restrict__ col,
    float* __restrict__ sent, float* __restrict__ recv, int E) {
  int e = blockIdx.x * 256 + threadIdx.x;
  if (e >= E) return;
  int r = row[e], c = col[e];
  const float* xr = x + (size_t)r * DD;
  const float* xc = x + (size_t)c * DD;
  const float* en = edge_new + (size_t)e * DD;
  #pragma unroll 1
  for (int dir = 0; dir < 2; ++dir) {
    float p;
    int idx;
    if (dir == 0) { idx = r; p = __expf(w_s[e] - dec_f(mk_s[r])) / (sm_s[r] + 1e-16f); }
    else          { idx = c; p = __expf(w_r[e] - dec_f(mk_r[c])) / (sm_r[c] + 1e-16f); }
    const float* kv = dir ? xr : xc;
    float acc[DD];
    #pragma unroll
    for (int o = 0; o < DD; ++o) acc[o] = b3[o];
    gemv_seg(acc, kv, W3 + 0,  2 * DD);
    gemv_seg(acc, en, W3 + DD, 2 * DD);
    float* dst = (dir ? recv : sent) + (size_t)idx * DD;
    #pragma unroll
    for (int o = 0; o < DD; ++o) atomicAdd(dst + o, p * acc[o]);
  }
}

// ---- K4: x_new = relu(W_node * [x; sent; recv; u[nbatch]] + b_node) ----
__global__ void __launch_bounds__(256) k_node(
    const float* __restrict__ x, const float* __restrict__ sent, const float* __restrict__ recv,
    const float* __restrict__ u, const float* __restrict__ Wn, const float* __restrict__ bn,
    const int* __restrict__ nbat, float* __restrict__ x_out, int N) {
  int n = blockIdx.x * 256 + threadIdx.x;
  if (n >= N) return;
  int g = nbat[n];
  float acc[DD];
  #pragma unroll
  for (int o = 0; o < DD; ++o) acc[o] = bn[o];
  #pragma unroll 1
  for (int s = 0; s < 4; ++s) {
    const float* src = (s == 0) ? x    + (size_t)n * DD
                     : (s == 1) ? sent + (size_t)n * DD
                     : (s == 2) ? recv + (size_t)n * DD
                                : u    + (size_t)g * DD;
    gemv_seg(acc, src, Wn + s * DD, 4 * DD);
  }
  float* dst = x_out + (size_t)n * DD;
  #pragma unroll
  for (int o = 0; o < DD; o += 4) {
    float4 v;
    v.x = fmaxf(acc[o + 0], 0.f); v.y = fmaxf(acc[o + 1], 0.f);
    v.z = fmaxf(acc[o + 2], 0.f); v.w = fmaxf(acc[o + 3], 0.f);
    *reinterpret_cast<float4*>(dst + o) = v;
  }
}

// ---- K5: segment-sum over sorted segment ids (run-length + atomic flush) ----
__global__ void __launch_bounds__(256) k_segsum(
    const float* __restrict__ vals, const int* __restrict__ seg,
    float* __restrict__ out, int n) {
  int d = threadIdx.x & 63;
  int grp = threadIdx.x >> 6;
  long base = (long)blockIdx.x * 1024 + (long)grp * 256;
  float sum = 0.f;
  int cur = -1;
  for (int k = 0; k < 256; ++k) {
    long e = base + k;
    if (e >= n) break;
    int gb = seg[e];
    float v = vals[e * DD + d];
    if (gb != cur) {
      if (cur >= 0) atomicAdd(out + (size_t)cur * DD + d, sum);
      cur = gb; sum = v;
    } else {
      sum += v;
    }
  }
  if (cur >= 0) atomicAdd(out + (size_t)cur * DD + d, sum);
}

// ---- K6: u_new = relu(W_glob * [u; node_agg; edge_agg] + b_glob) ----
__global__ void __launch_bounds__(64) k_glob(
    const float* __restrict__ u, const float* __restrict__ nagg, const float* __restrict__ eagg,
    const float* __restrict__ Wg, const float* __restrict__ bg,
    float* __restrict__ u_out, int G) {
  int t = blockIdx.x * 64 + threadIdx.x;
  if (t >= G * 64) return;
  int g = t >> 6, o = t & 63;
  float acc = bg[o];
  const float* wr = Wg + (size_t)o * 192;
  for (int i = 0; i < 64; ++i) acc = fmaf(u[g * 64 + i],    wr[i],       acc);
  for (int i = 0; i < 64; ++i) acc = fmaf(nagg[g * 64 + i], wr[64 + i],  acc);
  for (int i = 0; i < 64; ++i) acc = fmaf(eagg[g * 64 + i], wr[128 + i], acc);
  u_out[t] = fmaxf(acc, 0.f);
}

extern "C" void kernel_launch(void* const* d_in, const int* in_sizes, int n_in,
                              void* d_out, int out_size, void* d_ws, size_t ws_size,
                              hipStream_t stream) {
  const float* x   = (const float*)d_in[0];
  const float* ea  = (const float*)d_in[1];
  const float* u   = (const float*)d_in[2];
  const float* We  = (const float*)d_in[3];
  const float* be  = (const float*)d_in[4];
  const float* Wn  = (const float*)d_in[5];
  const float* bn  = (const float*)d_in[6];
  const float* Wg  = (const float*)d_in[7];
  const float* bg  = (const float*)d_in[8];
  const float* W1  = (const float*)d_in[9];
  const float* b1  = (const float*)d_in[10];
  const float* w2  = (const float*)d_in[11];
  const float* W3  = (const float*)d_in[12];
  const float* b3  = (const float*)d_in[13];
  const int* eidx  = (const int*)d_in[14];
  const int* nbat  = (const int*)d_in[15];
  const int* ebat  = (const int*)d_in[16];

  const int N = in_sizes[0] / 64;
  const int E = in_sizes[1] / 64;
  const int G = in_sizes[2] / 64;
  const int* row = eidx;
  const int* col = eidx + E;

  float* out   = (float*)d_out;
  float* x_out = out;
  float* e_out = out + (size_t)N * 64;
  float* u_out = out + (size_t)(N + E) * 64;

  // workspace layout (floats)
  float* ws = (float*)d_ws;
  float* w_s = ws;
  float* w_r = ws + (size_t)E;
  unsigned int* mk_s = (unsigned int*)(ws + 2 * (size_t)E);
  unsigned int* mk_r = mk_s + N;
  float* sm_s = ws + 2 * (size_t)E + 2 * (size_t)N;
  float* sm_r = sm_s + N;
  float* sent = sm_r + N;
  float* recv = sent + (size_t)N * 64;
  float* nagg = recv + (size_t)N * 64;
  float* eagg = nagg + (size_t)G * 64;
  size_t ws_floats = 2 * (size_t)E + 4 * (size_t)N + 128 * (size_t)N + 128 * (size_t)G;

  hipMemsetAsync(d_ws, 0, ws_floats * sizeof(float), stream);

  const int gE = (E + 255) / 256;
  const int gN = (N + 255) / 256;

  k_edge<<<gE, 256, 0, stream>>>(x, ea, u, We, be, row, col, ebat, e_out, E);
  k_attnw<<<gE, 256, 0, stream>>>(x, e_out, W1, b1, w2, row, col, w_s, w_r, mk_s, mk_r, E);
  k_expsum<<<gE, 256, 0, stream>>>(w_s, w_r, mk_s, mk_r, row, col, sm_s, sm_r, E);
  k_scatter<<<gE, 256, 0, stream>>>(x, e_out, W3, b3, w_s, w_r, mk_s, mk_r, sm_s, sm_r,
                                    row, col, sent, recv, E);
  k_node<<<gN, 256, 0, stream>>>(x, sent, recv, u, Wn, bn, nbat, x_out, N);
  k_segsum<<<(E + 1023) / 1024, 256, 0, stream>>>(e_out, ebat, eagg, E);
  k_segsum<<<(N + 1023) / 1024, 256, 0, stream>>>(x_out, nbat, nagg, N);
  k_glob<<<(G * 64 + 63) / 64, 64, 0, stream>>>(u, nagg, eagg, Wg, bg, u_out, G);
}

// Round 2
// 1996.939 us; speedup vs baseline: 2.9958x; 2.9958x over previous
//
#include <hip/hip_runtime.h>

#define DD 64

__device__ __forceinline__ float4 ld4(const float* p) {
  return *reinterpret_cast<const float4*>(p);
}

// acc[64] += W[o*ldw + 0..63] . src[0..63]; W wave-uniform (scalar loads),
// src per-lane global pointer (float4 loads). acc statically indexed.
__device__ __forceinline__ void gemv_seg(float* acc, const float* __restrict__ src,
                                         const float* __restrict__ W, const int ldw) {
  #pragma unroll 1
  for (int ic = 0; ic < DD; ic += 8) {
    const float4 a = ld4(src + ic);
    const float4 b = ld4(src + ic + 4);
    #pragma unroll
    for (int o = 0; o < DD; ++o) {
      const float* wr = W + o * ldw + ic;
      float t = acc[o];
      t = fmaf(a.x, wr[0], t); t = fmaf(a.y, wr[1], t);
      t = fmaf(a.z, wr[2], t); t = fmaf(a.w, wr[3], t);
      t = fmaf(b.x, wr[4], t); t = fmaf(b.y, wr[5], t);
      t = fmaf(b.z, wr[6], t);
      acc[o] = fmaf(b.w, wr[7], t);
    }
  }
}

// acc[64] += W[64x128] . s[0..127] where s lives in REGISTERS (full static unroll).
__device__ __forceinline__ void gemv_reg128(float* acc, const float* s,
                                            const float* __restrict__ W) {
  #pragma unroll
  for (int ic = 0; ic < 128; ic += 8) {
    #pragma unroll
    for (int o = 0; o < DD; ++o) {
      const float* wr = W + o * 128 + ic;
      float t = acc[o];
      t = fmaf(s[ic + 0], wr[0], t); t = fmaf(s[ic + 1], wr[1], t);
      t = fmaf(s[ic + 2], wr[2], t); t = fmaf(s[ic + 3], wr[3], t);
      t = fmaf(s[ic + 4], wr[4], t); t = fmaf(s[ic + 5], wr[5], t);
      t = fmaf(s[ic + 6], wr[6], t);
      acc[o] = fmaf(s[ic + 7], wr[7], t);
    }
  }
}

// ---- build padded CSR (both directions), MAXDEG=64 ----
__global__ void __launch_bounds__(256) k_fill(
    const int* __restrict__ row, const int* __restrict__ col,
    int* __restrict__ deg_s, int* __restrict__ deg_r,
    int* __restrict__ lst_s, int* __restrict__ lst_r, int E) {
  int e = blockIdx.x * 256 + threadIdx.x;
  if (e >= E) return;
  int r = row[e], c = col[e];
  int s0 = atomicAdd(deg_s + r, 1);
  if (s0 < 64) lst_s[(size_t)r * 64 + s0] = e;
  int s1 = atomicAdd(deg_r + c, 1);
  if (s1 < 64) lst_r[(size_t)c * 64 + s1] = e;
}

// ---- per-node precompute: px1=Wx1.x, px2=Wx2.x, hq=W1q.x, hkv=W1kv.x; pu=Wu.u (g<G) ----
__global__ void __launch_bounds__(256) k_nodepre(
    const float* __restrict__ x, const float* __restrict__ u,
    const float* __restrict__ We, const float* __restrict__ W1,
    float* __restrict__ px1, float* __restrict__ px2,
    float* __restrict__ hq, float* __restrict__ hkv, float* __restrict__ pu,
    int N, int G) {
  int n = blockIdx.x * 256 + threadIdx.x;
  if (n >= N) return;
  const float* xr = x + (size_t)n * DD;
  float acc[DD];
  #pragma unroll
  for (int o = 0; o < DD; ++o) acc[o] = 0.f;
  gemv_seg(acc, xr, We + 64, 256);
  #pragma unroll
  for (int o = 0; o < DD; o += 4) *reinterpret_cast<float4*>(px1 + (size_t)n * DD + o) = make_float4(acc[o], acc[o+1], acc[o+2], acc[o+3]);
  #pragma unroll
  for (int o = 0; o < DD; ++o) acc[o] = 0.f;
  gemv_seg(acc, xr, We + 128, 256);
  #pragma unroll
  for (int o = 0; o < DD; o += 4) *reinterpret_cast<float4*>(px2 + (size_t)n * DD + o) = make_float4(acc[o], acc[o+1], acc[o+2], acc[o+3]);
  #pragma unroll
  for (int o = 0; o < DD; ++o) acc[o] = 0.f;
  gemv_seg(acc, xr, W1 + 0, 192);
  #pragma unroll
  for (int o = 0; o < DD; o += 4) *reinterpret_cast<float4*>(hq + (size_t)n * DD + o) = make_float4(acc[o], acc[o+1], acc[o+2], acc[o+3]);
  #pragma unroll
  for (int o = 0; o < DD; ++o) acc[o] = 0.f;
  gemv_seg(acc, xr, W1 + 64, 192);
  #pragma unroll
  for (int o = 0; o < DD; o += 4) *reinterpret_cast<float4*>(hkv + (size_t)n * DD + o) = make_float4(acc[o], acc[o+1], acc[o+2], acc[o+3]);
  if (n < G) {
    #pragma unroll
    for (int o = 0; o < DD; ++o) acc[o] = 0.f;
    gemv_seg(acc, u + (size_t)n * DD, We + 192, 256);
    #pragma unroll
    for (int o = 0; o < DD; o += 4) *reinterpret_cast<float4*>(pu + (size_t)n * DD + o) = make_float4(acc[o], acc[o+1], acc[o+2], acc[o+3]);
  }
}

// ---- edge MLP: edge_new = relu(Wea.ea + px1[row] + px2[col] + pu[g] + be) ----
__global__ void __launch_bounds__(256) k_edge2(
    const float* __restrict__ ea,
    const float* __restrict__ px1, const float* __restrict__ px2, const float* __restrict__ pu,
    const float* __restrict__ We, const float* __restrict__ be,
    const int* __restrict__ row, const int* __restrict__ col, const int* __restrict__ ebat,
    float* __restrict__ edge_out, int E) {
  int e = blockIdx.x * 256 + threadIdx.x;
  if (e >= E) return;
  int r = row[e], c = col[e], g = ebat[e];
  float acc[DD];
  #pragma unroll
  for (int o = 0; o < DD; ++o) acc[o] = be[o];
  gemv_seg(acc, ea + (size_t)e * DD, We + 0, 256);
  const float* p1 = px1 + (size_t)r * DD;
  const float* p2 = px2 + (size_t)c * DD;
  const float* p3 = pu + (size_t)g * DD;
  float* dst = edge_out + (size_t)e * DD;
  #pragma unroll
  for (int o = 0; o < DD; o += 4) {
    float4 a = ld4(p1 + o), b = ld4(p2 + o), cc = ld4(p3 + o);
    float4 v;
    v.x = fmaxf(acc[o + 0] + a.x + b.x + cc.x, 0.f);
    v.y = fmaxf(acc[o + 1] + a.y + b.y + cc.y, 0.f);
    v.z = fmaxf(acc[o + 2] + a.z + b.z + cc.z, 0.f);
    v.w = fmaxf(acc[o + 3] + a.w + b.w + cc.w, 0.f);
    *reinterpret_cast<float4*>(dst + o) = v;
  }
}

// ---- attention logits: t = b1 + W1en.en (shared); w_s/w_r via hq/hkv gathers ----
__global__ void __launch_bounds__(256) k_attnw2(
    const float* __restrict__ edge_new,
    const float* __restrict__ hq, const float* __restrict__ hkv,
    const float* __restrict__ W1, const float* __restrict__ b1, const float* __restrict__ w2,
    const int* __restrict__ row, const int* __restrict__ col,
    float* __restrict__ w_s, float* __restrict__ w_r, int E) {
  int e = blockIdx.x * 256 + threadIdx.x;
  if (e >= E) return;
  int r = row[e], c = col[e];
  float t[DD];
  #pragma unroll
  for (int o = 0; o < DD; ++o) t[o] = b1[o];
  gemv_seg(t, edge_new + (size_t)e * DD, W1 + 128, 192);
  const float* hqr = hq + (size_t)r * DD;
  const float* hqc = hq + (size_t)c * DD;
  const float* hkr = hkv + (size_t)r * DD;
  const float* hkc = hkv + (size_t)c * DD;
  float accs = 0.f, accr = 0.f;
  #pragma unroll
  for (int o = 0; o < DD; o += 4) {
    float4 a = ld4(hqr + o), b = ld4(hkc + o), cc = ld4(hqc + o), d = ld4(hkr + o);
    float4 wv = ld4(w2 + o);
    float h;
    h = t[o + 0] + a.x + b.x; h = (h >= 0.f) ? h : 0.01f * h; accs = fmaf(h, wv.x, accs);
    h = t[o + 1] + a.y + b.y; h = (h >= 0.f) ? h : 0.01f * h; accs = fmaf(h, wv.y, accs);
    h = t[o + 2] + a.z + b.z; h = (h >= 0.f) ? h : 0.01f * h; accs = fmaf(h, wv.z, accs);
    h = t[o + 3] + a.w + b.w; h = (h >= 0.f) ? h : 0.01f * h; accs = fmaf(h, wv.w, accs);
    h = t[o + 0] + cc.x + d.x; h = (h >= 0.f) ? h : 0.01f * h; accr = fmaf(h, wv.x, accr);
    h = t[o + 1] + cc.y + d.y; h = (h >= 0.f) ? h : 0.01f * h; accr = fmaf(h, wv.y, accr);
    h = t[o + 2] + cc.z + d.z; h = (h >= 0.f) ? h : 0.01f * h; accr = fmaf(h, wv.z, accr);
    h = t[o + 3] + cc.w + d.w; h = (h >= 0.f) ? h : 0.01f * h; accr = fmaf(h, wv.w, accr);
  }
  w_s[e] = accs;
  w_r[e] = accr;
}

// ---- gather: per node, softmax over its edge list, p-weighted input sums, then W3 matvec ----
__global__ void __launch_bounds__(256) k_gather(
    const float* __restrict__ x, const float* __restrict__ edge_new,
    const float* __restrict__ w, const int* __restrict__ lst, const int* __restrict__ deg_a,
    const int* __restrict__ other_idx,
    const float* __restrict__ W3, const float* __restrict__ b3,
    float* __restrict__ out, int N) {
  int n = blockIdx.x * 256 + threadIdx.x;
  if (n >= N) return;
  int deg = deg_a[n];
  deg = deg < 64 ? deg : 64;
  float* dst = out + (size_t)n * DD;
  if (deg == 0) {
    #pragma unroll
    for (int o = 0; o < DD; o += 4) *reinterpret_cast<float4*>(dst + o) = make_float4(0.f, 0.f, 0.f, 0.f);
    return;
  }
  const int* le = lst + (size_t)n * 64;
  float m = -1e30f;
  for (int i = 0; i < deg; ++i) m = fmaxf(m, w[le[i]]);
  float s[128];
  #pragma unroll
  for (int k = 0; k < 128; ++k) s[k] = 0.f;
  float S = 0.f;
  for (int i = 0; i < deg; ++i) {
    int e = le[i];
    float p = __expf(w[e] - m);
    S += p;
    const float* xv = x + (size_t)other_idx[e] * DD;
    const float* ev = edge_new + (size_t)e * DD;
    #pragma unroll
    for (int k = 0; k < DD; k += 4) {
      float4 a = ld4(xv + k);
      s[k + 0] = fmaf(p, a.x, s[k + 0]); s[k + 1] = fmaf(p, a.y, s[k + 1]);
      s[k + 2] = fmaf(p, a.z, s[k + 2]); s[k + 3] = fmaf(p, a.w, s[k + 3]);
    }
    #pragma unroll
    for (int k = 0; k < DD; k += 4) {
      float4 a = ld4(ev + k);
      s[64 + k + 0] = fmaf(p, a.x, s[64 + k + 0]); s[64 + k + 1] = fmaf(p, a.y, s[64 + k + 1]);
      s[64 + k + 2] = fmaf(p, a.z, s[64 + k + 2]); s[64 + k + 3] = fmaf(p, a.w, s[64 + k + 3]);
    }
  }
  float inv = 1.f / (S + 1e-16f);
  float scale = S * inv;
  #pragma unroll
  for (int k = 0; k < 128; ++k) s[k] *= inv;
  float acc[DD];
  #pragma unroll
  for (int o = 0; o < DD; ++o) acc[o] = b3[o] * scale;
  gemv_reg128(acc, s, W3);
  #pragma unroll
  for (int o = 0; o < DD; o += 4) *reinterpret_cast<float4*>(dst + o) = make_float4(acc[o], acc[o+1], acc[o+2], acc[o+3]);
}

// ---- node MLP ----
__global__ void __launch_bounds__(256) k_node(
    const float* __restrict__ x, const float* __restrict__ sent, const float* __restrict__ recv,
    const float* __restrict__ u, const float* __restrict__ Wn, const float* __restrict__ bn,
    const int* __restrict__ nbat, float* __restrict__ x_out, int N) {
  int n = blockIdx.x * 256 + threadIdx.x;
  if (n >= N) return;
  int g = nbat[n];
  float acc[DD];
  #pragma unroll
  for (int o = 0; o < DD; ++o) acc[o] = bn[o];
  #pragma unroll 1
  for (int s = 0; s < 4; ++s) {
    const float* src = (s == 0) ? x    + (size_t)n * DD
                     : (s == 1) ? sent + (size_t)n * DD
                     : (s == 2) ? recv + (size_t)n * DD
                                : u    + (size_t)g * DD;
    gemv_seg(acc, src, Wn + s * DD, 4 * DD);
  }
  float* dst = x_out + (size_t)n * DD;
  #pragma unroll
  for (int o = 0; o < DD; o += 4) {
    float4 v;
    v.x = fmaxf(acc[o + 0], 0.f); v.y = fmaxf(acc[o + 1], 0.f);
    v.z = fmaxf(acc[o + 2], 0.f); v.w = fmaxf(acc[o + 3], 0.f);
    *reinterpret_cast<float4*>(dst + o) = v;
  }
}

// ---- segment-sum over sorted segment ids (run-length + atomic flush) ----
__global__ void __launch_bounds__(256) k_segsum(
    const float* __restrict__ vals, const int* __restrict__ seg,
    float* __restrict__ out, int n) {
  int d = threadIdx.x & 63;
  int grp = threadIdx.x >> 6;
  long base = (long)blockIdx.x * 1024 + (long)grp * 256;
  float sum = 0.f;
  int cur = -1;
  for (int k = 0; k < 256; ++k) {
    long e = base + k;
    if (e >= n) break;
    int gb = seg[e];
    float v = vals[e * DD + d];
    if (gb != cur) {
      if (cur >= 0) atomicAdd(out + (size_t)cur * DD + d, sum);
      cur = gb; sum = v;
    } else {
      sum += v;
    }
  }
  if (cur >= 0) atomicAdd(out + (size_t)cur * DD + d, sum);
}

// ---- global MLP ----
__global__ void __launch_bounds__(64) k_glob(
    const float* __restrict__ u, const float* __restrict__ nagg, const float* __restrict__ eagg,
    const float* __restrict__ Wg, const float* __restrict__ bg,
    float* __restrict__ u_out, int G) {
  int t = blockIdx.x * 64 + threadIdx.x;
  if (t >= G * 64) return;
  int g = t >> 6, o = t & 63;
  float acc = bg[o];
  const float* wr = Wg + (size_t)o * 192;
  for (int i = 0; i < 64; ++i) acc = fmaf(u[g * 64 + i],    wr[i],       acc);
  for (int i = 0; i < 64; ++i) acc = fmaf(nagg[g * 64 + i], wr[64 + i],  acc);
  for (int i = 0; i < 64; ++i) acc = fmaf(eagg[g * 64 + i], wr[128 + i], acc);
  u_out[t] = fmaxf(acc, 0.f);
}

extern "C" void kernel_launch(void* const* d_in, const int* in_sizes, int n_in,
                              void* d_out, int out_size, void* d_ws, size_t ws_size,
                              hipStream_t stream) {
  const float* x   = (const float*)d_in[0];
  const float* ea  = (const float*)d_in[1];
  const float* u   = (const float*)d_in[2];
  const float* We  = (const float*)d_in[3];
  const float* be  = (const float*)d_in[4];
  const float* Wn  = (const float*)d_in[5];
  const float* bn  = (const float*)d_in[6];
  const float* Wg  = (const float*)d_in[7];
  const float* bg  = (const float*)d_in[8];
  const float* W1  = (const float*)d_in[9];
  const float* b1  = (const float*)d_in[10];
  const float* w2  = (const float*)d_in[11];
  const float* W3  = (const float*)d_in[12];
  const float* b3  = (const float*)d_in[13];
  const int* eidx  = (const int*)d_in[14];
  const int* nbat  = (const int*)d_in[15];
  const int* ebat  = (const int*)d_in[16];

  const int N = in_sizes[0] / 64;
  const int E = in_sizes[1] / 64;
  const int G = in_sizes[2] / 64;
  const int* row = eidx;
  const int* col = eidx + E;

  float* out   = (float*)d_out;
  float* x_out = out;
  float* e_out = out + (size_t)N * 64;
  float* u_out = out + (size_t)(N + E) * 64;

  // ---- workspace layout ----
  float* ws = (float*)d_ws;
  // R1: px1,px2,hq,hkv (4*N*64) during pre/edge/attn; sent,recv reuse first 2*N*64 after
  float* px1 = ws;
  float* px2 = ws + (size_t)N * 64;
  float* hq  = ws + 2 * (size_t)N * 64;
  float* hkv = ws + 3 * (size_t)N * 64;
  float* sent = px1;  // reuse (px dead after k_attnw2)
  float* recv = px2;
  float* w_s = ws + 4 * (size_t)N * 64;
  float* w_r = w_s + E;
  float* pu  = w_r + E;                         // G*64
  int* lst_s = (int*)(pu + (size_t)G * 64);     // N*64
  int* lst_r = lst_s + (size_t)N * 64;          // N*64
  int* deg_s = lst_r + (size_t)N * 64;          // N
  int* deg_r = deg_s + N;                       // N
  float* nagg = (float*)(deg_r + N);            // G*64
  float* eagg = nagg + (size_t)G * 64;          // G*64

  // zero deg + aggs (contiguous)
  hipMemsetAsync(deg_s, 0, (2 * (size_t)N + 2 * (size_t)G * 64) * sizeof(int), stream);

  const int gE = (E + 255) / 256;
  const int gN = (N + 255) / 256;

  k_fill<<<gE, 256, 0, stream>>>(row, col, deg_s, deg_r, lst_s, lst_r, E);
  k_nodepre<<<gN, 256, 0, stream>>>(x, u, We, W1, px1, px2, hq, hkv, pu, N, G);
  k_edge2<<<gE, 256, 0, stream>>>(ea, px1, px2, pu, We, be, row, col, ebat, e_out, E);
  k_attnw2<<<gE, 256, 0, stream>>>(e_out, hq, hkv, W1, b1, w2, row, col, w_s, w_r, E);
  k_segsum<<<(E + 1023) / 1024, 256, 0, stream>>>(e_out, ebat, eagg, E);
  // gathers overwrite px1/px2 (sent/recv) — px dead by now
  k_gather<<<gN, 256, 0, stream>>>(x, e_out, w_s, lst_s, deg_s, col, W3, b3, sent, N);
  k_gather<<<gN, 256, 0, stream>>>(x, e_out, w_r, lst_r, deg_r, row, W3, b3, recv, N);
  k_node<<<gN, 256, 0, stream>>>(x, sent, recv, u, Wn, bn, nbat, x_out, N);
  k_segsum<<<(N + 1023) / 1024, 256, 0, stream>>>(x_out, nbat, nagg, N);
  k_glob<<<(G * 64 + 63) / 64, 64, 0, stream>>>(u, nagg, eagg, Wg, bg, u_out, G);
}

// Round 3
// 1996.263 us; speedup vs baseline: 2.9968x; 1.0003x over previous
//
#include <hip/hip_runtime.h>

#define DD 64

__device__ __forceinline__ float4 ld4(const float* p) {
  return *reinterpret_cast<const float4*>(p);
}

// acc[64] += W[o*ldw + 0..LEN-1] . src[0..LEN-1]; W wave-uniform (scalar loads),
// src per-lane global pointer (float4 loads).
template <int LEN>
__device__ __forceinline__ void gemv_g(float* acc, const float* __restrict__ src,
                                       const float* __restrict__ W, const int ldw) {
  #pragma unroll 1
  for (int ic = 0; ic < LEN; ic += 8) {
    const float4 a = ld4(src + ic);
    const float4 b = ld4(src + ic + 4);
    #pragma unroll
    for (int o = 0; o < DD; ++o) {
      const float* wr = W + o * ldw + ic;
      float t = acc[o];
      t = fmaf(a.x, wr[0], t); t = fmaf(a.y, wr[1], t);
      t = fmaf(a.z, wr[2], t); t = fmaf(a.w, wr[3], t);
      t = fmaf(b.x, wr[4], t); t = fmaf(b.y, wr[5], t);
      t = fmaf(b.z, wr[6], t);
      acc[o] = fmaf(b.w, wr[7], t);
    }
  }
}

// acc[64] += W[o*ldw + 0..63] . s[0..63] with s in REGISTERS (static indexing).
__device__ __forceinline__ void gemv_reg64(float* acc, const float* s,
                                           const float* __restrict__ W, const int ldw) {
  #pragma unroll 1
  for (int ic = 0; ic < DD; ic += 8) {
    #pragma unroll
    for (int o = 0; o < DD; ++o) {
      const float* wr = W + o * ldw + ic;
      float t = acc[o];
      t = fmaf(s[ic + 0], wr[0], t); t = fmaf(s[ic + 1], wr[1], t);
      t = fmaf(s[ic + 2], wr[2], t); t = fmaf(s[ic + 3], wr[3], t);
      t = fmaf(s[ic + 4], wr[4], t); t = fmaf(s[ic + 5], wr[5], t);
      t = fmaf(s[ic + 6], wr[6], t);
      acc[o] = fmaf(s[ic + 7], wr[7], t);
    }
  }
}

// ---- build padded CSR (both directions), MAXDEG=64 ----
__global__ void __launch_bounds__(256) k_fill(
    const int* __restrict__ row, const int* __restrict__ col,
    int* __restrict__ deg_s, int* __restrict__ deg_r,
    int* __restrict__ lst_s, int* __restrict__ lst_r, int E) {
  int e = blockIdx.x * 256 + threadIdx.x;
  if (e >= E) return;
  int r = row[e], c = col[e];
  int s0 = atomicAdd(deg_s + r, 1);
  if (s0 < 64) lst_s[(size_t)r * 64 + s0] = e;
  int s1 = atomicAdd(deg_r + c, 1);
  if (s1 < 64) lst_r[(size_t)c * 64 + s1] = e;
}

// ---- per-node precompute: px1=Wx1.x, px2=Wx2.x, hq=W1q.x, hkv=W1kv.x; pu=Wu.u ----
__global__ void __launch_bounds__(256) k_nodepre(
    const float* __restrict__ x, const float* __restrict__ u,
    const float* __restrict__ We, const float* __restrict__ W1,
    float* __restrict__ px1, float* __restrict__ px2,
    float* __restrict__ hq, float* __restrict__ hkv, float* __restrict__ pu,
    int N, int G) {
  int n = blockIdx.x * 256 + threadIdx.x;
  if (n >= N) return;
  const float* xr = x + (size_t)n * DD;
  float acc[DD];
  #pragma unroll
  for (int o = 0; o < DD; ++o) acc[o] = 0.f;
  gemv_g<64>(acc, xr, We + 64, 256);
  #pragma unroll
  for (int o = 0; o < DD; o += 4) *reinterpret_cast<float4*>(px1 + (size_t)n * DD + o) = make_float4(acc[o], acc[o+1], acc[o+2], acc[o+3]);
  #pragma unroll
  for (int o = 0; o < DD; ++o) acc[o] = 0.f;
  gemv_g<64>(acc, xr, We + 128, 256);
  #pragma unroll
  for (int o = 0; o < DD; o += 4) *reinterpret_cast<float4*>(px2 + (size_t)n * DD + o) = make_float4(acc[o], acc[o+1], acc[o+2], acc[o+3]);
  #pragma unroll
  for (int o = 0; o < DD; ++o) acc[o] = 0.f;
  gemv_g<64>(acc, xr, W1 + 0, 192);
  #pragma unroll
  for (int o = 0; o < DD; o += 4) *reinterpret_cast<float4*>(hq + (size_t)n * DD + o) = make_float4(acc[o], acc[o+1], acc[o+2], acc[o+3]);
  #pragma unroll
  for (int o = 0; o < DD; ++o) acc[o] = 0.f;
  gemv_g<64>(acc, xr, W1 + 64, 192);
  #pragma unroll
  for (int o = 0; o < DD; o += 4) *reinterpret_cast<float4*>(hkv + (size_t)n * DD + o) = make_float4(acc[o], acc[o+1], acc[o+2], acc[o+3]);
  if (n < G) {
    #pragma unroll
    for (int o = 0; o < DD; ++o) acc[o] = 0.f;
    gemv_g<64>(acc, u + (size_t)n * DD, We + 192, 256);
    #pragma unroll
    for (int o = 0; o < DD; o += 4) *reinterpret_cast<float4*>(pu + (size_t)n * DD + o) = make_float4(acc[o], acc[o+1], acc[o+2], acc[o+3]);
  }
}

// ---- precombine: Ms = Wn[:,64:128].W3, cs = Wn[:,64:128].b3; Mr/cr for 128:192 ----
__global__ void __launch_bounds__(128) k_precomb(
    const float* __restrict__ Wn, const float* __restrict__ W3, const float* __restrict__ b3,
    float* __restrict__ Ms, float* __restrict__ cs,
    float* __restrict__ Mr, float* __restrict__ cr) {
  int t = threadIdx.x;           // 128 threads: dir*64 + o
  int dir = t >> 6, o = t & 63;
  const float* wrow = Wn + (size_t)o * 256 + 64 + 64 * dir;
  float* M  = dir ? Mr : Ms;
  float* cv = dir ? cr : cs;
  if (blockIdx.x == 0) {
    float cb = 0.f;
    for (int k = 0; k < 64; ++k) cb = fmaf(wrow[k], b3[k], cb);
    cv[o] = cb;
  }
  int c0 = blockIdx.x * 16;
  for (int c = c0; c < c0 + 16; ++c) {
    float m = 0.f;
    for (int k = 0; k < 64; ++k) m = fmaf(wrow[k], W3[k * 128 + c], m);
    M[(size_t)o * 128 + c] = m;
  }
}

// ---- fused edge MLP + attention logits ----
__global__ void __launch_bounds__(256) k_edgeattn(
    const float* __restrict__ ea,
    const float* __restrict__ px1, const float* __restrict__ px2, const float* __restrict__ pu,
    const float* __restrict__ hq, const float* __restrict__ hkv,
    const float* __restrict__ We, const float* __restrict__ be,
    const float* __restrict__ W1, const float* __restrict__ b1, const float* __restrict__ w2,
    const int* __restrict__ row, const int* __restrict__ col, const int* __restrict__ ebat,
    float* __restrict__ edge_out, float* __restrict__ w_s, float* __restrict__ w_r, int E) {
  int e = blockIdx.x * 256 + threadIdx.x;
  if (e >= E) return;
  int r = row[e], c = col[e], g = ebat[e];
  // edge_new in registers
  float en[DD];
  #pragma unroll
  for (int o = 0; o < DD; ++o) en[o] = be[o];
  gemv_g<64>(en, ea + (size_t)e * DD, We, 256);
  const float* p1 = px1 + (size_t)r * DD;
  const float* p2 = px2 + (size_t)c * DD;
  const float* p3 = pu + (size_t)g * DD;
  float* dst = edge_out + (size_t)e * DD;
  #pragma unroll
  for (int o = 0; o < DD; o += 4) {
    float4 a = ld4(p1 + o), b = ld4(p2 + o), cc = ld4(p3 + o);
    en[o + 0] = fmaxf(en[o + 0] + a.x + b.x + cc.x, 0.f);
    en[o + 1] = fmaxf(en[o + 1] + a.y + b.y + cc.y, 0.f);
    en[o + 2] = fmaxf(en[o + 2] + a.z + b.z + cc.z, 0.f);
    en[o + 3] = fmaxf(en[o + 3] + a.w + b.w + cc.w, 0.f);
    *reinterpret_cast<float4*>(dst + o) = make_float4(en[o], en[o+1], en[o+2], en[o+3]);
  }
  // t = b1 + W1en . en  (en from registers — no global re-read)
  float t[DD];
  #pragma unroll
  for (int o = 0; o < DD; ++o) t[o] = b1[o];
  gemv_reg64(t, en, W1 + 128, 192);
  // logits for both directions
  const float* hqr = hq + (size_t)r * DD;
  const float* hqc = hq + (size_t)c * DD;
  const float* hkr = hkv + (size_t)r * DD;
  const float* hkc = hkv + (size_t)c * DD;
  float accs = 0.f, accr = 0.f;
  #pragma unroll
  for (int o = 0; o < DD; o += 4) {
    float4 a = ld4(hqr + o), b = ld4(hkc + o), cc = ld4(hqc + o), d = ld4(hkr + o);
    float4 wv = ld4(w2 + o);
    float h;
    h = t[o + 0] + a.x + b.x; h = (h >= 0.f) ? h : 0.01f * h; accs = fmaf(h, wv.x, accs);
    h = t[o + 1] + a.y + b.y; h = (h >= 0.f) ? h : 0.01f * h; accs = fmaf(h, wv.y, accs);
    h = t[o + 2] + a.z + b.z; h = (h >= 0.f) ? h : 0.01f * h; accs = fmaf(h, wv.z, accs);
    h = t[o + 3] + a.w + b.w; h = (h >= 0.f) ? h : 0.01f * h; accs = fmaf(h, wv.w, accs);
    h = t[o + 0] + cc.x + d.x; h = (h >= 0.f) ? h : 0.01f * h; accr = fmaf(h, wv.x, accr);
    h = t[o + 1] + cc.y + d.y; h = (h >= 0.f) ? h : 0.01f * h; accr = fmaf(h, wv.y, accr);
    h = t[o + 2] + cc.z + d.z; h = (h >= 0.f) ? h : 0.01f * h; accr = fmaf(h, wv.z, accr);
    h = t[o + 3] + cc.w + d.w; h = (h >= 0.f) ? h : 0.01f * h; accr = fmaf(h, wv.w, accr);
  }
  w_s[e] = accs;
  w_r[e] = accr;
}

// ---- wave-per-node gather: softmax over edge list, coalesced p-weighted row sums ----
// lane = channel. Outputs: ss[n*128 + 0:128] = [sum_p*x_other ; sum_p*en] / (S+eps),
// gam[n] = S/(S+eps).
__global__ void __launch_bounds__(256) k_gatherw(
    const float* __restrict__ x, const float* __restrict__ en, const float* __restrict__ w,
    const int* __restrict__ lst, const int* __restrict__ deg_a, const int* __restrict__ other_idx,
    float* __restrict__ ss, float* __restrict__ gam, int N) {
  int wid = threadIdx.x >> 6, lane = threadIdx.x & 63;
  int n = blockIdx.x * 4 + wid;
  if (n >= N) return;
  int deg = deg_a[n];
  deg = deg < 64 ? deg : 64;
  float* ssd = ss + (size_t)n * 128;
  if (deg == 0) {
    ssd[lane] = 0.f; ssd[64 + lane] = 0.f;
    if (lane == 0) gam[n] = 0.f;
    return;
  }
  int e = 0, oe = 0;
  float wv = -1e30f;
  if (lane < deg) {
    e = lst[(size_t)n * 64 + lane];
    oe = other_idx[e];
    wv = w[e];
  }
  float m = wv;
  #pragma unroll
  for (int d = 32; d; d >>= 1) m = fmaxf(m, __shfl_xor(m, d, 64));
  float p = (lane < deg) ? __expf(wv - m) : 0.f;
  float S = p;
  #pragma unroll
  for (int d = 32; d; d >>= 1) S += __shfl_xor(S, d, 64);
  float sx = 0.f, se = 0.f;
  for (int i = 0; i < deg; ++i) {
    float pi = __shfl(p, i, 64);
    int ei = __shfl(e, i, 64);
    int oi = __shfl(oe, i, 64);
    sx = fmaf(pi, x[(size_t)oi * DD + lane], sx);     // coalesced 256B row
    se = fmaf(pi, en[(size_t)ei * DD + lane], se);    // coalesced 256B row
  }
  float inv = 1.f / (S + 1e-16f);
  ssd[lane] = sx * inv;
  ssd[64 + lane] = se * inv;
  if (lane == 0) gam[n] = S * inv;
}

// ---- node MLP with folded attention-value matvecs ----
__global__ void __launch_bounds__(256) k_node2(
    const float* __restrict__ x, const float* __restrict__ ss_s, const float* __restrict__ ss_r,
    const float* __restrict__ gam_s, const float* __restrict__ gam_r,
    const float* __restrict__ u,
    const float* __restrict__ Wn, const float* __restrict__ bn,
    const float* __restrict__ Ms, const float* __restrict__ cs,
    const float* __restrict__ Mr, const float* __restrict__ cr,
    const int* __restrict__ nbat, float* __restrict__ x_out, int N) {
  int n = blockIdx.x * 256 + threadIdx.x;
  if (n >= N) return;
  int g = nbat[n];
  float gs = gam_s[n], gr = gam_r[n];
  float acc[DD];
  #pragma unroll
  for (int o = 0; o < DD; ++o) acc[o] = fmaf(gs, cs[o], fmaf(gr, cr[o], bn[o]));
  gemv_g<64>(acc, x + (size_t)n * DD, Wn, 256);
  gemv_g<64>(acc, u + (size_t)g * DD, Wn + 192, 256);
  gemv_g<128>(acc, ss_s + (size_t)n * 128, Ms, 128);
  gemv_g<128>(acc, ss_r + (size_t)n * 128, Mr, 128);
  float* dst = x_out + (size_t)n * DD;
  #pragma unroll
  for (int o = 0; o < DD; o += 4) {
    float4 v;
    v.x = fmaxf(acc[o + 0], 0.f); v.y = fmaxf(acc[o + 1], 0.f);
    v.z = fmaxf(acc[o + 2], 0.f); v.w = fmaxf(acc[o + 3], 0.f);
    *reinterpret_cast<float4*>(dst + o) = v;
  }
}

// ---- segment-sum over sorted segment ids (run-length + atomic flush) ----
__global__ void __launch_bounds__(256) k_segsum(
    const float* __restrict__ vals, const int* __restrict__ seg,
    float* __restrict__ out, int n) {
  int d = threadIdx.x & 63;
  int grp = threadIdx.x >> 6;
  long base = (long)blockIdx.x * 1024 + (long)grp * 256;
  float sum = 0.f;
  int cur = -1;
  for (int k = 0; k < 256; ++k) {
    long e = base + k;
    if (e >= n) break;
    int gb = seg[e];
    float v = vals[e * DD + d];
    if (gb != cur) {
      if (cur >= 0) atomicAdd(out + (size_t)cur * DD + d, sum);
      cur = gb; sum = v;
    } else {
      sum += v;
    }
  }
  if (cur >= 0) atomicAdd(out + (size_t)cur * DD + d, sum);
}

// ---- global MLP ----
__global__ void __launch_bounds__(64) k_glob(
    const float* __restrict__ u, const float* __restrict__ nagg, const float* __restrict__ eagg,
    const float* __restrict__ Wg, const float* __restrict__ bg,
    float* __restrict__ u_out, int G) {
  int t = blockIdx.x * 64 + threadIdx.x;
  if (t >= G * 64) return;
  int g = t >> 6, o = t & 63;
  float acc = bg[o];
  const float* wr = Wg + (size_t)o * 192;
  for (int i = 0; i < 64; ++i) acc = fmaf(u[g * 64 + i],    wr[i],       acc);
  for (int i = 0; i < 64; ++i) acc = fmaf(nagg[g * 64 + i], wr[64 + i],  acc);
  for (int i = 0; i < 64; ++i) acc = fmaf(eagg[g * 64 + i], wr[128 + i], acc);
  u_out[t] = fmaxf(acc, 0.f);
}

extern "C" void kernel_launch(void* const* d_in, const int* in_sizes, int n_in,
                              void* d_out, int out_size, void* d_ws, size_t ws_size,
                              hipStream_t stream) {
  const float* x   = (const float*)d_in[0];
  const float* ea  = (const float*)d_in[1];
  const float* u   = (const float*)d_in[2];
  const float* We  = (const float*)d_in[3];
  const float* be  = (const float*)d_in[4];
  const float* Wn  = (const float*)d_in[5];
  const float* bn  = (const float*)d_in[6];
  const float* Wg  = (const float*)d_in[7];
  const float* bg  = (const float*)d_in[8];
  const float* W1  = (const float*)d_in[9];
  const float* b1  = (const float*)d_in[10];
  const float* w2  = (const float*)d_in[11];
  const float* W3  = (const float*)d_in[12];
  const float* b3  = (const float*)d_in[13];
  const int* eidx  = (const int*)d_in[14];
  const int* nbat  = (const int*)d_in[15];
  const int* ebat  = (const int*)d_in[16];

  const int N = in_sizes[0] / 64;
  const int E = in_sizes[1] / 64;
  const int G = in_sizes[2] / 64;
  const int* row = eidx;
  const int* col = eidx + E;

  float* out   = (float*)d_out;
  float* x_out = out;
  float* e_out = out + (size_t)N * 64;
  float* u_out = out + (size_t)(N + E) * 64;

  // ---- workspace layout ----
  float* ws = (float*)d_ws;
  // region A (N*128): px1|px2 during edge phase; ss_s after
  float* px1 = ws;
  float* px2 = ws + (size_t)N * 64;
  float* ss_s = ws;
  // region B (N*128): hq|hkv during edge phase; ss_r after
  float* hq  = ws + (size_t)N * 128;
  float* hkv = hq + (size_t)N * 64;
  float* ss_r = hq;
  float* w_s = ws + (size_t)N * 256;            // E
  float* w_r = w_s + E;                         // E
  float* pu  = w_r + E;                         // G*64
  int* lst_s = (int*)(pu + (size_t)G * 64);     // N*64
  int* lst_r = lst_s + (size_t)N * 64;          // N*64
  int* deg_s = lst_r + (size_t)N * 64;          // N    (memset from here...)
  int* deg_r = deg_s + N;                       // N
  float* nagg = (float*)(deg_r + N);            // G*64
  float* eagg = nagg + (size_t)G * 64;          // G*64 (...to here)
  float* gam_s = eagg + (size_t)G * 64;         // N
  float* gam_r = gam_s + N;                     // N
  float* Ms = gam_r + N;                        // 64*128
  float* Mr = Ms + 64 * 128;                    // 64*128
  float* cs = Mr + 64 * 128;                    // 64
  float* cr = cs + 64;                          // 64

  hipMemsetAsync(deg_s, 0, (2 * (size_t)N + 2 * (size_t)G * 64) * sizeof(int), stream);

  const int gE = (E + 255) / 256;
  const int gN = (N + 255) / 256;

  k_fill<<<gE, 256, 0, stream>>>(row, col, deg_s, deg_r, lst_s, lst_r, E);
  k_nodepre<<<gN, 256, 0, stream>>>(x, u, We, W1, px1, px2, hq, hkv, pu, N, G);
  k_precomb<<<8, 128, 0, stream>>>(Wn, W3, b3, Ms, cs, Mr, cr);
  k_edgeattn<<<gE, 256, 0, stream>>>(ea, px1, px2, pu, hq, hkv, We, be, W1, b1, w2,
                                     row, col, ebat, e_out, w_s, w_r, E);
  k_segsum<<<(E + 1023) / 1024, 256, 0, stream>>>(e_out, ebat, eagg, E);
  // gathers overwrite regions A/B (px/hq dead after k_edgeattn)
  k_gatherw<<<(N + 3) / 4, 256, 0, stream>>>(x, e_out, w_s, lst_s, deg_s, col, ss_s, gam_s, N);
  k_gatherw<<<(N + 3) / 4, 256, 0, stream>>>(x, e_out, w_r, lst_r, deg_r, row, ss_r, gam_r, N);
  k_node2<<<gN, 256, 0, stream>>>(x, ss_s, ss_r, gam_s, gam_r, u, Wn, bn,
                                  Ms, cs, Mr, cr, nbat, x_out, N);
  k_segsum<<<(N + 1023) / 1024, 256, 0, stream>>>(x_out, nbat, nagg, N);
  k_glob<<<(G * 64 + 63) / 64, 64, 0, stream>>>(u, nagg, eagg, Wg, bg, u_out, G);
}

// Round 4
// 1953.372 us; speedup vs baseline: 3.0626x; 1.0220x over previous
//
#include <hip/hip_runtime.h>

#define DD 64

__device__ __forceinline__ float4 ld4(const float* p) {
  return *reinterpret_cast<const float4*>(p);
}

// acc[64] += W[o*ldw + 0..LEN-1] . src[0..LEN-1]; W wave-uniform (scalar loads),
// src per-lane global pointer (float4 loads). acc statically indexed.
template <int LEN>
__device__ __forceinline__ void gemv_g(float* acc, const float* __restrict__ src,
                                       const float* __restrict__ W, const int ldw) {
  #pragma unroll 1
  for (int ic = 0; ic < LEN; ic += 8) {
    const float4 a = ld4(src + ic);
    const float4 b = ld4(src + ic + 4);
    #pragma unroll
    for (int o = 0; o < DD; ++o) {
      const float* wr = W + o * ldw + ic;
      float t = acc[o];
      t = fmaf(a.x, wr[0], t); t = fmaf(a.y, wr[1], t);
      t = fmaf(a.z, wr[2], t); t = fmaf(a.w, wr[3], t);
      t = fmaf(b.x, wr[4], t); t = fmaf(b.y, wr[5], t);
      t = fmaf(b.z, wr[6], t);
      acc[o] = fmaf(b.w, wr[7], t);
    }
  }
}

// acc[64] += W[o*ldw + 0..63] . s[0..63] with s in REGISTERS.
// FULLY unrolled: every s[] index is compile-time constant (no scratch).
__device__ __forceinline__ void gemv_reg64(float* acc, const float* s,
                                           const float* __restrict__ W, const int ldw) {
  #pragma unroll
  for (int ic = 0; ic < DD; ic += 8) {
    #pragma unroll
    for (int o = 0; o < DD; ++o) {
      const float* wr = W + o * ldw + ic;
      float t = acc[o];
      t = fmaf(s[ic + 0], wr[0], t); t = fmaf(s[ic + 1], wr[1], t);
      t = fmaf(s[ic + 2], wr[2], t); t = fmaf(s[ic + 3], wr[3], t);
      t = fmaf(s[ic + 4], wr[4], t); t = fmaf(s[ic + 5], wr[5], t);
      t = fmaf(s[ic + 6], wr[6], t);
      acc[o] = fmaf(s[ic + 7], wr[7], t);
    }
  }
}

// ---- build padded CSR (both directions), MAXDEG=64 ----
__global__ void __launch_bounds__(256) k_fill(
    const int* __restrict__ row, const int* __restrict__ col,
    int* __restrict__ deg_s, int* __restrict__ deg_r,
    int* __restrict__ lst_s, int* __restrict__ lst_r, int E) {
  int e = blockIdx.x * 256 + threadIdx.x;
  if (e >= E) return;
  int r = row[e], c = col[e];
  int s0 = atomicAdd(deg_s + r, 1);
  if (s0 < 64) lst_s[(size_t)r * 64 + s0] = e;
  int s1 = atomicAdd(deg_r + c, 1);
  if (s1 < 64) lst_r[(size_t)c * 64 + s1] = e;
}

// ---- per-node precompute: px1=Wx1.x, px2=Wx2.x, hq=W1q.x, hkv=W1kv.x; pu=Wu.u ----
__global__ void __launch_bounds__(256, 2) k_nodepre(
    const float* __restrict__ x, const float* __restrict__ u,
    const float* __restrict__ We, const float* __restrict__ W1,
    float* __restrict__ px1, float* __restrict__ px2,
    float* __restrict__ hq, float* __restrict__ hkv, float* __restrict__ pu,
    int N, int G) {
  int n = blockIdx.x * 256 + threadIdx.x;
  if (n >= N) return;
  const float* xr = x + (size_t)n * DD;
  float acc[DD];
  #pragma unroll
  for (int o = 0; o < DD; ++o) acc[o] = 0.f;
  gemv_g<64>(acc, xr, We + 64, 256);
  #pragma unroll
  for (int o = 0; o < DD; o += 4) *reinterpret_cast<float4*>(px1 + (size_t)n * DD + o) = make_float4(acc[o], acc[o+1], acc[o+2], acc[o+3]);
  #pragma unroll
  for (int o = 0; o < DD; ++o) acc[o] = 0.f;
  gemv_g<64>(acc, xr, We + 128, 256);
  #pragma unroll
  for (int o = 0; o < DD; o += 4) *reinterpret_cast<float4*>(px2 + (size_t)n * DD + o) = make_float4(acc[o], acc[o+1], acc[o+2], acc[o+3]);
  #pragma unroll
  for (int o = 0; o < DD; ++o) acc[o] = 0.f;
  gemv_g<64>(acc, xr, W1 + 0, 192);
  #pragma unroll
  for (int o = 0; o < DD; o += 4) *reinterpret_cast<float4*>(hq + (size_t)n * DD + o) = make_float4(acc[o], acc[o+1], acc[o+2], acc[o+3]);
  #pragma unroll
  for (int o = 0; o < DD; ++o) acc[o] = 0.f;
  gemv_g<64>(acc, xr, W1 + 64, 192);
  #pragma unroll
  for (int o = 0; o < DD; o += 4) *reinterpret_cast<float4*>(hkv + (size_t)n * DD + o) = make_float4(acc[o], acc[o+1], acc[o+2], acc[o+3]);
  if (n < G) {
    #pragma unroll
    for (int o = 0; o < DD; ++o) acc[o] = 0.f;
    gemv_g<64>(acc, u + (size_t)n * DD, We + 192, 256);
    #pragma unroll
    for (int o = 0; o < DD; o += 4) *reinterpret_cast<float4*>(pu + (size_t)n * DD + o) = make_float4(acc[o], acc[o+1], acc[o+2], acc[o+3]);
  }
}

// ---- precombine: Ms = Wn[:,64:128].W3, cs = Wn[:,64:128].b3; Mr/cr for 128:192 ----
__global__ void __launch_bounds__(128) k_precomb(
    const float* __restrict__ Wn, const float* __restrict__ W3, const float* __restrict__ b3,
    float* __restrict__ Ms, float* __restrict__ cs,
    float* __restrict__ Mr, float* __restrict__ cr) {
  int t = threadIdx.x;           // 128 threads: dir*64 + o
  int dir = t >> 6, o = t & 63;
  const float* wrow = Wn + (size_t)o * 256 + 64 + 64 * dir;
  float* M  = dir ? Mr : Ms;
  float* cv = dir ? cr : cs;
  if (blockIdx.x == 0) {
    float cb = 0.f;
    for (int k = 0; k < 64; ++k) cb = fmaf(wrow[k], b3[k], cb);
    cv[o] = cb;
  }
  int c0 = blockIdx.x * 16;
  for (int c = c0; c < c0 + 16; ++c) {
    float m = 0.f;
    for (int k = 0; k < 64; ++k) m = fmaf(wrow[k], W3[k * 128 + c], m);
    M[(size_t)o * 128 + c] = m;
  }
}

// ---- fused edge MLP + attention logits ----
__global__ void __launch_bounds__(256, 2) k_edgeattn(
    const float* __restrict__ ea,
    const float* __restrict__ px1, const float* __restrict__ px2, const float* __restrict__ pu,
    const float* __restrict__ hq, const float* __restrict__ hkv,
    const float* __restrict__ We, const float* __restrict__ be,
    const float* __restrict__ W1, const float* __restrict__ b1, const float* __restrict__ w2,
    const int* __restrict__ row, const int* __restrict__ col, const int* __restrict__ ebat,
    float* __restrict__ edge_out, float* __restrict__ w_s, float* __restrict__ w_r, int E) {
  int e = blockIdx.x * 256 + threadIdx.x;
  if (e >= E) return;
  int r = row[e], c = col[e], g = ebat[e];
  // edge_new in registers
  float en[DD];
  #pragma unroll
  for (int o = 0; o < DD; ++o) en[o] = be[o];
  gemv_g<64>(en, ea + (size_t)e * DD, We, 256);
  const float* p1 = px1 + (size_t)r * DD;
  const float* p2 = px2 + (size_t)c * DD;
  const float* p3 = pu + (size_t)g * DD;
  float* dst = edge_out + (size_t)e * DD;
  #pragma unroll
  for (int o = 0; o < DD; o += 4) {
    float4 a = ld4(p1 + o), b = ld4(p2 + o), cc = ld4(p3 + o);
    en[o + 0] = fmaxf(en[o + 0] + a.x + b.x + cc.x, 0.f);
    en[o + 1] = fmaxf(en[o + 1] + a.y + b.y + cc.y, 0.f);
    en[o + 2] = fmaxf(en[o + 2] + a.z + b.z + cc.z, 0.f);
    en[o + 3] = fmaxf(en[o + 3] + a.w + b.w + cc.w, 0.f);
    *reinterpret_cast<float4*>(dst + o) = make_float4(en[o], en[o+1], en[o+2], en[o+3]);
  }
  // t = b1 + W1en . en  (en from registers — statically indexed, no scratch)
  float t[DD];
  #pragma unroll
  for (int o = 0; o < DD; ++o) t[o] = b1[o];
  gemv_reg64(t, en, W1 + 128, 192);
  // logits for both directions
  const float* hqr = hq + (size_t)r * DD;
  const float* hqc = hq + (size_t)c * DD;
  const float* hkr = hkv + (size_t)r * DD;
  const float* hkc = hkv + (size_t)c * DD;
  float accs = 0.f, accr = 0.f;
  #pragma unroll
  for (int o = 0; o < DD; o += 4) {
    float4 a = ld4(hqr + o), b = ld4(hkc + o), cc = ld4(hqc + o), d = ld4(hkr + o);
    float4 wv = ld4(w2 + o);
    float h;
    h = t[o + 0] + a.x + b.x; h = (h >= 0.f) ? h : 0.01f * h; accs = fmaf(h, wv.x, accs);
    h = t[o + 1] + a.y + b.y; h = (h >= 0.f) ? h : 0.01f * h; accs = fmaf(h, wv.y, accs);
    h = t[o + 2] + a.z + b.z; h = (h >= 0.f) ? h : 0.01f * h; accs = fmaf(h, wv.z, accs);
    h = t[o + 3] + a.w + b.w; h = (h >= 0.f) ? h : 0.01f * h; accs = fmaf(h, wv.w, accs);
    h = t[o + 0] + cc.x + d.x; h = (h >= 0.f) ? h : 0.01f * h; accr = fmaf(h, wv.x, accr);
    h = t[o + 1] + cc.y + d.y; h = (h >= 0.f) ? h : 0.01f * h; accr = fmaf(h, wv.y, accr);
    h = t[o + 2] + cc.z + d.z; h = (h >= 0.f) ? h : 0.01f * h; accr = fmaf(h, wv.z, accr);
    h = t[o + 3] + cc.w + d.w; h = (h >= 0.f) ? h : 0.01f * h; accr = fmaf(h, wv.w, accr);
  }
  w_s[e] = accs;
  w_r[e] = accr;
}

// ---- wave-per-node gather: softmax over edge list, coalesced p-weighted row sums ----
__global__ void __launch_bounds__(256) k_gatherw(
    const float* __restrict__ x, const float* __restrict__ en, const float* __restrict__ w,
    const int* __restrict__ lst, const int* __restrict__ deg_a, const int* __restrict__ other_idx,
    float* __restrict__ ss, float* __restrict__ gam, int N) {
  int wid = threadIdx.x >> 6, lane = threadIdx.x & 63;
  int n = blockIdx.x * 4 + wid;
  if (n >= N) return;
  int deg = deg_a[n];
  deg = deg < 64 ? deg : 64;
  float* ssd = ss + (size_t)n * 128;
  if (deg == 0) {
    ssd[lane] = 0.f; ssd[64 + lane] = 0.f;
    if (lane == 0) gam[n] = 0.f;
    return;
  }
  int e = 0, oe = 0;
  float wv = -1e30f;
  if (lane < deg) {
    e = lst[(size_t)n * 64 + lane];
    oe = other_idx[e];
    wv = w[e];
  }
  float m = wv;
  #pragma unroll
  for (int d = 32; d; d >>= 1) m = fmaxf(m, __shfl_xor(m, d, 64));
  float p = (lane < deg) ? __expf(wv - m) : 0.f;
  float S = p;
  #pragma unroll
  for (int d = 32; d; d >>= 1) S += __shfl_xor(S, d, 64);
  float sx = 0.f, se = 0.f;
  for (int i = 0; i < deg; ++i) {
    float pi = __shfl(p, i, 64);
    int ei = __shfl(e, i, 64);
    int oi = __shfl(oe, i, 64);
    sx = fmaf(pi, x[(size_t)oi * DD + lane], sx);     // coalesced 256B row
    se = fmaf(pi, en[(size_t)ei * DD + lane], se);    // coalesced 256B row
  }
  float inv = 1.f / (S + 1e-16f);
  ssd[lane] = sx * inv;
  ssd[64 + lane] = se * inv;
  if (lane == 0) gam[n] = S * inv;
}

// ---- node MLP with folded attention-value matvecs ----
__global__ void __launch_bounds__(256, 2) k_node2(
    const float* __restrict__ x, const float* __restrict__ ss_s, const float* __restrict__ ss_r,
    const float* __restrict__ gam_s, const float* __restrict__ gam_r,
    const float* __restrict__ u,
    const float* __restrict__ Wn, const float* __restrict__ bn,
    const float* __restrict__ Ms, const float* __restrict__ cs,
    const float* __restrict__ Mr, const float* __restrict__ cr,
    const int* __restrict__ nbat, float* __restrict__ x_out, int N) {
  int n = blockIdx.x * 256 + threadIdx.x;
  if (n >= N) return;
  int g = nbat[n];
  float gs = gam_s[n], gr = gam_r[n];
  float acc[DD];
  #pragma unroll
  for (int o = 0; o < DD; ++o) acc[o] = fmaf(gs, cs[o], fmaf(gr, cr[o], bn[o]));
  gemv_g<64>(acc, x + (size_t)n * DD, Wn, 256);
  gemv_g<64>(acc, u + (size_t)g * DD, Wn + 192, 256);
  gemv_g<128>(acc, ss_s + (size_t)n * 128, Ms, 128);
  gemv_g<128>(acc, ss_r + (size_t)n * 128, Mr, 128);
  float* dst = x_out + (size_t)n * DD;
  #pragma unroll
  for (int o = 0; o < DD; o += 4) {
    float4 v;
    v.x = fmaxf(acc[o + 0], 0.f); v.y = fmaxf(acc[o + 1], 0.f);
    v.z = fmaxf(acc[o + 2], 0.f); v.w = fmaxf(acc[o + 3], 0.f);
    *reinterpret_cast<float4*>(dst + o) = v;
  }
}

// ---- segment-sum over sorted segment ids (run-length + atomic flush) ----
__global__ void __launch_bounds__(256) k_segsum(
    const float* __restrict__ vals, const int* __restrict__ seg,
    float* __restrict__ out, int n) {
  int d = threadIdx.x & 63;
  int grp = threadIdx.x >> 6;
  long base = (long)blockIdx.x * 1024 + (long)grp * 256;
  float sum = 0.f;
  int cur = -1;
  for (int k = 0; k < 256; ++k) {
    long e = base + k;
    if (e >= n) break;
    int gb = seg[e];
    float v = vals[e * DD + d];
    if (gb != cur) {
      if (cur >= 0) atomicAdd(out + (size_t)cur * DD + d, sum);
      cur = gb; sum = v;
    } else {
      sum += v;
    }
  }
  if (cur >= 0) atomicAdd(out + (size_t)cur * DD + d, sum);
}

// ---- global MLP ----
__global__ void __launch_bounds__(64) k_glob(
    const float* __restrict__ u, const float* __restrict__ nagg, const float* __restrict__ eagg,
    const float* __restrict__ Wg, const float* __restrict__ bg,
    float* __restrict__ u_out, int G) {
  int t = blockIdx.x * 64 + threadIdx.x;
  if (t >= G * 64) return;
  int g = t >> 6, o = t & 63;
  float acc = bg[o];
  const float* wr = Wg + (size_t)o * 192;
  for (int i = 0; i < 64; ++i) acc = fmaf(u[g * 64 + i],    wr[i],       acc);
  for (int i = 0; i < 64; ++i) acc = fmaf(nagg[g * 64 + i], wr[64 + i],  acc);
  for (int i = 0; i < 64; ++i) acc = fmaf(eagg[g * 64 + i], wr[128 + i], acc);
  u_out[t] = fmaxf(acc, 0.f);
}

extern "C" void kernel_launch(void* const* d_in, const int* in_sizes, int n_in,
                              void* d_out, int out_size, void* d_ws, size_t ws_size,
                              hipStream_t stream) {
  const float* x   = (const float*)d_in[0];
  const float* ea  = (const float*)d_in[1];
  const float* u   = (const float*)d_in[2];
  const float* We  = (const float*)d_in[3];
  const float* be  = (const float*)d_in[4];
  const float* Wn  = (const float*)d_in[5];
  const float* bn  = (const float*)d_in[6];
  const float* Wg  = (const float*)d_in[7];
  const float* bg  = (const float*)d_in[8];
  const float* W1  = (const float*)d_in[9];
  const float* b1  = (const float*)d_in[10];
  const float* w2  = (const float*)d_in[11];
  const float* W3  = (const float*)d_in[12];
  const float* b3  = (const float*)d_in[13];
  const int* eidx  = (const int*)d_in[14];
  const int* nbat  = (const int*)d_in[15];
  const int* ebat  = (const int*)d_in[16];

  const int N = in_sizes[0] / 64;
  const int E = in_sizes[1] / 64;
  const int G = in_sizes[2] / 64;
  const int* row = eidx;
  const int* col = eidx + E;

  float* out   = (float*)d_out;
  float* x_out = out;
  float* e_out = out + (size_t)N * 64;
  float* u_out = out + (size_t)(N + E) * 64;

  // ---- workspace layout ----
  float* ws = (float*)d_ws;
  // region A (N*128): px1|px2 during edge phase; ss_s after
  float* px1 = ws;
  float* px2 = ws + (size_t)N * 64;
  float* ss_s = ws;
  // region B (N*128): hq|hkv during edge phase; ss_r after
  float* hq  = ws + (size_t)N * 128;
  float* hkv = hq + (size_t)N * 64;
  float* ss_r = hq;
  float* w_s = ws + (size_t)N * 256;            // E
  float* w_r = w_s + E;                         // E
  float* pu  = w_r + E;                         // G*64
  int* lst_s = (int*)(pu + (size_t)G * 64);     // N*64
  int* lst_r = lst_s + (size_t)N * 64;          // N*64
  int* deg_s = lst_r + (size_t)N * 64;          // N    (memset from here...)
  int* deg_r = deg_s + N;                       // N
  float* nagg = (float*)(deg_r + N);            // G*64
  float* eagg = nagg + (size_t)G * 64;          // G*64 (...to here)
  float* gam_s = eagg + (size_t)G * 64;         // N
  float* gam_r = gam_s + N;                     // N
  float* Ms = gam_r + N;                        // 64*128
  float* Mr = Ms + 64 * 128;                    // 64*128
  float* cs = Mr + 64 * 128;                    // 64
  float* cr = cs + 64;                          // 64

  hipMemsetAsync(deg_s, 0, (2 * (size_t)N + 2 * (size_t)G * 64) * sizeof(int), stream);

  const int gE = (E + 255) / 256;
  const int gN = (N + 255) / 256;

  k_fill<<<gE, 256, 0, stream>>>(row, col, deg_s, deg_r, lst_s, lst_r, E);
  k_nodepre<<<gN, 256, 0, stream>>>(x, u, We, W1, px1, px2, hq, hkv, pu, N, G);
  k_precomb<<<8, 128, 0, stream>>>(Wn, W3, b3, Ms, cs, Mr, cr);
  k_edgeattn<<<gE, 256, 0, stream>>>(ea, px1, px2, pu, hq, hkv, We, be, W1, b1, w2,
                                     row, col, ebat, e_out, w_s, w_r, E);
  k_segsum<<<(E + 1023) / 1024, 256, 0, stream>>>(e_out, ebat, eagg, E);
  // gathers overwrite regions A/B (px/hq dead after k_edgeattn)
  k_gatherw<<<(N + 3) / 4, 256, 0, stream>>>(x, e_out, w_s, lst_s, deg_s, col, ss_s, gam_s, N);
  k_gatherw<<<(N + 3) / 4, 256, 0, stream>>>(x, e_out, w_r, lst_r, deg_r, row, ss_r, gam_r, N);
  k_node2<<<gN, 256, 0, stream>>>(x, ss_s, ss_r, gam_s, gam_r, u, Wn, bn,
                                  Ms, cs, Mr, cr, nbat, x_out, N);
  k_segsum<<<(N + 1023) / 1024, 256, 0, stream>>>(x_out, nbat, nagg, N);
  k_glob<<<(G * 64 + 63) / 64, 64, 0, stream>>>(u, nagg, eagg, Wg, bg, u_out, G);
}

// Round 5
// 1599.475 us; speedup vs baseline: 3.7402x; 1.2213x over previous
//
#include <hip/hip_runtime.h>

#define DD 64

__device__ __forceinline__ float4 ld4(const float* p) {
  return *reinterpret_cast<const float4*>(p);
}

__device__ __forceinline__ float rdlanef(float v, int l) {
  return __uint_as_float(__builtin_amdgcn_readlane(__float_as_uint(v), l));
}

// acc[64] += W[o*ldw + 0..LEN-1] . src[0..LEN-1]; W wave-uniform (scalar loads),
// src per-lane global pointer (float4 loads). acc statically indexed.
template <int LEN>
__device__ __forceinline__ void gemv_g(float* acc, const float* __restrict__ src,
                                       const float* __restrict__ W, const int ldw) {
  #pragma unroll 1
  for (int ic = 0; ic < LEN; ic += 8) {
    const float4 a = ld4(src + ic);
    const float4 b = ld4(src + ic + 4);
    #pragma unroll
    for (int o = 0; o < DD; ++o) {
      const float* wr = W + o * ldw + ic;
      float t = acc[o];
      t = fmaf(a.x, wr[0], t); t = fmaf(a.y, wr[1], t);
      t = fmaf(a.z, wr[2], t); t = fmaf(a.w, wr[3], t);
      t = fmaf(b.x, wr[4], t); t = fmaf(b.y, wr[5], t);
      t = fmaf(b.z, wr[6], t);
      acc[o] = fmaf(b.w, wr[7], t);
    }
  }
}

// ---- build padded CSR (both directions), MAXDEG=64 ----
__global__ void __launch_bounds__(256) k_fill(
    const int* __restrict__ row, const int* __restrict__ col,
    int* __restrict__ deg_s, int* __restrict__ deg_r,
    int* __restrict__ lst_s, int* __restrict__ lst_r, int E) {
  int e = blockIdx.x * 256 + threadIdx.x;
  if (e >= E) return;
  int r = row[e], c = col[e];
  int s0 = atomicAdd(deg_s + r, 1);
  if (s0 < 64) lst_s[(size_t)r * 64 + s0] = e;
  int s1 = atomicAdd(deg_r + c, 1);
  if (s1 < 64) lst_r[(size_t)c * 64 + s1] = e;
}

// ---- per-node precompute: px1=Wx1.x, px2=Wx2.x, hq=W1q.x, hkv=W1kv.x; pu=Wu.u ----
__global__ void __launch_bounds__(256, 2) k_nodepre(
    const float* __restrict__ x, const float* __restrict__ u,
    const float* __restrict__ We, const float* __restrict__ W1,
    float* __restrict__ px1, float* __restrict__ px2,
    float* __restrict__ hq, float* __restrict__ hkv, float* __restrict__ pu,
    int N, int G) {
  int n = blockIdx.x * 256 + threadIdx.x;
  if (n >= N) return;
  const float* xr = x + (size_t)n * DD;
  float acc[DD];
  #pragma unroll
  for (int o = 0; o < DD; ++o) acc[o] = 0.f;
  gemv_g<64>(acc, xr, We + 64, 256);
  #pragma unroll
  for (int o = 0; o < DD; o += 4) *reinterpret_cast<float4*>(px1 + (size_t)n * DD + o) = make_float4(acc[o], acc[o+1], acc[o+2], acc[o+3]);
  #pragma unroll
  for (int o = 0; o < DD; ++o) acc[o] = 0.f;
  gemv_g<64>(acc, xr, We + 128, 256);
  #pragma unroll
  for (int o = 0; o < DD; o += 4) *reinterpret_cast<float4*>(px2 + (size_t)n * DD + o) = make_float4(acc[o], acc[o+1], acc[o+2], acc[o+3]);
  #pragma unroll
  for (int o = 0; o < DD; ++o) acc[o] = 0.f;
  gemv_g<64>(acc, xr, W1 + 0, 192);
  #pragma unroll
  for (int o = 0; o < DD; o += 4) *reinterpret_cast<float4*>(hq + (size_t)n * DD + o) = make_float4(acc[o], acc[o+1], acc[o+2], acc[o+3]);
  #pragma unroll
  for (int o = 0; o < DD; ++o) acc[o] = 0.f;
  gemv_g<64>(acc, xr, W1 + 64, 192);
  #pragma unroll
  for (int o = 0; o < DD; o += 4) *reinterpret_cast<float4*>(hkv + (size_t)n * DD + o) = make_float4(acc[o], acc[o+1], acc[o+2], acc[o+3]);
  if (n < G) {
    #pragma unroll
    for (int o = 0; o < DD; ++o) acc[o] = 0.f;
    gemv_g<64>(acc, u + (size_t)n * DD, We + 192, 256);
    #pragma unroll
    for (int o = 0; o < DD; o += 4) *reinterpret_cast<float4*>(pu + (size_t)n * DD + o) = make_float4(acc[o], acc[o+1], acc[o+2], acc[o+3]);
  }
}

// ---- precombine: Ms = Wn[:,64:128].W3, cs = Wn[:,64:128].b3; Mr/cr for 128:192 ----
__global__ void __launch_bounds__(128) k_precomb(
    const float* __restrict__ Wn, const float* __restrict__ W3, const float* __restrict__ b3,
    float* __restrict__ Ms, float* __restrict__ cs,
    float* __restrict__ Mr, float* __restrict__ cr) {
  int t = threadIdx.x;           // 128 threads: dir*64 + o
  int dir = t >> 6, o = t & 63;
  const float* wrow = Wn + (size_t)o * 256 + 64 + 64 * dir;
  float* M  = dir ? Mr : Ms;
  float* cv = dir ? cr : cs;
  if (blockIdx.x == 0) {
    float cb = 0.f;
    for (int k = 0; k < 64; ++k) cb = fmaf(wrow[k], b3[k], cb);
    cv[o] = cb;
  }
  int c0 = blockIdx.x * 16;
  for (int c = c0; c < c0 + 16; ++c) {
    float m = 0.f;
    for (int k = 0; k < 64; ++k) m = fmaf(wrow[k], W3[k * 128 + c], m);
    M[(size_t)o * 128 + c] = m;
  }
}

// ---- fused edge MLP + attention logits: lane=channel, wave=16-edge tile ----
// LDS holds the two 64x64 weight blocks TRANSPOSED (pad 65 -> conflict-free).
// Edge values broadcast via v_readlane; all row accesses coalesced.
__global__ void __launch_bounds__(256) k_edgeattn2(
    const float* __restrict__ ea,
    const float* __restrict__ px1, const float* __restrict__ px2, const float* __restrict__ pu,
    const float* __restrict__ hq, const float* __restrict__ hkv,
    const float* __restrict__ We, const float* __restrict__ be,
    const float* __restrict__ W1, const float* __restrict__ b1, const float* __restrict__ w2,
    const int* __restrict__ row, const int* __restrict__ col, const int* __restrict__ ebat,
    float* __restrict__ edge_out, float* __restrict__ w_s, float* __restrict__ w_r, int E) {
  __shared__ float WtE[64 * 65];   // WtE[k*65+o] = We[o][k]   (ea block)
  __shared__ float Wt1[64 * 65];   // Wt1[k*65+o] = W1[o][128+k] (en block)
  const int tid = threadIdx.x;
  for (int idx = tid; idx < 4096; idx += 256) {
    int o = idx >> 6, k = idx & 63;
    WtE[k * 65 + o] = We[o * 256 + k];
    Wt1[k * 65 + o] = W1[o * 192 + 128 + k];
  }
  __syncthreads();

  const int lane = tid & 63;
  const int wid = tid >> 6;
  const int nwaves = gridDim.x * 4;
  const float bev = be[lane], b1v = b1[lane], w2v = w2[lane];

  for (int e0 = (blockIdx.x * 4 + wid) * 16; e0 < E; e0 += nwaves * 16) {
    // per-edge indices live in lanes 0..15
    int r_l = 0, c_l = 0, g_l = 0;
    if (lane < 16) {
      int ee = e0 + lane; if (ee >= E) ee = E - 1;
      r_l = row[ee]; c_l = col[ee]; g_l = ebat[ee];
    }
    // ea tile: lane holds ea[e0 + (lane>>2)][(lane&3)*16 + j], j=0..15
    float va[16];
    {
      int eld = e0 + (lane >> 2); if (eld >= E) eld = E - 1;
      const float* base = ea + (size_t)eld * 64 + (lane & 3) * 16;
      float4 A = ld4(base), B = ld4(base + 4), C = ld4(base + 8), D = ld4(base + 12);
      va[0]=A.x; va[1]=A.y; va[2]=A.z; va[3]=A.w;
      va[4]=B.x; va[5]=B.y; va[6]=B.z; va[7]=B.w;
      va[8]=C.x; va[9]=C.y; va[10]=C.z; va[11]=C.w;
      va[12]=D.x; va[13]=D.y; va[14]=D.z; va[15]=D.w;
    }
    // GEMV1: en[ep] = be + We_ea . ea[e0+ep]   (lane = out channel)
    float en[16];
    #pragma unroll
    for (int ep = 0; ep < 16; ++ep) en[ep] = bev;
    #pragma unroll 1
    for (int kb = 0; kb < 64; kb += 16) {
      int srcq = kb >> 4;
      #pragma unroll
      for (int j = 0; j < 16; ++j) {
        float wk = WtE[(kb + j) * 65 + lane];
        #pragma unroll
        for (int ep = 0; ep < 16; ++ep)
          en[ep] = fmaf(rdlanef(va[j], ep * 4 + srcq), wk, en[ep]);
      }
    }
    // epilogue: + px1[r] + px2[c] + pu[g], relu, store edge_new
    #pragma unroll
    for (int ep = 0; ep < 16; ++ep) {
      int rr = __builtin_amdgcn_readlane(r_l, ep);
      int cc = __builtin_amdgcn_readlane(c_l, ep);
      int gg = __builtin_amdgcn_readlane(g_l, ep);
      float v = en[ep] + px1[(size_t)rr * 64 + lane] + px2[(size_t)cc * 64 + lane]
                       + pu[(size_t)gg * 64 + lane];
      v = fmaxf(v, 0.f);
      en[ep] = v;
      if (e0 + ep < E) edge_out[((size_t)e0 + ep) * 64 + lane] = v;
    }
    // GEMV2: t[ep] = b1 + W1en . en[ep]   (en broadcast from lanes)
    float t[16];
    #pragma unroll
    for (int ep = 0; ep < 16; ++ep) t[ep] = b1v;
    #pragma unroll 1
    for (int kb = 0; kb < 64; kb += 16) {
      #pragma unroll
      for (int j = 0; j < 16; ++j) {
        int k = kb + j;
        float wk = Wt1[k * 65 + lane];
        #pragma unroll
        for (int ep = 0; ep < 16; ++ep)
          t[ep] = fmaf(rdlanef(en[ep], k), wk, t[ep]);
      }
    }
    // logits: leaky(t + hq[q] + hkv[kv]) . w2, both directions; wave-reduce
    float wsk = 0.f, wrk = 0.f;
    #pragma unroll
    for (int ep = 0; ep < 16; ++ep) {
      int rr = __builtin_amdgcn_readlane(r_l, ep);
      int cc = __builtin_amdgcn_readlane(c_l, ep);
      float hq_r = hq[(size_t)rr * 64 + lane], hq_c = hq[(size_t)cc * 64 + lane];
      float hk_r = hkv[(size_t)rr * 64 + lane], hk_c = hkv[(size_t)cc * 64 + lane];
      float hs = t[ep] + hq_r + hk_c; hs = (hs >= 0.f) ? hs : 0.01f * hs;
      float hr = t[ep] + hq_c + hk_r; hr = (hr >= 0.f) ? hr : 0.01f * hr;
      float as = hs * w2v, ar = hr * w2v;
      #pragma unroll
      for (int d = 32; d; d >>= 1) {
        as += __shfl_xor(as, d, 64);
        ar += __shfl_xor(ar, d, 64);
      }
      wsk = (lane == ep) ? as : wsk;
      wrk = (lane == ep) ? ar : wrk;
    }
    if (lane < 16 && e0 + lane < E) { w_s[e0 + lane] = wsk; w_r[e0 + lane] = wrk; }
  }
}

// ---- wave-per-node gather: softmax over edge list, coalesced p-weighted row sums ----
__global__ void __launch_bounds__(256) k_gatherw(
    const float* __restrict__ x, const float* __restrict__ en, const float* __restrict__ w,
    const int* __restrict__ lst, const int* __restrict__ deg_a, const int* __restrict__ other_idx,
    float* __restrict__ ss, float* __restrict__ gam, int N) {
  int wid = threadIdx.x >> 6, lane = threadIdx.x & 63;
  int n = blockIdx.x * 4 + wid;
  if (n >= N) return;
  int deg = deg_a[n];
  deg = deg < 64 ? deg : 64;
  float* ssd = ss + (size_t)n * 128;
  if (deg == 0) {
    ssd[lane] = 0.f; ssd[64 + lane] = 0.f;
    if (lane == 0) gam[n] = 0.f;
    return;
  }
  int e = 0, oe = 0;
  float wv = -1e30f;
  if (lane < deg) {
    e = lst[(size_t)n * 64 + lane];
    oe = other_idx[e];
    wv = w[e];
  }
  float m = wv;
  #pragma unroll
  for (int d = 32; d; d >>= 1) m = fmaxf(m, __shfl_xor(m, d, 64));
  float p = (lane < deg) ? __expf(wv - m) : 0.f;
  float S = p;
  #pragma unroll
  for (int d = 32; d; d >>= 1) S += __shfl_xor(S, d, 64);
  float sx = 0.f, se = 0.f;
  for (int i = 0; i < deg; ++i) {
    float pi = __shfl(p, i, 64);
    int ei = __shfl(e, i, 64);
    int oi = __shfl(oe, i, 64);
    sx = fmaf(pi, x[(size_t)oi * DD + lane], sx);     // coalesced 256B row
    se = fmaf(pi, en[(size_t)ei * DD + lane], se);    // coalesced 256B row
  }
  float inv = 1.f / (S + 1e-16f);
  ssd[lane] = sx * inv;
  ssd[64 + lane] = se * inv;
  if (lane == 0) gam[n] = S * inv;
}

// ---- node MLP with folded attention-value matvecs ----
__global__ void __launch_bounds__(256, 2) k_node2(
    const float* __restrict__ x, const float* __restrict__ ss_s, const float* __restrict__ ss_r,
    const float* __restrict__ gam_s, const float* __restrict__ gam_r,
    const float* __restrict__ u,
    const float* __restrict__ Wn, const float* __restrict__ bn,
    const float* __restrict__ Ms, const float* __restrict__ cs,
    const float* __restrict__ Mr, const float* __restrict__ cr,
    const int* __restrict__ nbat, float* __restrict__ x_out, int N) {
  int n = blockIdx.x * 256 + threadIdx.x;
  if (n >= N) return;
  int g = nbat[n];
  float gs = gam_s[n], gr = gam_r[n];
  float acc[DD];
  #pragma unroll
  for (int o = 0; o < DD; ++o) acc[o] = fmaf(gs, cs[o], fmaf(gr, cr[o], bn[o]));
  gemv_g<64>(acc, x + (size_t)n * DD, Wn, 256);
  gemv_g<64>(acc, u + (size_t)g * DD, Wn + 192, 256);
  gemv_g<128>(acc, ss_s + (size_t)n * 128, Ms, 128);
  gemv_g<128>(acc, ss_r + (size_t)n * 128, Mr, 128);
  float* dst = x_out + (size_t)n * DD;
  #pragma unroll
  for (int o = 0; o < DD; o += 4) {
    float4 v;
    v.x = fmaxf(acc[o + 0], 0.f); v.y = fmaxf(acc[o + 1], 0.f);
    v.z = fmaxf(acc[o + 2], 0.f); v.w = fmaxf(acc[o + 3], 0.f);
    *reinterpret_cast<float4*>(dst + o) = v;
  }
}

// ---- segment-sum over sorted segment ids (run-length + atomic flush) ----
__global__ void __launch_bounds__(256) k_segsum(
    const float* __restrict__ vals, const int* __restrict__ seg,
    float* __restrict__ out, int n) {
  int d = threadIdx.x & 63;
  int grp = threadIdx.x >> 6;
  long base = (long)blockIdx.x * 1024 + (long)grp * 256;
  float sum = 0.f;
  int cur = -1;
  for (int k = 0; k < 256; ++k) {
    long e = base + k;
    if (e >= n) break;
    int gb = seg[e];
    float v = vals[e * DD + d];
    if (gb != cur) {
      if (cur >= 0) atomicAdd(out + (size_t)cur * DD + d, sum);
      cur = gb; sum = v;
    } else {
      sum += v;
    }
  }
  if (cur >= 0) atomicAdd(out + (size_t)cur * DD + d, sum);
}

// ---- global MLP ----
__global__ void __launch_bounds__(64) k_glob(
    const float* __restrict__ u, const float* __restrict__ nagg, const float* __restrict__ eagg,
    const float* __restrict__ Wg, const float* __restrict__ bg,
    float* __restrict__ u_out, int G) {
  int t = blockIdx.x * 64 + threadIdx.x;
  if (t >= G * 64) return;
  int g = t >> 6, o = t & 63;
  float acc = bg[o];
  const float* wr = Wg + (size_t)o * 192;
  for (int i = 0; i < 64; ++i) acc = fmaf(u[g * 64 + i],    wr[i],       acc);
  for (int i = 0; i < 64; ++i) acc = fmaf(nagg[g * 64 + i], wr[64 + i],  acc);
  for (int i = 0; i < 64; ++i) acc = fmaf(eagg[g * 64 + i], wr[128 + i], acc);
  u_out[t] = fmaxf(acc, 0.f);
}

extern "C" void kernel_launch(void* const* d_in, const int* in_sizes, int n_in,
                              void* d_out, int out_size, void* d_ws, size_t ws_size,
                              hipStream_t stream) {
  const float* x   = (const float*)d_in[0];
  const float* ea  = (const float*)d_in[1];
  const float* u   = (const float*)d_in[2];
  const float* We  = (const float*)d_in[3];
  const float* be  = (const float*)d_in[4];
  const float* Wn  = (const float*)d_in[5];
  const float* bn  = (const float*)d_in[6];
  const float* Wg  = (const float*)d_in[7];
  const float* bg  = (const float*)d_in[8];
  const float* W1  = (const float*)d_in[9];
  const float* b1  = (const float*)d_in[10];
  const float* w2  = (const float*)d_in[11];
  const float* W3  = (const float*)d_in[12];
  const float* b3  = (const float*)d_in[13];
  const int* eidx  = (const int*)d_in[14];
  const int* nbat  = (const int*)d_in[15];
  const int* ebat  = (const int*)d_in[16];

  const int N = in_sizes[0] / 64;
  const int E = in_sizes[1] / 64;
  const int G = in_sizes[2] / 64;
  const int* row = eidx;
  const int* col = eidx + E;

  float* out   = (float*)d_out;
  float* x_out = out;
  float* e_out = out + (size_t)N * 64;
  float* u_out = out + (size_t)(N + E) * 64;

  // ---- workspace layout ----
  float* ws = (float*)d_ws;
  // region A (N*128): px1|px2 during edge phase; ss_s after
  float* px1 = ws;
  float* px2 = ws + (size_t)N * 64;
  float* ss_s = ws;
  // region B (N*128): hq|hkv during edge phase; ss_r after
  float* hq  = ws + (size_t)N * 128;
  float* hkv = hq + (size_t)N * 64;
  float* ss_r = hq;
  float* w_s = ws + (size_t)N * 256;            // E
  float* w_r = w_s + E;                         // E
  float* pu  = w_r + E;                         // G*64
  int* lst_s = (int*)(pu + (size_t)G * 64);     // N*64
  int* lst_r = lst_s + (size_t)N * 64;          // N*64
  int* deg_s = lst_r + (size_t)N * 64;          // N    (memset from here...)
  int* deg_r = deg_s + N;                       // N
  float* nagg = (float*)(deg_r + N);            // G*64
  float* eagg = nagg + (size_t)G * 64;          // G*64 (...to here)
  float* gam_s = eagg + (size_t)G * 64;         // N
  float* gam_r = gam_s + N;                     // N
  float* Ms = gam_r + N;                        // 64*128
  float* Mr = Ms + 64 * 128;                    // 64*128
  float* cs = Mr + 64 * 128;                    // 64
  float* cr = cs + 64;                          // 64

  hipMemsetAsync(deg_s, 0, (2 * (size_t)N + 2 * (size_t)G * 64) * sizeof(int), stream);

  const int gE = (E + 255) / 256;
  const int gN = (N + 255) / 256;

  k_fill<<<gE, 256, 0, stream>>>(row, col, deg_s, deg_r, lst_s, lst_r, E);
  k_nodepre<<<gN, 256, 0, stream>>>(x, u, We, W1, px1, px2, hq, hkv, pu, N, G);
  k_precomb<<<8, 128, 0, stream>>>(Wn, W3, b3, Ms, cs, Mr, cr);
  k_edgeattn2<<<1024, 256, 0, stream>>>(ea, px1, px2, pu, hq, hkv, We, be, W1, b1, w2,
                                        row, col, ebat, e_out, w_s, w_r, E);
  k_segsum<<<(E + 1023) / 1024, 256, 0, stream>>>(e_out, ebat, eagg, E);
  // gathers overwrite regions A/B (px/hq dead after k_edgeattn2)
  k_gatherw<<<(N + 3) / 4, 256, 0, stream>>>(x, e_out, w_s, lst_s, deg_s, col, ss_s, gam_s, N);
  k_gatherw<<<(N + 3) / 4, 256, 0, stream>>>(x, e_out, w_r, lst_r, deg_r, row, ss_r, gam_r, N);
  k_node2<<<gN, 256, 0, stream>>>(x, ss_s, ss_r, gam_s, gam_r, u, Wn, bn,
                                  Ms, cs, Mr, cr, nbat, x_out, N);
  k_segsum<<<(N + 1023) / 1024, 256, 0, stream>>>(x_out, nbat, nagg, N);
  k_glob<<<(G * 64 + 63) / 64, 64, 0, stream>>>(u, nagg, eagg, Wg, bg, u_out, G);
}

// Round 6
// 968.197 us; speedup vs baseline: 6.1789x; 1.6520x over previous
//
#include <hip/hip_runtime.h>

#define DD 64

__device__ __forceinline__ float4 ld4(const float* p) {
  return *reinterpret_cast<const float4*>(p);
}

__device__ __forceinline__ float rdlanef(float v, int l) {
  return __uint_as_float(__builtin_amdgcn_readlane(__float_as_uint(v), l));
}

// acc[OUT] += W[o*ldw + 0..LEN-1] . src[0..LEN-1]; W wave-uniform (scalar loads),
// src per-lane global pointer (float4 loads). acc statically indexed.
template <int LEN, int OUT>
__device__ __forceinline__ void gemv_go(float* acc, const float* __restrict__ src,
                                        const float* __restrict__ W, const int ldw) {
  #pragma unroll 1
  for (int ic = 0; ic < LEN; ic += 8) {
    const float4 a = ld4(src + ic);
    const float4 b = ld4(src + ic + 4);
    #pragma unroll
    for (int o = 0; o < OUT; ++o) {
      const float* wr = W + o * ldw + ic;
      float t = acc[o];
      t = fmaf(a.x, wr[0], t); t = fmaf(a.y, wr[1], t);
      t = fmaf(a.z, wr[2], t); t = fmaf(a.w, wr[3], t);
      t = fmaf(b.x, wr[4], t); t = fmaf(b.y, wr[5], t);
      t = fmaf(b.z, wr[6], t);
      acc[o] = fmaf(b.w, wr[7], t);
    }
  }
}

// ---- build padded CSR (both directions), MAXDEG=64 ----
__global__ void __launch_bounds__(256) k_fill(
    const int* __restrict__ row, const int* __restrict__ col,
    int* __restrict__ deg_s, int* __restrict__ deg_r,
    int* __restrict__ lst_s, int* __restrict__ lst_r, int E) {
  int e = blockIdx.x * 256 + threadIdx.x;
  if (e >= E) return;
  int r = row[e], c = col[e];
  int s0 = atomicAdd(deg_s + r, 1);
  if (s0 < 64) lst_s[(size_t)r * 64 + s0] = e;
  int s1 = atomicAdd(deg_r + c, 1);
  if (s1 < 64) lst_r[(size_t)c * 64 + s1] = e;
}

// ---- per-node precompute, split: blockIdx.y = {array 0..3} x {half 0..1} ----
// a=0: px1 = We[:,64:128].x   a=1: px2 = We[:,128:192].x
// a=2: hq  = W1[:,0:64].x     a=3: hkv = W1[:,64:128].x
// pu = We[:,192:256].u computed in a==0 blocks for n < G.
__global__ void __launch_bounds__(256) k_nodepre2(
    const float* __restrict__ x, const float* __restrict__ u,
    const float* __restrict__ We, const float* __restrict__ W1,
    float* __restrict__ px1, float* __restrict__ px2,
    float* __restrict__ hq, float* __restrict__ hkv, float* __restrict__ pu,
    int N, int G) {
  int n = blockIdx.x * 256 + threadIdx.x;
  if (n >= N) return;
  const int a = blockIdx.y >> 1, h = blockIdx.y & 1;
  const float* Wb;
  int ldw;
  float* dst;
  if (a == 0)      { Wb = We + 64  + h * 32 * 256; ldw = 256; dst = px1; }
  else if (a == 1) { Wb = We + 128 + h * 32 * 256; ldw = 256; dst = px2; }
  else if (a == 2) { Wb = W1 + 0   + h * 32 * 192; ldw = 192; dst = hq;  }
  else             { Wb = W1 + 64  + h * 32 * 192; ldw = 192; dst = hkv; }
  float acc[32];
  #pragma unroll
  for (int o = 0; o < 32; ++o) acc[o] = 0.f;
  gemv_go<64, 32>(acc, x + (size_t)n * DD, Wb, ldw);
  float* d = dst + (size_t)n * DD + h * 32;
  #pragma unroll
  for (int o = 0; o < 32; o += 4)
    *reinterpret_cast<float4*>(d + o) = make_float4(acc[o], acc[o+1], acc[o+2], acc[o+3]);
  if (a == 0 && n < G) {
    #pragma unroll
    for (int o = 0; o < 32; ++o) acc[o] = 0.f;
    gemv_go<64, 32>(acc, u + (size_t)n * DD, We + 192 + h * 32 * 256, 256);
    float* dp = pu + (size_t)n * DD + h * 32;
    #pragma unroll
    for (int o = 0; o < 32; o += 4)
      *reinterpret_cast<float4*>(dp + o) = make_float4(acc[o], acc[o+1], acc[o+2], acc[o+3]);
  }
}

// ---- precombine: Ms = Wn[:,64:128].W3, cs = Wn[:,64:128].b3; Mr/cr for 128:192 ----
__global__ void __launch_bounds__(128) k_precomb(
    const float* __restrict__ Wn, const float* __restrict__ W3, const float* __restrict__ b3,
    float* __restrict__ Ms, float* __restrict__ cs,
    float* __restrict__ Mr, float* __restrict__ cr) {
  int t = threadIdx.x;           // 128 threads: dir*64 + o
  int dir = t >> 6, o = t & 63;
  const float* wrow = Wn + (size_t)o * 256 + 64 + 64 * dir;
  float* M  = dir ? Mr : Ms;
  float* cv = dir ? cr : cs;
  if (blockIdx.x == 0) {
    float cb = 0.f;
    for (int k = 0; k < 64; ++k) cb = fmaf(wrow[k], b3[k], cb);
    cv[o] = cb;
  }
  int c0 = blockIdx.x * 16;
  for (int c = c0; c < c0 + 16; ++c) {
    float m = 0.f;
    for (int k = 0; k < 64; ++k) m = fmaf(wrow[k], W3[k * 128 + c], m);
    M[(size_t)o * 128 + c] = m;
  }
}

// ---- fused edge MLP + attention logits: lane=channel, wave=16-edge tile ----
__global__ void __launch_bounds__(256) k_edgeattn2(
    const float* __restrict__ ea,
    const float* __restrict__ px1, const float* __restrict__ px2, const float* __restrict__ pu,
    const float* __restrict__ hq, const float* __restrict__ hkv,
    const float* __restrict__ We, const float* __restrict__ be,
    const float* __restrict__ W1, const float* __restrict__ b1, const float* __restrict__ w2,
    const int* __restrict__ row, const int* __restrict__ col, const int* __restrict__ ebat,
    float* __restrict__ edge_out, float* __restrict__ w_s, float* __restrict__ w_r, int E) {
  __shared__ float WtE[64 * 65];   // WtE[k*65+o] = We[o][k]   (ea block)
  __shared__ float Wt1[64 * 65];   // Wt1[k*65+o] = W1[o][128+k] (en block)
  const int tid = threadIdx.x;
  for (int idx = tid; idx < 4096; idx += 256) {
    int o = idx >> 6, k = idx & 63;
    WtE[k * 65 + o] = We[o * 256 + k];
    Wt1[k * 65 + o] = W1[o * 192 + 128 + k];
  }
  __syncthreads();

  const int lane = tid & 63;
  const int wid = tid >> 6;
  const int nwaves = gridDim.x * 4;
  const float bev = be[lane], b1v = b1[lane], w2v = w2[lane];

  for (int e0 = (blockIdx.x * 4 + wid) * 16; e0 < E; e0 += nwaves * 16) {
    int r_l = 0, c_l = 0, g_l = 0;
    if (lane < 16) {
      int ee = e0 + lane; if (ee >= E) ee = E - 1;
      r_l = row[ee]; c_l = col[ee]; g_l = ebat[ee];
    }
    float va[16];
    {
      int eld = e0 + (lane >> 2); if (eld >= E) eld = E - 1;
      const float* base = ea + (size_t)eld * 64 + (lane & 3) * 16;
      float4 A = ld4(base), B = ld4(base + 4), C = ld4(base + 8), D = ld4(base + 12);
      va[0]=A.x; va[1]=A.y; va[2]=A.z; va[3]=A.w;
      va[4]=B.x; va[5]=B.y; va[6]=B.z; va[7]=B.w;
      va[8]=C.x; va[9]=C.y; va[10]=C.z; va[11]=C.w;
      va[12]=D.x; va[13]=D.y; va[14]=D.z; va[15]=D.w;
    }
    float en[16];
    #pragma unroll
    for (int ep = 0; ep < 16; ++ep) en[ep] = bev;
    #pragma unroll 1
    for (int kb = 0; kb < 64; kb += 16) {
      int srcq = kb >> 4;
      #pragma unroll
      for (int j = 0; j < 16; ++j) {
        float wk = WtE[(kb + j) * 65 + lane];
        #pragma unroll
        for (int ep = 0; ep < 16; ++ep)
          en[ep] = fmaf(rdlanef(va[j], ep * 4 + srcq), wk, en[ep]);
      }
    }
    #pragma unroll
    for (int ep = 0; ep < 16; ++ep) {
      int rr = __builtin_amdgcn_readlane(r_l, ep);
      int cc = __builtin_amdgcn_readlane(c_l, ep);
      int gg = __builtin_amdgcn_readlane(g_l, ep);
      float v = en[ep] + px1[(size_t)rr * 64 + lane] + px2[(size_t)cc * 64 + lane]
                       + pu[(size_t)gg * 64 + lane];
      v = fmaxf(v, 0.f);
      en[ep] = v;
      if (e0 + ep < E) edge_out[((size_t)e0 + ep) * 64 + lane] = v;
    }
    float t[16];
    #pragma unroll
    for (int ep = 0; ep < 16; ++ep) t[ep] = b1v;
    #pragma unroll 1
    for (int kb = 0; kb < 64; kb += 16) {
      #pragma unroll
      for (int j = 0; j < 16; ++j) {
        int k = kb + j;
        float wk = Wt1[k * 65 + lane];
        #pragma unroll
        for (int ep = 0; ep < 16; ++ep)
          t[ep] = fmaf(rdlanef(en[ep], k), wk, t[ep]);
      }
    }
    float wsk = 0.f, wrk = 0.f;
    #pragma unroll
    for (int ep = 0; ep < 16; ++ep) {
      int rr = __builtin_amdgcn_readlane(r_l, ep);
      int cc = __builtin_amdgcn_readlane(c_l, ep);
      float hq_r = hq[(size_t)rr * 64 + lane], hq_c = hq[(size_t)cc * 64 + lane];
      float hk_r = hkv[(size_t)rr * 64 + lane], hk_c = hkv[(size_t)cc * 64 + lane];
      float hs = t[ep] + hq_r + hk_c; hs = (hs >= 0.f) ? hs : 0.01f * hs;
      float hr = t[ep] + hq_c + hk_r; hr = (hr >= 0.f) ? hr : 0.01f * hr;
      float as = hs * w2v, ar = hr * w2v;
      #pragma unroll
      for (int d = 32; d; d >>= 1) {
        as += __shfl_xor(as, d, 64);
        ar += __shfl_xor(ar, d, 64);
      }
      wsk = (lane == ep) ? as : wsk;
      wrk = (lane == ep) ? ar : wrk;
    }
    if (lane < 16 && e0 + lane < E) { w_s[e0 + lane] = wsk; w_r[e0 + lane] = wrk; }
  }
}

// ---- wave-per-node gather: softmax over edge list, coalesced p-weighted row sums ----
__global__ void __launch_bounds__(256) k_gatherw(
    const float* __restrict__ x, const float* __restrict__ en, const float* __restrict__ w,
    const int* __restrict__ lst, const int* __restrict__ deg_a, const int* __restrict__ other_idx,
    float* __restrict__ ss, float* __restrict__ gam, int N) {
  int wid = threadIdx.x >> 6, lane = threadIdx.x & 63;
  int n = blockIdx.x * 4 + wid;
  if (n >= N) return;
  int deg = deg_a[n];
  deg = deg < 64 ? deg : 64;
  float* ssd = ss + (size_t)n * 128;
  if (deg == 0) {
    ssd[lane] = 0.f; ssd[64 + lane] = 0.f;
    if (lane == 0) gam[n] = 0.f;
    return;
  }
  int e = 0, oe = 0;
  float wv = -1e30f;
  if (lane < deg) {
    e = lst[(size_t)n * 64 + lane];
    oe = other_idx[e];
    wv = w[e];
  }
  float m = wv;
  #pragma unroll
  for (int d = 32; d; d >>= 1) m = fmaxf(m, __shfl_xor(m, d, 64));
  float p = (lane < deg) ? __expf(wv - m) : 0.f;
  float S = p;
  #pragma unroll
  for (int d = 32; d; d >>= 1) S += __shfl_xor(S, d, 64);
  float sx = 0.f, se = 0.f;
  for (int i = 0; i < deg; ++i) {
    float pi = __shfl(p, i, 64);
    int ei = __shfl(e, i, 64);
    int oi = __shfl(oe, i, 64);
    sx = fmaf(pi, x[(size_t)oi * DD + lane], sx);     // coalesced 256B row
    se = fmaf(pi, en[(size_t)ei * DD + lane], se);    // coalesced 256B row
  }
  float inv = 1.f / (S + 1e-16f);
  ssd[lane] = sx * inv;
  ssd[64 + lane] = se * inv;
  if (lane == 0) gam[n] = S * inv;
}

// ---- node MLP, quarter-split: blockIdx.y = output quarter (16 channels) ----
__global__ void __launch_bounds__(256) k_node2v(
    const float* __restrict__ x, const float* __restrict__ ss_s, const float* __restrict__ ss_r,
    const float* __restrict__ gam_s, const float* __restrict__ gam_r,
    const float* __restrict__ u,
    const float* __restrict__ Wn, const float* __restrict__ bn,
    const float* __restrict__ Ms, const float* __restrict__ cs,
    const float* __restrict__ Mr, const float* __restrict__ cr,
    const int* __restrict__ nbat, float* __restrict__ x_out, int N) {
  int n = blockIdx.x * 256 + threadIdx.x;
  if (n >= N) return;
  const int o0 = blockIdx.y * 16;
  int g = nbat[n];
  float gs = gam_s[n], gr = gam_r[n];
  float acc[16];
  #pragma unroll
  for (int j = 0; j < 16; ++j)
    acc[j] = fmaf(gs, cs[o0 + j], fmaf(gr, cr[o0 + j], bn[o0 + j]));
  gemv_go<64, 16>(acc, x + (size_t)n * DD, Wn + (size_t)o0 * 256, 256);
  gemv_go<64, 16>(acc, u + (size_t)g * DD, Wn + (size_t)o0 * 256 + 192, 256);
  gemv_go<128, 16>(acc, ss_s + (size_t)n * 128, Ms + (size_t)o0 * 128, 128);
  gemv_go<128, 16>(acc, ss_r + (size_t)n * 128, Mr + (size_t)o0 * 128, 128);
  float* dst = x_out + (size_t)n * DD + o0;
  #pragma unroll
  for (int j = 0; j < 16; j += 4) {
    float4 v;
    v.x = fmaxf(acc[j + 0], 0.f); v.y = fmaxf(acc[j + 1], 0.f);
    v.z = fmaxf(acc[j + 2], 0.f); v.w = fmaxf(acc[j + 3], 0.f);
    *reinterpret_cast<float4*>(dst + j) = v;
  }
}

// ---- segment-sum over sorted segment ids (run-length + atomic flush) ----
__global__ void __launch_bounds__(256) k_segsum(
    const float* __restrict__ vals, const int* __restrict__ seg,
    float* __restrict__ out, int n) {
  int d = threadIdx.x & 63;
  int grp = threadIdx.x >> 6;
  long base = (long)blockIdx.x * 1024 + (long)grp * 256;
  float sum = 0.f;
  int cur = -1;
  for (int k = 0; k < 256; ++k) {
    long e = base + k;
    if (e >= n) break;
    int gb = seg[e];
    float v = vals[e * DD + d];
    if (gb != cur) {
      if (cur >= 0) atomicAdd(out + (size_t)cur * DD + d, sum);
      cur = gb; sum = v;
    } else {
      sum += v;
    }
  }
  if (cur >= 0) atomicAdd(out + (size_t)cur * DD + d, sum);
}

// ---- global MLP ----
__global__ void __launch_bounds__(64) k_glob(
    const float* __restrict__ u, const float* __restrict__ nagg, const float* __restrict__ eagg,
    const float* __restrict__ Wg, const float* __restrict__ bg,
    float* __restrict__ u_out, int G) {
  int t = blockIdx.x * 64 + threadIdx.x;
  if (t >= G * 64) return;
  int g = t >> 6, o = t & 63;
  float acc = bg[o];
  const float* wr = Wg + (size_t)o * 192;
  for (int i = 0; i < 64; ++i) acc = fmaf(u[g * 64 + i],    wr[i],       acc);
  for (int i = 0; i < 64; ++i) acc = fmaf(nagg[g * 64 + i], wr[64 + i],  acc);
  for (int i = 0; i < 64; ++i) acc = fmaf(eagg[g * 64 + i], wr[128 + i], acc);
  u_out[t] = fmaxf(acc, 0.f);
}

extern "C" void kernel_launch(void* const* d_in, const int* in_sizes, int n_in,
                              void* d_out, int out_size, void* d_ws, size_t ws_size,
                              hipStream_t stream) {
  const float* x   = (const float*)d_in[0];
  const float* ea  = (const float*)d_in[1];
  const float* u   = (const float*)d_in[2];
  const float* We  = (const float*)d_in[3];
  const float* be  = (const float*)d_in[4];
  const float* Wn  = (const float*)d_in[5];
  const float* bn  = (const float*)d_in[6];
  const float* Wg  = (const float*)d_in[7];
  const float* bg  = (const float*)d_in[8];
  const float* W1  = (const float*)d_in[9];
  const float* b1  = (const float*)d_in[10];
  const float* w2  = (const float*)d_in[11];
  const float* W3  = (const float*)d_in[12];
  const float* b3  = (const float*)d_in[13];
  const int* eidx  = (const int*)d_in[14];
  const int* nbat  = (const int*)d_in[15];
  const int* ebat  = (const int*)d_in[16];

  const int N = in_sizes[0] / 64;
  const int E = in_sizes[1] / 64;
  const int G = in_sizes[2] / 64;
  const int* row = eidx;
  const int* col = eidx + E;

  float* out   = (float*)d_out;
  float* x_out = out;
  float* e_out = out + (size_t)N * 64;
  float* u_out = out + (size_t)(N + E) * 64;

  // ---- workspace layout ----
  float* ws = (float*)d_ws;
  float* px1 = ws;
  float* px2 = ws + (size_t)N * 64;
  float* ss_s = ws;
  float* hq  = ws + (size_t)N * 128;
  float* hkv = hq + (size_t)N * 64;
  float* ss_r = hq;
  float* w_s = ws + (size_t)N * 256;            // E
  float* w_r = w_s + E;                         // E
  float* pu  = w_r + E;                         // G*64
  int* lst_s = (int*)(pu + (size_t)G * 64);     // N*64
  int* lst_r = lst_s + (size_t)N * 64;          // N*64
  int* deg_s = lst_r + (size_t)N * 64;          // N    (memset from here...)
  int* deg_r = deg_s + N;                       // N
  float* nagg = (float*)(deg_r + N);            // G*64
  float* eagg = nagg + (size_t)G * 64;          // G*64 (...to here)
  float* gam_s = eagg + (size_t)G * 64;         // N
  float* gam_r = gam_s + N;                     // N
  float* Ms = gam_r + N;                        // 64*128
  float* Mr = Ms + 64 * 128;                    // 64*128
  float* cs = Mr + 64 * 128;                    // 64
  float* cr = cs + 64;                          // 64

  hipMemsetAsync(deg_s, 0, (2 * (size_t)N + 2 * (size_t)G * 64) * sizeof(int), stream);

  const int gE = (E + 255) / 256;
  const int gN = (N + 255) / 256;

  k_fill<<<gE, 256, 0, stream>>>(row, col, deg_s, deg_r, lst_s, lst_r, E);
  k_nodepre2<<<dim3(gN, 8), 256, 0, stream>>>(x, u, We, W1, px1, px2, hq, hkv, pu, N, G);
  k_precomb<<<8, 128, 0, stream>>>(Wn, W3, b3, Ms, cs, Mr, cr);
  k_edgeattn2<<<1024, 256, 0, stream>>>(ea, px1, px2, pu, hq, hkv, We, be, W1, b1, w2,
                                        row, col, ebat, e_out, w_s, w_r, E);
  k_segsum<<<(E + 1023) / 1024, 256, 0, stream>>>(e_out, ebat, eagg, E);
  // gathers overwrite regions A/B (px/hq dead after k_edgeattn2)
  k_gatherw<<<(N + 3) / 4, 256, 0, stream>>>(x, e_out, w_s, lst_s, deg_s, col, ss_s, gam_s, N);
  k_gatherw<<<(N + 3) / 4, 256, 0, stream>>>(x, e_out, w_r, lst_r, deg_r, row, ss_r, gam_r, N);
  k_node2v<<<dim3(gN, 4), 256, 0, stream>>>(x, ss_s, ss_r, gam_s, gam_r, u, Wn, bn,
                                            Ms, cs, Mr, cr, nbat, x_out, N);
  k_segsum<<<(N + 1023) / 1024, 256, 0, stream>>>(x_out, nbat, nagg, N);
  k_glob<<<(G * 64 + 63) / 64, 64, 0, stream>>>(u, nagg, eagg, Wg, bg, u_out, G);
}

// Round 7
// 823.446 us; speedup vs baseline: 7.2651x; 1.1758x over previous
//
#include <hip/hip_runtime.h>

#define DD 64

typedef __attribute__((ext_vector_type(8))) short bf16x8;   // 8 bf16 = 4 VGPRs
typedef __attribute__((ext_vector_type(4))) float f32x4;

#define MFMA16(A, B, C) __builtin_amdgcn_mfma_f32_16x16x32_bf16(A, B, C, 0, 0, 0)

__device__ __forceinline__ float4 ld4(const float* p) {
  return *reinterpret_cast<const float4*>(p);
}

__device__ __forceinline__ unsigned short f2bf(float f) {
  unsigned u = __float_as_uint(f);
  unsigned r = u + 0x7FFFu + ((u >> 16) & 1u);   // RNE
  return (unsigned short)(r >> 16);
}

__device__ __forceinline__ bf16x8 cvt8(float4 a, float4 b) {
  bf16x8 v;
  v[0] = (short)f2bf(a.x); v[1] = (short)f2bf(a.y);
  v[2] = (short)f2bf(a.z); v[3] = (short)f2bf(a.w);
  v[4] = (short)f2bf(b.x); v[5] = (short)f2bf(b.y);
  v[6] = (short)f2bf(b.z); v[7] = (short)f2bf(b.w);
  return v;
}

// acc[OUT] += W[o*ldw + 0..LEN-1] . src[0..LEN-1]; W wave-uniform (scalar loads).
template <int LEN, int OUT>
__device__ __forceinline__ void gemv_go(float* acc, const float* __restrict__ src,
                                        const float* __restrict__ W, const int ldw) {
  #pragma unroll 1
  for (int ic = 0; ic < LEN; ic += 8) {
    const float4 a = ld4(src + ic);
    const float4 b = ld4(src + ic + 4);
    #pragma unroll
    for (int o = 0; o < OUT; ++o) {
      const float* wr = W + o * ldw + ic;
      float t = acc[o];
      t = fmaf(a.x, wr[0], t); t = fmaf(a.y, wr[1], t);
      t = fmaf(a.z, wr[2], t); t = fmaf(a.w, wr[3], t);
      t = fmaf(b.x, wr[4], t); t = fmaf(b.y, wr[5], t);
      t = fmaf(b.z, wr[6], t);
      acc[o] = fmaf(b.w, wr[7], t);
    }
  }
}

// ---- build padded CSR (both directions), MAXDEG=64 ----
__global__ void __launch_bounds__(256) k_fill(
    const int* __restrict__ row, const int* __restrict__ col,
    int* __restrict__ deg_s, int* __restrict__ deg_r,
    int* __restrict__ lst_s, int* __restrict__ lst_r, int E) {
  int e = blockIdx.x * 256 + threadIdx.x;
  if (e >= E) return;
  int r = row[e], c = col[e];
  int s0 = atomicAdd(deg_s + r, 1);
  if (s0 < 64) lst_s[(size_t)r * 64 + s0] = e;
  int s1 = atomicAdd(deg_r + c, 1);
  if (s1 < 64) lst_r[(size_t)c * 64 + s1] = e;
}

// ---- per-node precompute, split: blockIdx.y = {array 0..3} x {half 0..1} ----
__global__ void __launch_bounds__(256) k_nodepre2(
    const float* __restrict__ x, const float* __restrict__ u,
    const float* __restrict__ We, const float* __restrict__ W1,
    float* __restrict__ px1, float* __restrict__ px2,
    float* __restrict__ hq, float* __restrict__ hkv, float* __restrict__ pu,
    int N, int G) {
  int n = blockIdx.x * 256 + threadIdx.x;
  if (n >= N) return;
  const int a = blockIdx.y >> 1, h = blockIdx.y & 1;
  const float* Wb;
  int ldw;
  float* dst;
  if (a == 0)      { Wb = We + 64  + h * 32 * 256; ldw = 256; dst = px1; }
  else if (a == 1) { Wb = We + 128 + h * 32 * 256; ldw = 256; dst = px2; }
  else if (a == 2) { Wb = W1 + 0   + h * 32 * 192; ldw = 192; dst = hq;  }
  else             { Wb = W1 + 64  + h * 32 * 192; ldw = 192; dst = hkv; }
  float acc[32];
  #pragma unroll
  for (int o = 0; o < 32; ++o) acc[o] = 0.f;
  gemv_go<64, 32>(acc, x + (size_t)n * DD, Wb, ldw);
  float* d = dst + (size_t)n * DD + h * 32;
  #pragma unroll
  for (int o = 0; o < 32; o += 4)
    *reinterpret_cast<float4*>(d + o) = make_float4(acc[o], acc[o+1], acc[o+2], acc[o+3]);
  if (a == 0 && n < G) {
    #pragma unroll
    for (int o = 0; o < 32; ++o) acc[o] = 0.f;
    gemv_go<64, 32>(acc, u + (size_t)n * DD, We + 192 + h * 32 * 256, 256);
    float* dp = pu + (size_t)n * DD + h * 32;
    #pragma unroll
    for (int o = 0; o < 32; o += 4)
      *reinterpret_cast<float4*>(dp + o) = make_float4(acc[o], acc[o+1], acc[o+2], acc[o+3]);
  }
}

// ---- precombine: Ms = Wn[:,64:128].W3, cs = Wn[:,64:128].b3; Mr/cr for 128:192 ----
__global__ void __launch_bounds__(128) k_precomb(
    const float* __restrict__ Wn, const float* __restrict__ W3, const float* __restrict__ b3,
    float* __restrict__ Ms, float* __restrict__ cs,
    float* __restrict__ Mr, float* __restrict__ cr) {
  int t = threadIdx.x;
  int dir = t >> 6, o = t & 63;
  const float* wrow = Wn + (size_t)o * 256 + 64 + 64 * dir;
  float* M  = dir ? Mr : Ms;
  float* cv = dir ? cr : cs;
  if (blockIdx.x == 0) {
    float cb = 0.f;
    for (int k = 0; k < 64; ++k) cb = fmaf(wrow[k], b3[k], cb);
    cv[o] = cb;
  }
  int c0 = blockIdx.x * 16;
  for (int c = c0; c < c0 + 16; ++c) {
    float m = 0.f;
    for (int k = 0; k < 64; ++k) m = fmaf(wrow[k], W3[k * 128 + c], m);
    M[(size_t)o * 128 + c] = m;
  }
}

// ---- MFMA fused edge MLP + attention logits: wave = 16 edges ----
// GEMM1: en(16x64) = ea(16x64) . We_ea^T  via 4 n-tiles x 2 k-steps MFMA.
// Epilogue1 adds px/pu gathers + relu, stores edge_new, packs bf16 -> LDS (swizzled).
// GEMM2: t(16x64) = en . W1en^T (A-frags re-read from LDS).
// Epilogue2: logits both directions, 16-lane shfl reduce.
__global__ void __launch_bounds__(256, 2) k_edgeattn3(
    const float* __restrict__ ea,
    const float* __restrict__ px1, const float* __restrict__ px2, const float* __restrict__ pu,
    const float* __restrict__ hq, const float* __restrict__ hkv,
    const float* __restrict__ We, const float* __restrict__ be,
    const float* __restrict__ W1, const float* __restrict__ b1, const float* __restrict__ w2,
    const int* __restrict__ row, const int* __restrict__ col, const int* __restrict__ ebat,
    float* __restrict__ edge_out, float* __restrict__ w_s, float* __restrict__ w_r, int E) {
  __shared__ unsigned short enl_all[4][16 * 64];  // per-wave 2KB bf16 tile, swizzled
  const int tid = threadIdx.x, lane = tid & 63, wid = tid >> 6;
  const int l15 = lane & 15, lg = lane >> 4;

  // ---- register-resident weight B-frags: B[k][n] = W[n][k]; lane: n=l15+nt*16, k=ks*32+lg*8+j ----
  bf16x8 B1[4][2], B2[4][2];
  #pragma unroll
  for (int nt = 0; nt < 4; ++nt) {
    #pragma unroll
    for (int ks = 0; ks < 2; ++ks) {
      const float* s1 = We + (size_t)(nt * 16 + l15) * 256 + ks * 32 + lg * 8;
      B1[nt][ks] = cvt8(ld4(s1), ld4(s1 + 4));
      const float* s2 = W1 + (size_t)(nt * 16 + l15) * 192 + 128 + ks * 32 + lg * 8;
      B2[nt][ks] = cvt8(ld4(s2), ld4(s2 + 4));
    }
  }
  float be_l[4], b1_l[4], w2_l[4];
  #pragma unroll
  for (int nt = 0; nt < 4; ++nt) {
    be_l[nt] = be[nt * 16 + l15];
    b1_l[nt] = b1[nt * 16 + l15];
    w2_l[nt] = w2[nt * 16 + l15];
  }
  unsigned short* enl = enl_all[wid];
  const int nwaves = gridDim.x * 4;
  const int swz_r = (l15 & 7) << 4;

  for (int e0 = (blockIdx.x * 4 + wid) * 16; e0 < E; e0 += nwaves * 16) {
    // per-group edge indices (edges lg*4 .. lg*4+3)
    int rj[4], cj[4], gj[4];
    if (e0 + 16 <= E) {
      int4 r4 = *(const int4*)(row + e0 + lg * 4);
      int4 c4 = *(const int4*)(col + e0 + lg * 4);
      int4 g4 = *(const int4*)(ebat + e0 + lg * 4);
      rj[0]=r4.x; rj[1]=r4.y; rj[2]=r4.z; rj[3]=r4.w;
      cj[0]=c4.x; cj[1]=c4.y; cj[2]=c4.z; cj[3]=c4.w;
      gj[0]=g4.x; gj[1]=g4.y; gj[2]=g4.z; gj[3]=g4.w;
    } else {
      #pragma unroll
      for (int j = 0; j < 4; ++j) {
        int ee = e0 + lg * 4 + j; if (ee >= E) ee = E - 1;
        rj[j] = row[ee]; cj[j] = col[ee]; gj[j] = ebat[ee];
      }
    }

    // ---- A1-frags from ea: lane = row l15, k = ks*32 + lg*8 + j ----
    int erow = e0 + l15; if (erow >= E) erow = E - 1;
    const float* arow = ea + (size_t)erow * 64;
    bf16x8 A1[2];
    #pragma unroll
    for (int ks = 0; ks < 2; ++ks) {
      const float* s = arow + ks * 32 + lg * 8;
      A1[ks] = cvt8(ld4(s), ld4(s + 4));
    }

    // ---- GEMM1 ----
    f32x4 acc[4];
    #pragma unroll
    for (int nt = 0; nt < 4; ++nt) acc[nt] = (f32x4){0.f, 0.f, 0.f, 0.f};
    #pragma unroll
    for (int nt = 0; nt < 4; ++nt) {
      acc[nt] = MFMA16(A1[0], B1[nt][0], acc[nt]);
      acc[nt] = MFMA16(A1[1], B1[nt][1], acc[nt]);
    }

    // ---- epilogue1: +bias +px1[r]+px2[c]+pu[g], relu, store, pack bf16->LDS ----
    #pragma unroll
    for (int j = 0; j < 4; ++j) {
      const int m = lg * 4 + j;
      const float* p1 = px1 + (size_t)rj[j] * 64 + l15;
      const float* p2 = px2 + (size_t)cj[j] * 64 + l15;
      const float* p3 = pu  + (size_t)gj[j] * 64 + l15;
      const bool st = (e0 + m) < E;
      float* eo = edge_out + (size_t)(e0 + m) * 64 + l15;
      const int rbase = m * 128, sw = (m & 7) << 4;
      #pragma unroll
      for (int nt = 0; nt < 4; ++nt) {
        float v = acc[nt][j] + be_l[nt] + p1[nt * 16] + p2[nt * 16] + p3[nt * 16];
        v = fmaxf(v, 0.f);
        if (st) eo[nt * 16] = v;
        int byte = rbase + ((nt * 32 + l15 * 2) ^ sw);
        *(unsigned short*)((char*)enl + byte) = f2bf(v);
      }
    }

    // ---- A2-frags from LDS (swizzled read, row = l15) ----
    asm volatile("s_waitcnt lgkmcnt(0)" ::: "memory");
    bf16x8 A2[2];
    #pragma unroll
    for (int ks = 0; ks < 2; ++ks) {
      int byte = l15 * 128 + (((ks * 64) + lg * 16) ^ swz_r);
      A2[ks] = *(const bf16x8*)((const char*)enl + byte);
    }

    // ---- GEMM2 ----
    f32x4 tac[4];
    #pragma unroll
    for (int nt = 0; nt < 4; ++nt) tac[nt] = (f32x4){0.f, 0.f, 0.f, 0.f};
    #pragma unroll
    for (int nt = 0; nt < 4; ++nt) {
      tac[nt] = MFMA16(A2[0], B2[nt][0], tac[nt]);
      tac[nt] = MFMA16(A2[1], B2[nt][1], tac[nt]);
    }

    // ---- epilogue2: logits for both directions ----
    float as4[4] = {0.f, 0.f, 0.f, 0.f}, ar4[4] = {0.f, 0.f, 0.f, 0.f};
    #pragma unroll
    for (int j = 0; j < 4; ++j) {
      const float* hqr = hq  + (size_t)rj[j] * 64 + l15;
      const float* hqc = hq  + (size_t)cj[j] * 64 + l15;
      const float* hkr = hkv + (size_t)rj[j] * 64 + l15;
      const float* hkc = hkv + (size_t)cj[j] * 64 + l15;
      #pragma unroll
      for (int nt = 0; nt < 4; ++nt) {
        float tt = tac[nt][j] + b1_l[nt];
        float hs = tt + hqr[nt * 16] + hkc[nt * 16]; hs = (hs >= 0.f) ? hs : 0.01f * hs;
        float hr = tt + hqc[nt * 16] + hkr[nt * 16]; hr = (hr >= 0.f) ? hr : 0.01f * hr;
        as4[j] = fmaf(hs, w2_l[nt], as4[j]);
        ar4[j] = fmaf(hr, w2_l[nt], ar4[j]);
      }
    }
    #pragma unroll
    for (int j = 0; j < 4; ++j) {
      #pragma unroll
      for (int d = 1; d < 16; d <<= 1) {
        as4[j] += __shfl_xor(as4[j], d, 64);
        ar4[j] += __shfl_xor(ar4[j], d, 64);
      }
    }
    if (l15 == 0) {
      #pragma unroll
      for (int j = 0; j < 4; ++j) {
        int e = e0 + lg * 4 + j;
        if (e < E) { w_s[e] = as4[j]; w_r[e] = ar4[j]; }
      }
    }
  }
}

// ---- wave-per-node gather: softmax over edge list, coalesced p-weighted row sums ----
__global__ void __launch_bounds__(256) k_gatherw(
    const float* __restrict__ x, const float* __restrict__ en, const float* __restrict__ w,
    const int* __restrict__ lst, const int* __restrict__ deg_a, const int* __restrict__ other_idx,
    float* __restrict__ ss, float* __restrict__ gam, int N) {
  int wid = threadIdx.x >> 6, lane = threadIdx.x & 63;
  int n = blockIdx.x * 4 + wid;
  if (n >= N) return;
  int deg = deg_a[n];
  deg = deg < 64 ? deg : 64;
  float* ssd = ss + (size_t)n * 128;
  if (deg == 0) {
    ssd[lane] = 0.f; ssd[64 + lane] = 0.f;
    if (lane == 0) gam[n] = 0.f;
    return;
  }
  int e = 0, oe = 0;
  float wv = -1e30f;
  if (lane < deg) {
    e = lst[(size_t)n * 64 + lane];
    oe = other_idx[e];
    wv = w[e];
  }
  float m = wv;
  #pragma unroll
  for (int d = 32; d; d >>= 1) m = fmaxf(m, __shfl_xor(m, d, 64));
  float p = (lane < deg) ? __expf(wv - m) : 0.f;
  float S = p;
  #pragma unroll
  for (int d = 32; d; d >>= 1) S += __shfl_xor(S, d, 64);
  float sx = 0.f, se = 0.f;
  for (int i = 0; i < deg; ++i) {
    float pi = __shfl(p, i, 64);
    int ei = __shfl(e, i, 64);
    int oi = __shfl(oe, i, 64);
    sx = fmaf(pi, x[(size_t)oi * DD + lane], sx);
    se = fmaf(pi, en[(size_t)ei * DD + lane], se);
  }
  float inv = 1.f / (S + 1e-16f);
  ssd[lane] = sx * inv;
  ssd[64 + lane] = se * inv;
  if (lane == 0) gam[n] = S * inv;
}

// ---- node MLP, quarter-split: blockIdx.y = output quarter (16 channels) ----
__global__ void __launch_bounds__(256) k_node2v(
    const float* __restrict__ x, const float* __restrict__ ss_s, const float* __restrict__ ss_r,
    const float* __restrict__ gam_s, const float* __restrict__ gam_r,
    const float* __restrict__ u,
    const float* __restrict__ Wn, const float* __restrict__ bn,
    const float* __restrict__ Ms, const float* __restrict__ cs,
    const float* __restrict__ Mr, const float* __restrict__ cr,
    const int* __restrict__ nbat, float* __restrict__ x_out, int N) {
  int n = blockIdx.x * 256 + threadIdx.x;
  if (n >= N) return;
  const int o0 = blockIdx.y * 16;
  int g = nbat[n];
  float gs = gam_s[n], gr = gam_r[n];
  float acc[16];
  #pragma unroll
  for (int j = 0; j < 16; ++j)
    acc[j] = fmaf(gs, cs[o0 + j], fmaf(gr, cr[o0 + j], bn[o0 + j]));
  gemv_go<64, 16>(acc, x + (size_t)n * DD, Wn + (size_t)o0 * 256, 256);
  gemv_go<64, 16>(acc, u + (size_t)g * DD, Wn + (size_t)o0 * 256 + 192, 256);
  gemv_go<128, 16>(acc, ss_s + (size_t)n * 128, Ms + (size_t)o0 * 128, 128);
  gemv_go<128, 16>(acc, ss_r + (size_t)n * 128, Mr + (size_t)o0 * 128, 128);
  float* dst = x_out + (size_t)n * DD + o0;
  #pragma unroll
  for (int j = 0; j < 16; j += 4) {
    float4 v;
    v.x = fmaxf(acc[j + 0], 0.f); v.y = fmaxf(acc[j + 1], 0.f);
    v.z = fmaxf(acc[j + 2], 0.f); v.w = fmaxf(acc[j + 3], 0.f);
    *reinterpret_cast<float4*>(dst + j) = v;
  }
}

// ---- segment-sum over sorted segment ids (run-length + atomic flush) ----
__global__ void __launch_bounds__(256) k_segsum(
    const float* __restrict__ vals, const int* __restrict__ seg,
    float* __restrict__ out, int n) {
  int d = threadIdx.x & 63;
  int grp = threadIdx.x >> 6;
  long base = (long)blockIdx.x * 1024 + (long)grp * 256;
  float sum = 0.f;
  int cur = -1;
  for (int k = 0; k < 256; ++k) {
    long e = base + k;
    if (e >= n) break;
    int gb = seg[e];
    float v = vals[e * DD + d];
    if (gb != cur) {
      if (cur >= 0) atomicAdd(out + (size_t)cur * DD + d, sum);
      cur = gb; sum = v;
    } else {
      sum += v;
    }
  }
  if (cur >= 0) atomicAdd(out + (size_t)cur * DD + d, sum);
}

// ---- global MLP ----
__global__ void __launch_bounds__(64) k_glob(
    const float* __restrict__ u, const float* __restrict__ nagg, const float* __restrict__ eagg,
    const float* __restrict__ Wg, const float* __restrict__ bg,
    float* __restrict__ u_out, int G) {
  int t = blockIdx.x * 64 + threadIdx.x;
  if (t >= G * 64) return;
  int g = t >> 6, o = t & 63;
  float acc = bg[o];
  const float* wr = Wg + (size_t)o * 192;
  for (int i = 0; i < 64; ++i) acc = fmaf(u[g * 64 + i],    wr[i],       acc);
  for (int i = 0; i < 64; ++i) acc = fmaf(nagg[g * 64 + i], wr[64 + i],  acc);
  for (int i = 0; i < 64; ++i) acc = fmaf(eagg[g * 64 + i], wr[128 + i], acc);
  u_out[t] = fmaxf(acc, 0.f);
}

extern "C" void kernel_launch(void* const* d_in, const int* in_sizes, int n_in,
                              void* d_out, int out_size, void* d_ws, size_t ws_size,
                              hipStream_t stream) {
  const float* x   = (const float*)d_in[0];
  const float* ea  = (const float*)d_in[1];
  const float* u   = (const float*)d_in[2];
  const float* We  = (const float*)d_in[3];
  const float* be  = (const float*)d_in[4];
  const float* Wn  = (const float*)d_in[5];
  const float* bn  = (const float*)d_in[6];
  const float* Wg  = (const float*)d_in[7];
  const float* bg  = (const float*)d_in[8];
  const float* W1  = (const float*)d_in[9];
  const float* b1  = (const float*)d_in[10];
  const float* w2  = (const float*)d_in[11];
  const float* W3  = (const float*)d_in[12];
  const float* b3  = (const float*)d_in[13];
  const int* eidx  = (const int*)d_in[14];
  const int* nbat  = (const int*)d_in[15];
  const int* ebat  = (const int*)d_in[16];

  const int N = in_sizes[0] / 64;
  const int E = in_sizes[1] / 64;
  const int G = in_sizes[2] / 64;
  const int* row = eidx;
  const int* col = eidx + E;

  float* out   = (float*)d_out;
  float* x_out = out;
  float* e_out = out + (size_t)N * 64;
  float* u_out = out + (size_t)(N + E) * 64;

  // ---- workspace layout ----
  float* ws = (float*)d_ws;
  float* px1 = ws;
  float* px2 = ws + (size_t)N * 64;
  float* ss_s = ws;
  float* hq  = ws + (size_t)N * 128;
  float* hkv = hq + (size_t)N * 64;
  float* ss_r = hq;
  float* w_s = ws + (size_t)N * 256;            // E
  float* w_r = w_s + E;                         // E
  float* pu  = w_r + E;                         // G*64
  int* lst_s = (int*)(pu + (size_t)G * 64);     // N*64
  int* lst_r = lst_s + (size_t)N * 64;          // N*64
  int* deg_s = lst_r + (size_t)N * 64;          // N    (memset from here...)
  int* deg_r = deg_s + N;                       // N
  float* nagg = (float*)(deg_r + N);            // G*64
  float* eagg = nagg + (size_t)G * 64;          // G*64 (...to here)
  float* gam_s = eagg + (size_t)G * 64;         // N
  float* gam_r = gam_s + N;                     // N
  float* Ms = gam_r + N;                        // 64*128
  float* Mr = Ms + 64 * 128;                    // 64*128
  float* cs = Mr + 64 * 128;                    // 64
  float* cr = cs + 64;                          // 64

  hipMemsetAsync(deg_s, 0, (2 * (size_t)N + 2 * (size_t)G * 64) * sizeof(int), stream);

  const int gE = (E + 255) / 256;
  const int gN = (N + 255) / 256;

  k_fill<<<gE, 256, 0, stream>>>(row, col, deg_s, deg_r, lst_s, lst_r, E);
  k_nodepre2<<<dim3(gN, 8), 256, 0, stream>>>(x, u, We, W1, px1, px2, hq, hkv, pu, N, G);
  k_precomb<<<8, 128, 0, stream>>>(Wn, W3, b3, Ms, cs, Mr, cr);
  k_edgeattn3<<<1024, 256, 0, stream>>>(ea, px1, px2, pu, hq, hkv, We, be, W1, b1, w2,
                                        row, col, ebat, e_out, w_s, w_r, E);
  k_segsum<<<(E + 1023) / 1024, 256, 0, stream>>>(e_out, ebat, eagg, E);
  // gathers overwrite regions A/B (px/hq dead after k_edgeattn3)
  k_gatherw<<<(N + 3) / 4, 256, 0, stream>>>(x, e_out, w_s, lst_s, deg_s, col, ss_s, gam_s, N);
  k_gatherw<<<(N + 3) / 4, 256, 0, stream>>>(x, e_out, w_r, lst_r, deg_r, row, ss_r, gam_r, N);
  k_node2v<<<dim3(gN, 4), 256, 0, stream>>>(x, ss_s, ss_r, gam_s, gam_r, u, Wn, bn,
                                            Ms, cs, Mr, cr, nbat, x_out, N);
  k_segsum<<<(N + 1023) / 1024, 256, 0, stream>>>(x_out, nbat, nagg, N);
  k_glob<<<(G * 64 + 63) / 64, 64, 0, stream>>>(u, nagg, eagg, Wg, bg, u_out, G);
}

// Round 8
// 700.829 us; speedup vs baseline: 8.5362x; 1.1750x over previous
//
#include <hip/hip_runtime.h>

#define DD 64

typedef __attribute__((ext_vector_type(8))) short bf16x8;   // 8 bf16 = 4 VGPRs
typedef __attribute__((ext_vector_type(4))) float f32x4;

#define MFMA16(A, B, C) __builtin_amdgcn_mfma_f32_16x16x32_bf16(A, B, C, 0, 0, 0)

__device__ __forceinline__ float4 ld4(const float* p) {
  return *reinterpret_cast<const float4*>(p);
}

__device__ __forceinline__ unsigned short f2bf(float f) {
  unsigned u = __float_as_uint(f);
  unsigned r = u + 0x7FFFu + ((u >> 16) & 1u);   // RNE
  return (unsigned short)(r >> 16);
}

__device__ __forceinline__ bf16x8 cvt8(float4 a, float4 b) {
  bf16x8 v;
  v[0] = (short)f2bf(a.x); v[1] = (short)f2bf(a.y);
  v[2] = (short)f2bf(a.z); v[3] = (short)f2bf(a.w);
  v[4] = (short)f2bf(b.x); v[5] = (short)f2bf(b.y);
  v[6] = (short)f2bf(b.z); v[7] = (short)f2bf(b.w);
  return v;
}

// ---- build padded CSR (both directions), MAXDEG=64 ----
__global__ void __launch_bounds__(256) k_fill(
    const int* __restrict__ row, const int* __restrict__ col,
    int* __restrict__ deg_s, int* __restrict__ deg_r,
    int* __restrict__ lst_s, int* __restrict__ lst_r, int E) {
  int e = blockIdx.x * 256 + threadIdx.x;
  if (e >= E) return;
  int r = row[e], c = col[e];
  int s0 = atomicAdd(deg_s + r, 1);
  if (s0 < 64) lst_s[(size_t)r * 64 + s0] = e;
  int s1 = atomicAdd(deg_r + c, 1);
  if (s1 < 64) lst_r[(size_t)c * 64 + s1] = e;
}

// ---- precombine: Ms=Wn[:,64:128].W3, cs=Wn[:,64:128].b3; Mr/cr for 128:192;
//      pu = We[:,192:256].u ; pun = Wn[:,192:256].u ----
__global__ void __launch_bounds__(128) k_precomb(
    const float* __restrict__ Wn, const float* __restrict__ W3, const float* __restrict__ b3,
    const float* __restrict__ We, const float* __restrict__ u_,
    float* __restrict__ Ms, float* __restrict__ cs,
    float* __restrict__ Mr, float* __restrict__ cr,
    float* __restrict__ pu, float* __restrict__ pun, int G) {
  int t = threadIdx.x;
  if (blockIdx.x < 8) {
    int dir = t >> 6, o = t & 63;
    const float* wrow = Wn + (size_t)o * 256 + 64 + 64 * dir;
    float* M  = dir ? Mr : Ms;
    float* cv = dir ? cr : cs;
    if (blockIdx.x == 0) {
      float cb = 0.f;
      for (int k = 0; k < 64; ++k) cb = fmaf(wrow[k], b3[k], cb);
      cv[o] = cb;
    }
    int c0 = blockIdx.x * 16;
    for (int c = c0; c < c0 + 16; ++c) {
      float m = 0.f;
      for (int k = 0; k < 64; ++k) m = fmaf(wrow[k], W3[k * 128 + c], m);
      M[(size_t)o * 128 + c] = m;
    }
  } else {
    const float* W = (blockIdx.x == 8) ? We : Wn;
    float* dst = (blockIdx.x == 8) ? pu : pun;
    int o = t & 63;
    const float* wr = W + (size_t)o * 256 + 192;
    for (int g = t >> 6; g < G; g += 2) {
      float a = 0.f;
      const float* uv = u_ + (size_t)g * 64;
      for (int k = 0; k < 64; ++k) a = fmaf(wr[k], uv[k], a);
      dst[(size_t)g * 64 + o] = a;
    }
  }
}

// ---- pack B matrices to bf16 MFMA-frag layout (one-time) ----
// BpP: nodepre GEMM  K=64,N=256 : chunk idx=(ks*16+nt)*64+lane, ks<2, nt<16
//      B[k][c]: c=nt*16+l15, a=c>>6, o=c&63; a0:We[o][64+k] a1:We[o][128+k]
//      a2:W1[o][k] a3:W1[o][64+k]
// BpN: node GEMM     K=320,N=64 : chunk idx=(ks*4+nt)*64+lane, ks<10, nt<4
//      B[k][col]: col=nt*16+l15; k<64:Wn[col][k]; k<192:Ms[col][k-64]; else Mr[col][k-192]
__global__ void __launch_bounds__(256) k_pack(
    const float* __restrict__ We, const float* __restrict__ W1, const float* __restrict__ Wn,
    const float* __restrict__ Ms, const float* __restrict__ Mr,
    unsigned short* __restrict__ BpP, unsigned short* __restrict__ BpN) {
  int idx = blockIdx.x * 256 + threadIdx.x;
  if (idx < 2048) {
    int lane = idx & 63, nt = (idx >> 6) & 15, ks = idx >> 10;
    int l15 = lane & 15, lg = lane >> 4;
    int c = nt * 16 + l15, a = c >> 6, o = c & 63;
    bf16x8 v;
    #pragma unroll
    for (int j = 0; j < 8; ++j) {
      int k = ks * 32 + lg * 8 + j;
      float f = (a == 0) ? We[o * 256 + 64 + k]
              : (a == 1) ? We[o * 256 + 128 + k]
              : (a == 2) ? W1[o * 192 + k]
                         : W1[o * 192 + 64 + k];
      v[j] = (short)f2bf(f);
    }
    *(bf16x8*)(BpP + (size_t)idx * 8) = v;
  } else if (idx < 2048 + 2560) {
    int i2 = idx - 2048;
    int lane = i2 & 63, nt = (i2 >> 6) & 3, ks = i2 >> 8;
    int l15 = lane & 15, lg = lane >> 4;
    int col = nt * 16 + l15;
    bf16x8 v;
    #pragma unroll
    for (int j = 0; j < 8; ++j) {
      int k = ks * 32 + lg * 8 + j;
      float f = (k < 64) ? Wn[col * 256 + k]
              : (k < 192) ? Ms[col * 128 + (k - 64)]
                          : Mr[col * 128 + (k - 192)];
      v[j] = (short)f2bf(f);
    }
    *(bf16x8*)(BpN + (size_t)i2 * 8) = v;
  }
}

// ---- nodepre via MFMA: [px1|px2|hq|hkv](50k x 256) = x(50k x 64) . Bp ----
__global__ void __launch_bounds__(256) k_nodepre3(
    const float* __restrict__ x, const unsigned short* __restrict__ BpP,
    float* __restrict__ px1, float* __restrict__ px2,
    float* __restrict__ hq, float* __restrict__ hkv, int N) {
  __shared__ unsigned short lB[2048 * 8];   // 32KB
  const int tid = threadIdx.x;
  for (int i = tid; i < 2048; i += 256)
    *(uint4*)(lB + (size_t)i * 8) = *(const uint4*)(BpP + (size_t)i * 8);
  __syncthreads();
  const int lane = tid & 63, wid = tid >> 6, l15 = lane & 15, lg = lane >> 4;
  const int tile = blockIdx.x * 4 + wid;
  const int n0 = tile * 16;
  if (n0 >= N) return;
  int arow = n0 + l15; if (arow >= N) arow = N - 1;
  const float* src = x + (size_t)arow * 64 + lg * 8;
  bf16x8 A0 = cvt8(ld4(src), ld4(src + 4));
  bf16x8 A1 = cvt8(ld4(src + 32), ld4(src + 36));
  f32x4 acc[16];
  #pragma unroll
  for (int nt = 0; nt < 16; ++nt) {
    acc[nt] = (f32x4){0.f, 0.f, 0.f, 0.f};
    acc[nt] = MFMA16(A0, *(const bf16x8*)(lB + ((size_t)(0 * 16 + nt) * 64 + lane) * 8), acc[nt]);
    acc[nt] = MFMA16(A1, *(const bf16x8*)(lB + ((size_t)(1 * 16 + nt) * 64 + lane) * 8), acc[nt]);
  }
  float* dsts[4] = {px1, px2, hq, hkv};
  #pragma unroll
  for (int nt = 0; nt < 16; ++nt) {
    float* d = dsts[nt >> 2];
    const int o = (nt & 3) * 16 + l15;
    #pragma unroll
    for (int j = 0; j < 4; ++j) {
      int n = n0 + lg * 4 + j;
      if (n < N) d[(size_t)n * 64 + o] = acc[nt][j];
    }
  }
}

// ---- MFMA fused edge MLP + attention logits: wave = 16 edges ----
__global__ void __launch_bounds__(256, 2) k_edgeattn3(
    const float* __restrict__ ea,
    const float* __restrict__ px1, const float* __restrict__ px2, const float* __restrict__ pu,
    const float* __restrict__ hq, const float* __restrict__ hkv,
    const float* __restrict__ We, const float* __restrict__ be,
    const float* __restrict__ W1, const float* __restrict__ b1, const float* __restrict__ w2,
    const int* __restrict__ row, const int* __restrict__ col, const int* __restrict__ ebat,
    float* __restrict__ edge_out, float* __restrict__ w_s, float* __restrict__ w_r, int E) {
  __shared__ unsigned short enl_all[4][16 * 64];  // per-wave 2KB bf16 tile, swizzled
  const int tid = threadIdx.x, lane = tid & 63, wid = tid >> 6;
  const int l15 = lane & 15, lg = lane >> 4;

  bf16x8 B1[4][2], B2[4][2];
  #pragma unroll
  for (int nt = 0; nt < 4; ++nt) {
    #pragma unroll
    for (int ks = 0; ks < 2; ++ks) {
      const float* s1 = We + (size_t)(nt * 16 + l15) * 256 + ks * 32 + lg * 8;
      B1[nt][ks] = cvt8(ld4(s1), ld4(s1 + 4));
      const float* s2 = W1 + (size_t)(nt * 16 + l15) * 192 + 128 + ks * 32 + lg * 8;
      B2[nt][ks] = cvt8(ld4(s2), ld4(s2 + 4));
    }
  }
  float be_l[4], b1_l[4], w2_l[4];
  #pragma unroll
  for (int nt = 0; nt < 4; ++nt) {
    be_l[nt] = be[nt * 16 + l15];
    b1_l[nt] = b1[nt * 16 + l15];
    w2_l[nt] = w2[nt * 16 + l15];
  }
  unsigned short* enl = enl_all[wid];
  const int nwaves = gridDim.x * 4;
  const int swz_r = (l15 & 7) << 4;

  for (int e0 = (blockIdx.x * 4 + wid) * 16; e0 < E; e0 += nwaves * 16) {
    // ---- indices ----
    int rj[4], cj[4], gj[4];
    if (e0 + 16 <= E) {
      int4 r4 = *(const int4*)(row + e0 + lg * 4);
      int4 c4 = *(const int4*)(col + e0 + lg * 4);
      int4 g4 = *(const int4*)(ebat + e0 + lg * 4);
      rj[0]=r4.x; rj[1]=r4.y; rj[2]=r4.z; rj[3]=r4.w;
      cj[0]=c4.x; cj[1]=c4.y; cj[2]=c4.z; cj[3]=c4.w;
      gj[0]=g4.x; gj[1]=g4.y; gj[2]=g4.z; gj[3]=g4.w;
    } else {
      #pragma unroll
      for (int j = 0; j < 4; ++j) {
        int ee = e0 + lg * 4 + j; if (ee >= E) ee = E - 1;
        rj[j] = row[ee]; cj[j] = col[ee]; gj[j] = ebat[ee];
      }
    }

    // ---- HOISTED epilogue-2 gathers: issue now, consume after GEMM2 ----
    float hqr_v[4][4], hqc_v[4][4], hkr_v[4][4], hkc_v[4][4];
    #pragma unroll
    for (int j = 0; j < 4; ++j) {
      #pragma unroll
      for (int nt = 0; nt < 4; ++nt) {
        hqr_v[j][nt] = hq [(size_t)rj[j] * 64 + nt * 16 + l15];
        hqc_v[j][nt] = hq [(size_t)cj[j] * 64 + nt * 16 + l15];
        hkr_v[j][nt] = hkv[(size_t)rj[j] * 64 + nt * 16 + l15];
        hkc_v[j][nt] = hkv[(size_t)cj[j] * 64 + nt * 16 + l15];
      }
    }

    // ---- A1-frags from ea ----
    int erow = e0 + l15; if (erow >= E) erow = E - 1;
    const float* arow = ea + (size_t)erow * 64;
    bf16x8 A1[2];
    #pragma unroll
    for (int ks = 0; ks < 2; ++ks) {
      const float* s = arow + ks * 32 + lg * 8;
      A1[ks] = cvt8(ld4(s), ld4(s + 4));
    }

    // ---- GEMM1 ----
    f32x4 acc[4];
    #pragma unroll
    for (int nt = 0; nt < 4; ++nt) acc[nt] = (f32x4){0.f, 0.f, 0.f, 0.f};
    #pragma unroll
    for (int nt = 0; nt < 4; ++nt) {
      acc[nt] = MFMA16(A1[0], B1[nt][0], acc[nt]);
      acc[nt] = MFMA16(A1[1], B1[nt][1], acc[nt]);
    }

    // ---- epilogue1: +bias +px1[r]+px2[c]+pu[g], relu, store, pack bf16->LDS ----
    #pragma unroll
    for (int j = 0; j < 4; ++j) {
      const int m = lg * 4 + j;
      const float* p1 = px1 + (size_t)rj[j] * 64 + l15;
      const float* p2 = px2 + (size_t)cj[j] * 64 + l15;
      const float* p3 = pu  + (size_t)gj[j] * 64 + l15;
      const bool st = (e0 + m) < E;
      float* eo = edge_out + (size_t)(e0 + m) * 64 + l15;
      const int rbase = m * 128, sw = (m & 7) << 4;
      #pragma unroll
      for (int nt = 0; nt < 4; ++nt) {
        float v = acc[nt][j] + be_l[nt] + p1[nt * 16] + p2[nt * 16] + p3[nt * 16];
        v = fmaxf(v, 0.f);
        if (st) eo[nt * 16] = v;
        int byte = rbase + ((nt * 32 + l15 * 2) ^ sw);
        *(unsigned short*)((char*)enl + byte) = f2bf(v);
      }
    }

    // ---- A2-frags from LDS (swizzled read) ----
    asm volatile("s_waitcnt lgkmcnt(0)" ::: "memory");
    bf16x8 A2[2];
    #pragma unroll
    for (int ks = 0; ks < 2; ++ks) {
      int byte = l15 * 128 + (((ks * 64) + lg * 16) ^ swz_r);
      A2[ks] = *(const bf16x8*)((const char*)enl + byte);
    }

    // ---- GEMM2 ----
    f32x4 tac[4];
    #pragma unroll
    for (int nt = 0; nt < 4; ++nt) tac[nt] = (f32x4){0.f, 0.f, 0.f, 0.f};
    #pragma unroll
    for (int nt = 0; nt < 4; ++nt) {
      tac[nt] = MFMA16(A2[0], B2[nt][0], tac[nt]);
      tac[nt] = MFMA16(A2[1], B2[nt][1], tac[nt]);
    }

    // ---- epilogue2: logits (uses hoisted gathers) ----
    float as4[4] = {0.f, 0.f, 0.f, 0.f}, ar4[4] = {0.f, 0.f, 0.f, 0.f};
    #pragma unroll
    for (int j = 0; j < 4; ++j) {
      #pragma unroll
      for (int nt = 0; nt < 4; ++nt) {
        float tt = tac[nt][j] + b1_l[nt];
        float hs = tt + hqr_v[j][nt] + hkc_v[j][nt]; hs = (hs >= 0.f) ? hs : 0.01f * hs;
        float hr = tt + hqc_v[j][nt] + hkr_v[j][nt]; hr = (hr >= 0.f) ? hr : 0.01f * hr;
        as4[j] = fmaf(hs, w2_l[nt], as4[j]);
        ar4[j] = fmaf(hr, w2_l[nt], ar4[j]);
      }
    }
    #pragma unroll
    for (int j = 0; j < 4; ++j) {
      #pragma unroll
      for (int d = 1; d < 16; d <<= 1) {
        as4[j] += __shfl_xor(as4[j], d, 64);
        ar4[j] += __shfl_xor(ar4[j], d, 64);
      }
    }
    if (l15 == 0) {
      #pragma unroll
      for (int j = 0; j < 4; ++j) {
        int e = e0 + lg * 4 + j;
        if (e < E) { w_s[e] = as4[j]; w_r[e] = ar4[j]; }
      }
    }
  }
}

// ---- wave-per-node gather: softmax over edge list, coalesced p-weighted row sums ----
__global__ void __launch_bounds__(256) k_gatherw(
    const float* __restrict__ x, const float* __restrict__ en, const float* __restrict__ w,
    const int* __restrict__ lst, const int* __restrict__ deg_a, const int* __restrict__ other_idx,
    float* __restrict__ ss, float* __restrict__ gam, int N) {
  int wid = threadIdx.x >> 6, lane = threadIdx.x & 63;
  int n = blockIdx.x * 4 + wid;
  if (n >= N) return;
  int deg = deg_a[n];
  deg = deg < 64 ? deg : 64;
  float* ssd = ss + (size_t)n * 128;
  if (deg == 0) {
    ssd[lane] = 0.f; ssd[64 + lane] = 0.f;
    if (lane == 0) gam[n] = 0.f;
    return;
  }
  int e = 0, oe = 0;
  float wv = -1e30f;
  if (lane < deg) {
    e = lst[(size_t)n * 64 + lane];
    oe = other_idx[e];
    wv = w[e];
  }
  float m = wv;
  #pragma unroll
  for (int d = 32; d; d >>= 1) m = fmaxf(m, __shfl_xor(m, d, 64));
  float p = (lane < deg) ? __expf(wv - m) : 0.f;
  float S = p;
  #pragma unroll
  for (int d = 32; d; d >>= 1) S += __shfl_xor(S, d, 64);
  float sx = 0.f, se = 0.f;
  for (int i = 0; i < deg; ++i) {
    float pi = __shfl(p, i, 64);
    int ei = __shfl(e, i, 64);
    int oi = __shfl(oe, i, 64);
    sx = fmaf(pi, x[(size_t)oi * DD + lane], sx);
    se = fmaf(pi, en[(size_t)ei * DD + lane], se);
  }
  float inv = 1.f / (S + 1e-16f);
  ssd[lane] = sx * inv;
  ssd[64 + lane] = se * inv;
  if (lane == 0) gam[n] = S * inv;
}

// ---- node MLP via MFMA: x_new(50k x 64) = [x|ss_s|ss_r](50k x 320) . BpN + epilogue ----
__global__ void __launch_bounds__(256) k_node3(
    const float* __restrict__ x, const float* __restrict__ ss_s, const float* __restrict__ ss_r,
    const float* __restrict__ gam_s, const float* __restrict__ gam_r,
    const unsigned short* __restrict__ BpN,
    const float* __restrict__ bn, const float* __restrict__ cs, const float* __restrict__ cr,
    const float* __restrict__ pun, const int* __restrict__ nbat,
    float* __restrict__ x_out, int N) {
  __shared__ unsigned short lB[2560 * 8];   // 40KB
  const int tid = threadIdx.x;
  for (int i = tid; i < 2560; i += 256)
    *(uint4*)(lB + (size_t)i * 8) = *(const uint4*)(BpN + (size_t)i * 8);
  __syncthreads();
  const int lane = tid & 63, wid = tid >> 6, l15 = lane & 15, lg = lane >> 4;
  const int tile = blockIdx.x * 4 + wid;
  const int n0 = tile * 16;
  if (n0 >= N) return;
  int arow = n0 + l15; if (arow >= N) arow = N - 1;

  f32x4 acc[4];
  #pragma unroll
  for (int nt = 0; nt < 4; ++nt) acc[nt] = (f32x4){0.f, 0.f, 0.f, 0.f};

  // ks 0..1: x ; ks 2..5: ss_s ; ks 6..9: ss_r
  #pragma unroll
  for (int ks = 0; ks < 10; ++ks) {
    const float* s;
    if (ks < 2)      s = x    + (size_t)arow * 64  + ks * 32 + lg * 8;
    else if (ks < 6) s = ss_s + (size_t)arow * 128 + (ks - 2) * 32 + lg * 8;
    else             s = ss_r + (size_t)arow * 128 + (ks - 6) * 32 + lg * 8;
    bf16x8 A = cvt8(ld4(s), ld4(s + 4));
    #pragma unroll
    for (int nt = 0; nt < 4; ++nt)
      acc[nt] = MFMA16(A, *(const bf16x8*)(lB + ((size_t)(ks * 4 + nt) * 64 + lane) * 8), acc[nt]);
  }

  #pragma unroll
  for (int j = 0; j < 4; ++j) {
    int n = n0 + lg * 4 + j;
    int nn = n < N ? n : N - 1;
    int g = nbat[nn];
    float gs = gam_s[nn], gr = gam_r[nn];
    #pragma unroll
    for (int nt = 0; nt < 4; ++nt) {
      int o = nt * 16 + l15;
      float v = acc[nt][j] + bn[o] + pun[(size_t)g * 64 + o] + gs * cs[o] + gr * cr[o];
      v = fmaxf(v, 0.f);
      if (n < N) x_out[(size_t)n * 64 + o] = v;
    }
  }
}

// ---- segment-sum over sorted segment ids (run-length + atomic flush) ----
__global__ void __launch_bounds__(256) k_segsum(
    const float* __restrict__ vals, const int* __restrict__ seg,
    float* __restrict__ out, int n) {
  int d = threadIdx.x & 63;
  int grp = threadIdx.x >> 6;
  long base = (long)blockIdx.x * 1024 + (long)grp * 256;
  float sum = 0.f;
  int cur = -1;
  for (int k = 0; k < 256; ++k) {
    long e = base + k;
    if (e >= n) break;
    int gb = seg[e];
    float v = vals[e * DD + d];
    if (gb != cur) {
      if (cur >= 0) atomicAdd(out + (size_t)cur * DD + d, sum);
      cur = gb; sum = v;
    } else {
      sum += v;
    }
  }
  if (cur >= 0) atomicAdd(out + (size_t)cur * DD + d, sum);
}

// ---- global MLP ----
__global__ void __launch_bounds__(64) k_glob(
    const float* __restrict__ u, const float* __restrict__ nagg, const float* __restrict__ eagg,
    const float* __restrict__ Wg, const float* __restrict__ bg,
    float* __restrict__ u_out, int G) {
  int t = blockIdx.x * 64 + threadIdx.x;
  if (t >= G * 64) return;
  int g = t >> 6, o = t & 63;
  float acc = bg[o];
  const float* wr = Wg + (size_t)o * 192;
  for (int i = 0; i < 64; ++i) acc = fmaf(u[g * 64 + i],    wr[i],       acc);
  for (int i = 0; i < 64; ++i) acc = fmaf(nagg[g * 64 + i], wr[64 + i],  acc);
  for (int i = 0; i < 64; ++i) acc = fmaf(eagg[g * 64 + i], wr[128 + i], acc);
  u_out[t] = fmaxf(acc, 0.f);
}

extern "C" void kernel_launch(void* const* d_in, const int* in_sizes, int n_in,
                              void* d_out, int out_size, void* d_ws, size_t ws_size,
                              hipStream_t stream) {
  const float* x   = (const float*)d_in[0];
  const float* ea  = (const float*)d_in[1];
  const float* u   = (const float*)d_in[2];
  const float* We  = (const float*)d_in[3];
  const float* be  = (const float*)d_in[4];
  const float* Wn  = (const float*)d_in[5];
  const float* bn  = (const float*)d_in[6];
  const float* Wg  = (const float*)d_in[7];
  const float* bg  = (const float*)d_in[8];
  const float* W1  = (const float*)d_in[9];
  const float* b1  = (const float*)d_in[10];
  const float* w2  = (const float*)d_in[11];
  const float* W3  = (const float*)d_in[12];
  const float* b3  = (const float*)d_in[13];
  const int* eidx  = (const int*)d_in[14];
  const int* nbat  = (const int*)d_in[15];
  const int* ebat  = (const int*)d_in[16];

  const int N = in_sizes[0] / 64;
  const int E = in_sizes[1] / 64;
  const int G = in_sizes[2] / 64;
  const int* row = eidx;
  const int* col = eidx + E;

  float* out   = (float*)d_out;
  float* x_out = out;
  float* e_out = out + (size_t)N * 64;
  float* u_out = out + (size_t)(N + E) * 64;

  // ---- workspace layout ----
  float* ws = (float*)d_ws;
  float* px1 = ws;
  float* px2 = ws + (size_t)N * 64;
  float* ss_s = ws;
  float* hq  = ws + (size_t)N * 128;
  float* hkv = hq + (size_t)N * 64;
  float* ss_r = hq;
  float* w_s = ws + (size_t)N * 256;            // E
  float* w_r = w_s + E;                         // E
  float* pu  = w_r + E;                         // G*64
  int* lst_s = (int*)(pu + (size_t)G * 64);     // N*64
  int* lst_r = lst_s + (size_t)N * 64;          // N*64
  int* deg_s = lst_r + (size_t)N * 64;          // N    (memset from here...)
  int* deg_r = deg_s + N;                       // N
  float* nagg = (float*)(deg_r + N);            // G*64
  float* eagg = nagg + (size_t)G * 64;          // G*64 (...to here)
  float* gam_s = eagg + (size_t)G * 64;         // N
  float* gam_r = gam_s + N;                     // N
  float* Ms = gam_r + N;                        // 64*128
  float* Mr = Ms + 64 * 128;                    // 64*128
  float* cs = Mr + 64 * 128;                    // 64
  float* cr = cs + 64;                          // 64
  float* pun = cr + 64;                         // G*64
  unsigned short* BpP = (unsigned short*)(pun + (size_t)G * 64);  // 2048*8 shorts
  unsigned short* BpN = BpP + 2048 * 8;                           // 2560*8 shorts

  hipMemsetAsync(deg_s, 0, (2 * (size_t)N + 2 * (size_t)G * 64) * sizeof(int), stream);

  const int gE = (E + 255) / 256;
  const int gT = (N / 16 + 3) / 4;   // MFMA node-tile blocks (4 waves x 16 nodes)

  k_fill<<<gE, 256, 0, stream>>>(row, col, deg_s, deg_r, lst_s, lst_r, E);
  k_precomb<<<10, 128, 0, stream>>>(Wn, W3, b3, We, u, Ms, cs, Mr, cr, pu, pun, G);
  k_pack<<<18, 256, 0, stream>>>(We, W1, Wn, Ms, Mr, BpP, BpN);
  k_nodepre3<<<gT, 256, 0, stream>>>(x, BpP, px1, px2, hq, hkv, N);
  k_edgeattn3<<<2048, 256, 0, stream>>>(ea, px1, px2, pu, hq, hkv, We, be, W1, b1, w2,
                                        row, col, ebat, e_out, w_s, w_r, E);
  k_segsum<<<(E + 1023) / 1024, 256, 0, stream>>>(e_out, ebat, eagg, E);
  // gathers overwrite regions A/B (px/hq dead after k_edgeattn3)
  k_gatherw<<<(N + 3) / 4, 256, 0, stream>>>(x, e_out, w_s, lst_s, deg_s, col, ss_s, gam_s, N);
  k_gatherw<<<(N + 3) / 4, 256, 0, stream>>>(x, e_out, w_r, lst_r, deg_r, row, ss_r, gam_r, N);
  k_node3<<<gT, 256, 0, stream>>>(x, ss_s, ss_r, gam_s, gam_r, BpN, bn, cs, cr,
                                  pun, nbat, x_out, N);
  k_segsum<<<(N + 1023) / 1024, 256, 0, stream>>>(x_out, nbat, nagg, N);
  k_glob<<<(G * 64 + 63) / 64, 64, 0, stream>>>(u, nagg, eagg, Wg, bg, u_out, G);
}

// Round 9
// 593.834 us; speedup vs baseline: 10.0742x; 1.1802x over previous
//
#include <hip/hip_runtime.h>

typedef __attribute__((ext_vector_type(8))) short bf16x8;   // 8 bf16 = 4 VGPRs
typedef __attribute__((ext_vector_type(4))) float f32x4;

#define MFMA16(A, B, C) __builtin_amdgcn_mfma_f32_16x16x32_bf16(A, B, C, 0, 0, 0)

__device__ __forceinline__ float4 ld4(const float* p) {
  return *reinterpret_cast<const float4*>(p);
}

__device__ __forceinline__ unsigned short f2bf(float f) {
  unsigned u = __float_as_uint(f);
  unsigned r = u + 0x7FFFu + ((u >> 16) & 1u);   // RNE
  return (unsigned short)(r >> 16);
}

__device__ __forceinline__ float bf2f(unsigned short b) {
  return __uint_as_float(((unsigned)b) << 16);
}
__device__ __forceinline__ float bflo(unsigned u) { return __uint_as_float(u << 16); }
__device__ __forceinline__ float bfhi(unsigned u) { return __uint_as_float(u & 0xFFFF0000u); }
__device__ __forceinline__ unsigned bfpack(float lo, float hi) {
  return (unsigned)f2bf(lo) | ((unsigned)f2bf(hi) << 16);
}

__device__ __forceinline__ bf16x8 cvt8(float4 a, float4 b) {
  bf16x8 v;
  v[0] = (short)f2bf(a.x); v[1] = (short)f2bf(a.y);
  v[2] = (short)f2bf(a.z); v[3] = (short)f2bf(a.w);
  v[4] = (short)f2bf(b.x); v[5] = (short)f2bf(b.y);
  v[6] = (short)f2bf(b.z); v[7] = (short)f2bf(b.w);
  return v;
}

// ---- build padded CSR (both directions), MAXDEG=64 ----
__global__ void __launch_bounds__(256) k_fill(
    const int* __restrict__ row, const int* __restrict__ col,
    int* __restrict__ deg_s, int* __restrict__ deg_r,
    int* __restrict__ lst_s, int* __restrict__ lst_r, int E) {
  int e = blockIdx.x * 256 + threadIdx.x;
  if (e >= E) return;
  int r = row[e], c = col[e];
  int s0 = atomicAdd(deg_s + r, 1);
  if (s0 < 64) lst_s[(size_t)r * 64 + s0] = e;
  int s1 = atomicAdd(deg_r + c, 1);
  if (s1 < 64) lst_r[(size_t)c * 64 + s1] = e;
}

// ---- precombine: Ms=Wn[:,64:128].W3, cs=.b3; Mr/cr for 128:192; pu/pun ----
__global__ void __launch_bounds__(128) k_precomb(
    const float* __restrict__ Wn, const float* __restrict__ W3, const float* __restrict__ b3,
    const float* __restrict__ We, const float* __restrict__ u_,
    float* __restrict__ Ms, float* __restrict__ cs,
    float* __restrict__ Mr, float* __restrict__ cr,
    float* __restrict__ pu, float* __restrict__ pun, int G) {
  int t = threadIdx.x;
  if (blockIdx.x < 8) {
    int dir = t >> 6, o = t & 63;
    const float* wrow = Wn + (size_t)o * 256 + 64 + 64 * dir;
    float* M  = dir ? Mr : Ms;
    float* cv = dir ? cr : cs;
    if (blockIdx.x == 0) {
      float cb = 0.f;
      for (int k = 0; k < 64; ++k) cb = fmaf(wrow[k], b3[k], cb);
      cv[o] = cb;
    }
    int c0 = blockIdx.x * 16;
    for (int c = c0; c < c0 + 16; ++c) {
      float m = 0.f;
      for (int k = 0; k < 64; ++k) m = fmaf(wrow[k], W3[k * 128 + c], m);
      M[(size_t)o * 128 + c] = m;
    }
  } else {
    const float* W = (blockIdx.x == 8) ? We : Wn;
    float* dst = (blockIdx.x == 8) ? pu : pun;
    int o = t & 63;
    const float* wr = W + (size_t)o * 256 + 192;
    for (int g = t >> 6; g < G; g += 2) {
      float a = 0.f;
      const float* uv = u_ + (size_t)g * 64;
      for (int k = 0; k < 64; ++k) a = fmaf(wr[k], uv[k], a);
      dst[(size_t)g * 64 + o] = a;
    }
  }
}

// ---- pack B matrices to bf16 MFMA-frag layout (one-time) ----
__global__ void __launch_bounds__(256) k_pack(
    const float* __restrict__ We, const float* __restrict__ W1, const float* __restrict__ Wn,
    const float* __restrict__ Ms, const float* __restrict__ Mr,
    unsigned short* __restrict__ BpP, unsigned short* __restrict__ BpN) {
  int idx = blockIdx.x * 256 + threadIdx.x;
  if (idx < 2048) {
    int lane = idx & 63, nt = (idx >> 6) & 15, ks = idx >> 10;
    int l15 = lane & 15, lg = lane >> 4;
    int c = nt * 16 + l15, a = c >> 6, o = c & 63;
    bf16x8 v;
    #pragma unroll
    for (int j = 0; j < 8; ++j) {
      int k = ks * 32 + lg * 8 + j;
      float f = (a == 0) ? We[o * 256 + 64 + k]
              : (a == 1) ? We[o * 256 + 128 + k]
              : (a == 2) ? W1[o * 192 + k]
                         : W1[o * 192 + 64 + k];
      v[j] = (short)f2bf(f);
    }
    *(bf16x8*)(BpP + (size_t)idx * 8) = v;
  } else if (idx < 2048 + 2560) {
    int i2 = idx - 2048;
    int lane = i2 & 63, nt = (i2 >> 6) & 3, ks = i2 >> 8;
    int l15 = lane & 15, lg = lane >> 4;
    int col = nt * 16 + l15;
    bf16x8 v;
    #pragma unroll
    for (int j = 0; j < 8; ++j) {
      int k = ks * 32 + lg * 8 + j;
      float f = (k < 64) ? Wn[col * 256 + k]
              : (k < 192) ? Ms[col * 128 + (k - 64)]
                          : Mr[col * 128 + (k - 192)];
      v[j] = (short)f2bf(f);
    }
    *(bf16x8*)(BpN + (size_t)i2 * 8) = v;
  }
}

// ---- nodepre via MFMA; outputs PAIRED bf16 arrays pxx={px1,px2}, hqk={hq,hkv}
//      and x_bf (bf16 copy of x) ----
__global__ void __launch_bounds__(256) k_nodepre4(
    const float* __restrict__ x, const unsigned short* __restrict__ BpP,
    unsigned int* __restrict__ pxx, unsigned int* __restrict__ hqk,
    unsigned short* __restrict__ x_bf, int N) {
  __shared__ unsigned short lB[2048 * 8];   // 32KB
  const int tid = threadIdx.x;
  for (int i = tid; i < 2048; i += 256)
    *(uint4*)(lB + (size_t)i * 8) = *(const uint4*)(BpP + (size_t)i * 8);
  __syncthreads();
  const int lane = tid & 63, wid = tid >> 6, l15 = lane & 15, lg = lane >> 4;
  const int n0 = (blockIdx.x * 4 + wid) * 16;
  if (n0 >= N) return;
  int arow = n0 + l15; if (arow >= N) arow = N - 1;
  const float* src = x + (size_t)arow * 64 + lg * 8;
  bf16x8 A0 = cvt8(ld4(src), ld4(src + 4));
  bf16x8 A1 = cvt8(ld4(src + 32), ld4(src + 36));
  if (n0 + l15 < N) {
    *(bf16x8*)(x_bf + (size_t)(n0 + l15) * 64 + lg * 8) = A0;
    *(bf16x8*)(x_bf + (size_t)(n0 + l15) * 64 + 32 + lg * 8) = A1;
  }
  f32x4 acc[16];
  #pragma unroll
  for (int nt = 0; nt < 16; ++nt) {
    acc[nt] = (f32x4){0.f, 0.f, 0.f, 0.f};
    acc[nt] = MFMA16(A0, *(const bf16x8*)(lB + ((size_t)(0 * 16 + nt) * 64 + lane) * 8), acc[nt]);
    acc[nt] = MFMA16(A1, *(const bf16x8*)(lB + ((size_t)(1 * 16 + nt) * 64 + lane) * 8), acc[nt]);
  }
  // nt = a*4+q, a: 0=px1 1=px2 2=hq 3=hkv ; o = q*16+l15
  #pragma unroll
  for (int q = 0; q < 4; ++q) {
    const int o = q * 16 + l15;
    #pragma unroll
    for (int j = 0; j < 4; ++j) {
      int n = n0 + lg * 4 + j;
      if (n < N) {
        pxx[(size_t)n * 64 + o] = bfpack(acc[q][j],     acc[4 + q][j]);
        hqk[(size_t)n * 64 + o] = bfpack(acc[8 + q][j], acc[12 + q][j]);
      }
    }
  }
}

// ---- MFMA fused edge MLP + attention logits: wave = 16 edges; paired bf16 gathers ----
__global__ void __launch_bounds__(256, 2) k_edgeattn4(
    const float* __restrict__ ea,
    const unsigned int* __restrict__ pxx, const unsigned int* __restrict__ hqk,
    const float* __restrict__ pu,
    const float* __restrict__ We, const float* __restrict__ be,
    const float* __restrict__ W1, const float* __restrict__ b1, const float* __restrict__ w2,
    const int* __restrict__ row, const int* __restrict__ col, const int* __restrict__ ebat,
    float* __restrict__ edge_out, unsigned short* __restrict__ en_bf,
    float* __restrict__ w_s, float* __restrict__ w_r, int E) {
  __shared__ unsigned short enl_all[4][16 * 64];  // per-wave 2KB bf16 tile, swizzled
  const int tid = threadIdx.x, lane = tid & 63, wid = tid >> 6;
  const int l15 = lane & 15, lg = lane >> 4;

  bf16x8 B1[4][2], B2[4][2];
  #pragma unroll
  for (int nt = 0; nt < 4; ++nt) {
    #pragma unroll
    for (int ks = 0; ks < 2; ++ks) {
      const float* s1 = We + (size_t)(nt * 16 + l15) * 256 + ks * 32 + lg * 8;
      B1[nt][ks] = cvt8(ld4(s1), ld4(s1 + 4));
      const float* s2 = W1 + (size_t)(nt * 16 + l15) * 192 + 128 + ks * 32 + lg * 8;
      B2[nt][ks] = cvt8(ld4(s2), ld4(s2 + 4));
    }
  }
  float be_l[4], b1_l[4], w2_l[4];
  #pragma unroll
  for (int nt = 0; nt < 4; ++nt) {
    be_l[nt] = be[nt * 16 + l15];
    b1_l[nt] = b1[nt * 16 + l15];
    w2_l[nt] = w2[nt * 16 + l15];
  }
  unsigned short* enl = enl_all[wid];
  const int nwaves = gridDim.x * 4;
  const int swz_r = (l15 & 7) << 4;

  for (int e0 = (blockIdx.x * 4 + wid) * 16; e0 < E; e0 += nwaves * 16) {
    // ---- indices ----
    int rj[4], cj[4], gj[4];
    if (e0 + 16 <= E) {
      int4 r4 = *(const int4*)(row + e0 + lg * 4);
      int4 c4 = *(const int4*)(col + e0 + lg * 4);
      int4 g4 = *(const int4*)(ebat + e0 + lg * 4);
      rj[0]=r4.x; rj[1]=r4.y; rj[2]=r4.z; rj[3]=r4.w;
      cj[0]=c4.x; cj[1]=c4.y; cj[2]=c4.z; cj[3]=c4.w;
      gj[0]=g4.x; gj[1]=g4.y; gj[2]=g4.z; gj[3]=g4.w;
    } else {
      #pragma unroll
      for (int j = 0; j < 4; ++j) {
        int ee = e0 + lg * 4 + j; if (ee >= E) ee = E - 1;
        rj[j] = row[ee]; cj[j] = col[ee]; gj[j] = ebat[ee];
      }
    }

    // ---- ALL gathers issued before GEMM1 (paired bf16: half loads, half bytes) ----
    unsigned hr_[4][4], hc_[4][4], pr_[4][4], pc_[4][4];
    float puv[4][4];
    #pragma unroll
    for (int j = 0; j < 4; ++j) {
      #pragma unroll
      for (int nt = 0; nt < 4; ++nt) {
        const int o = nt * 16 + l15;
        hr_[j][nt] = hqk[(size_t)rj[j] * 64 + o];
        hc_[j][nt] = hqk[(size_t)cj[j] * 64 + o];
        pr_[j][nt] = pxx[(size_t)rj[j] * 64 + o];
        pc_[j][nt] = pxx[(size_t)cj[j] * 64 + o];
        puv[j][nt] = pu [(size_t)gj[j] * 64 + o];
      }
    }

    // ---- A1-frags from ea ----
    int erow = e0 + l15; if (erow >= E) erow = E - 1;
    const float* arow = ea + (size_t)erow * 64;
    bf16x8 A1[2];
    #pragma unroll
    for (int ks = 0; ks < 2; ++ks) {
      const float* s = arow + ks * 32 + lg * 8;
      A1[ks] = cvt8(ld4(s), ld4(s + 4));
    }

    // ---- GEMM1 ----
    f32x4 acc[4];
    #pragma unroll
    for (int nt = 0; nt < 4; ++nt) acc[nt] = (f32x4){0.f, 0.f, 0.f, 0.f};
    #pragma unroll
    for (int nt = 0; nt < 4; ++nt) {
      acc[nt] = MFMA16(A1[0], B1[nt][0], acc[nt]);
      acc[nt] = MFMA16(A1[1], B1[nt][1], acc[nt]);
    }

    // ---- epilogue1: +bias +px1[r]+px2[c]+pu[g], relu, store f32+bf16, LDS pack ----
    #pragma unroll
    for (int j = 0; j < 4; ++j) {
      const int m = lg * 4 + j;
      const bool st = (e0 + m) < E;
      float* eo = edge_out + (size_t)(e0 + m) * 64 + l15;
      unsigned short* eb = en_bf + (size_t)(e0 + m) * 64 + l15;
      const int rbase = m * 128, sw = (m & 7) << 4;
      #pragma unroll
      for (int nt = 0; nt < 4; ++nt) {
        float v = acc[nt][j] + be_l[nt] + bflo(pr_[j][nt]) + bfhi(pc_[j][nt]) + puv[j][nt];
        v = fmaxf(v, 0.f);
        unsigned short bv = f2bf(v);
        if (st) { eo[nt * 16] = v; eb[nt * 16] = bv; }
        int byte = rbase + ((nt * 32 + l15 * 2) ^ sw);
        *(unsigned short*)((char*)enl + byte) = bv;
      }
    }

    // ---- A2-frags from LDS (swizzled read) ----
    asm volatile("s_waitcnt lgkmcnt(0)" ::: "memory");
    bf16x8 A2[2];
    #pragma unroll
    for (int ks = 0; ks < 2; ++ks) {
      int byte = l15 * 128 + (((ks * 64) + lg * 16) ^ swz_r);
      A2[ks] = *(const bf16x8*)((const char*)enl + byte);
    }

    // ---- GEMM2 ----
    f32x4 tac[4];
    #pragma unroll
    for (int nt = 0; nt < 4; ++nt) tac[nt] = (f32x4){0.f, 0.f, 0.f, 0.f};
    #pragma unroll
    for (int nt = 0; nt < 4; ++nt) {
      tac[nt] = MFMA16(A2[0], B2[nt][0], tac[nt]);
      tac[nt] = MFMA16(A2[1], B2[nt][1], tac[nt]);
    }

    // ---- epilogue2: logits from paired hqk ----
    float as4[4] = {0.f, 0.f, 0.f, 0.f}, ar4[4] = {0.f, 0.f, 0.f, 0.f};
    #pragma unroll
    for (int j = 0; j < 4; ++j) {
      #pragma unroll
      for (int nt = 0; nt < 4; ++nt) {
        float tt = tac[nt][j] + b1_l[nt];
        float hs = tt + bflo(hr_[j][nt]) + bfhi(hc_[j][nt]); hs = (hs >= 0.f) ? hs : 0.01f * hs;
        float hr2 = tt + bflo(hc_[j][nt]) + bfhi(hr_[j][nt]); hr2 = (hr2 >= 0.f) ? hr2 : 0.01f * hr2;
        as4[j] = fmaf(hs, w2_l[nt], as4[j]);
        ar4[j] = fmaf(hr2, w2_l[nt], ar4[j]);
      }
    }
    #pragma unroll
    for (int j = 0; j < 4; ++j) {
      #pragma unroll
      for (int d = 1; d < 16; d <<= 1) {
        as4[j] += __shfl_xor(as4[j], d, 64);
        ar4[j] += __shfl_xor(ar4[j], d, 64);
      }
    }
    if (l15 == 0) {
      #pragma unroll
      for (int j = 0; j < 4; ++j) {
        int e = e0 + lg * 4 + j;
        if (e < E) { w_s[e] = as4[j]; w_r[e] = ar4[j]; }
      }
    }
  }
}

// ---- wave-per-node gather: bf16 rows, 4-deep unrolled pipeline ----
__global__ void __launch_bounds__(256) k_gatherw(
    const unsigned short* __restrict__ x_bf, const unsigned short* __restrict__ en_bf,
    const float* __restrict__ w,
    const int* __restrict__ lst, const int* __restrict__ deg_a, const int* __restrict__ other_idx,
    unsigned short* __restrict__ ss, float* __restrict__ gam, int N) {
  int wid = threadIdx.x >> 6, lane = threadIdx.x & 63;
  int n = blockIdx.x * 4 + wid;
  if (n >= N) return;
  int deg = deg_a[n];
  deg = deg < 64 ? deg : 64;
  unsigned short* ssd = ss + (size_t)n * 128;
  if (deg == 0) {
    ssd[lane] = 0; ssd[64 + lane] = 0;
    if (lane == 0) gam[n] = 0.f;
    return;
  }
  int e = 0, oe = 0;
  float wv = -1e30f;
  if (lane < deg) {
    e = lst[(size_t)n * 64 + lane];
    oe = other_idx[e];
    wv = w[e];
  }
  float m = wv;
  #pragma unroll
  for (int d = 32; d; d >>= 1) m = fmaxf(m, __shfl_xor(m, d, 64));
  float p = (lane < deg) ? __expf(wv - m) : 0.f;
  float S = p;
  #pragma unroll
  for (int d = 32; d; d >>= 1) S += __shfl_xor(S, d, 64);
  float sx0 = 0.f, sx1 = 0.f, sx2 = 0.f, sx3 = 0.f;
  float se0 = 0.f, se1 = 0.f, se2 = 0.f, se3 = 0.f;
  int i = 0;
  for (; i + 4 <= deg; i += 4) {
    float p0 = __shfl(p, i, 64),     p1 = __shfl(p, i + 1, 64);
    float p2 = __shfl(p, i + 2, 64), p3 = __shfl(p, i + 3, 64);
    int o0 = __shfl(oe, i, 64),     o1 = __shfl(oe, i + 1, 64);
    int o2 = __shfl(oe, i + 2, 64), o3 = __shfl(oe, i + 3, 64);
    int e0 = __shfl(e, i, 64),      e1 = __shfl(e, i + 1, 64);
    int e2 = __shfl(e, i + 2, 64),  e3 = __shfl(e, i + 3, 64);
    float xa0 = bf2f(x_bf[(size_t)o0 * 64 + lane]);
    float xa1 = bf2f(x_bf[(size_t)o1 * 64 + lane]);
    float xa2 = bf2f(x_bf[(size_t)o2 * 64 + lane]);
    float xa3 = bf2f(x_bf[(size_t)o3 * 64 + lane]);
    float ea0 = bf2f(en_bf[(size_t)e0 * 64 + lane]);
    float ea1 = bf2f(en_bf[(size_t)e1 * 64 + lane]);
    float ea2 = bf2f(en_bf[(size_t)e2 * 64 + lane]);
    float ea3 = bf2f(en_bf[(size_t)e3 * 64 + lane]);
    sx0 = fmaf(p0, xa0, sx0); sx1 = fmaf(p1, xa1, sx1);
    sx2 = fmaf(p2, xa2, sx2); sx3 = fmaf(p3, xa3, sx3);
    se0 = fmaf(p0, ea0, se0); se1 = fmaf(p1, ea1, se1);
    se2 = fmaf(p2, ea2, se2); se3 = fmaf(p3, ea3, se3);
  }
  for (; i < deg; ++i) {
    float pi = __shfl(p, i, 64);
    int ei = __shfl(e, i, 64);
    int oi = __shfl(oe, i, 64);
    sx0 = fmaf(pi, bf2f(x_bf[(size_t)oi * 64 + lane]), sx0);
    se0 = fmaf(pi, bf2f(en_bf[(size_t)ei * 64 + lane]), se0);
  }
  float sx = (sx0 + sx1) + (sx2 + sx3);
  float se = (se0 + se1) + (se2 + se3);
  float inv = 1.f / (S + 1e-16f);
  ssd[lane] = f2bf(sx * inv);
  ssd[64 + lane] = f2bf(se * inv);
  if (lane == 0) gam[n] = S * inv;
}

// ---- node MLP via MFMA: A-rows read directly as bf16 (x_bf | ss_s | ss_r) ----
__global__ void __launch_bounds__(256) k_node4(
    const unsigned short* __restrict__ x_bf,
    const unsigned short* __restrict__ ss_s, const unsigned short* __restrict__ ss_r,
    const float* __restrict__ gam_s, const float* __restrict__ gam_r,
    const unsigned short* __restrict__ BpN,
    const float* __restrict__ bn, const float* __restrict__ cs, const float* __restrict__ cr,
    const float* __restrict__ pun, const int* __restrict__ nbat,
    float* __restrict__ x_out, int N) {
  __shared__ unsigned short lB[2560 * 8];   // 40KB
  const int tid = threadIdx.x;
  for (int i = tid; i < 2560; i += 256)
    *(uint4*)(lB + (size_t)i * 8) = *(const uint4*)(BpN + (size_t)i * 8);
  __syncthreads();
  const int lane = tid & 63, wid = tid >> 6, l15 = lane & 15, lg = lane >> 4;
  const int n0 = (blockIdx.x * 4 + wid) * 16;
  if (n0 >= N) return;
  int arow = n0 + l15; if (arow >= N) arow = N - 1;

  f32x4 acc[4];
  #pragma unroll
  for (int nt = 0; nt < 4; ++nt) acc[nt] = (f32x4){0.f, 0.f, 0.f, 0.f};

  #pragma unroll
  for (int ks = 0; ks < 10; ++ks) {
    const unsigned short* s;
    if (ks < 2)      s = x_bf + (size_t)arow * 64  + ks * 32 + lg * 8;
    else if (ks < 6) s = ss_s + (size_t)arow * 128 + (ks - 2) * 32 + lg * 8;
    else             s = ss_r + (size_t)arow * 128 + (ks - 6) * 32 + lg * 8;
    bf16x8 A = *(const bf16x8*)s;
    #pragma unroll
    for (int nt = 0; nt < 4; ++nt)
      acc[nt] = MFMA16(A, *(const bf16x8*)(lB + ((size_t)(ks * 4 + nt) * 64 + lane) * 8), acc[nt]);
  }

  #pragma unroll
  for (int j = 0; j < 4; ++j) {
    int n = n0 + lg * 4 + j;
    int nn = n < N ? n : N - 1;
    int g = nbat[nn];
    float gs = gam_s[nn], gr = gam_r[nn];
    #pragma unroll
    for (int nt = 0; nt < 4; ++nt) {
      int o = nt * 16 + l15;
      float v = acc[nt][j] + bn[o] + pun[(size_t)g * 64 + o] + gs * cs[o] + gr * cr[o];
      v = fmaxf(v, 0.f);
      if (n < N) x_out[(size_t)n * 64 + o] = v;
    }
  }
}

// ---- segment-sum f32 (sorted ids, run-length + atomic flush) ----
__global__ void __launch_bounds__(256) k_segsum(
    const float* __restrict__ vals, const int* __restrict__ seg,
    float* __restrict__ out, int n) {
  int d = threadIdx.x & 63;
  int grp = threadIdx.x >> 6;
  long base = (long)blockIdx.x * 1024 + (long)grp * 256;
  float sum = 0.f;
  int cur = -1;
  for (int k = 0; k < 256; ++k) {
    long e = base + k;
    if (e >= n) break;
    int gb = seg[e];
    float v = vals[e * 64 + d];
    if (gb != cur) {
      if (cur >= 0) atomicAdd(out + (size_t)cur * 64 + d, sum);
      cur = gb; sum = v;
    } else {
      sum += v;
    }
  }
  if (cur >= 0) atomicAdd(out + (size_t)cur * 64 + d, sum);
}

// ---- segment-sum bf16 input ----
__global__ void __launch_bounds__(256) k_segsum_bf(
    const unsigned short* __restrict__ vals, const int* __restrict__ seg,
    float* __restrict__ out, int n) {
  int d = threadIdx.x & 63;
  int grp = threadIdx.x >> 6;
  long base = (long)blockIdx.x * 1024 + (long)grp * 256;
  float sum = 0.f;
  int cur = -1;
  for (int k = 0; k < 256; ++k) {
    long e = base + k;
    if (e >= n) break;
    int gb = seg[e];
    float v = bf2f(vals[e * 64 + d]);
    if (gb != cur) {
      if (cur >= 0) atomicAdd(out + (size_t)cur * 64 + d, sum);
      cur = gb; sum = v;
    } else {
      sum += v;
    }
  }
  if (cur >= 0) atomicAdd(out + (size_t)cur * 64 + d, sum);
}

// ---- global MLP ----
__global__ void __launch_bounds__(64) k_glob(
    const float* __restrict__ u, const float* __restrict__ nagg, const float* __restrict__ eagg,
    const float* __restrict__ Wg, const float* __restrict__ bg,
    float* __restrict__ u_out, int G) {
  int t = blockIdx.x * 64 + threadIdx.x;
  if (t >= G * 64) return;
  int g = t >> 6, o = t & 63;
  float acc = bg[o];
  const float* wr = Wg + (size_t)o * 192;
  for (int i = 0; i < 64; ++i) acc = fmaf(u[g * 64 + i],    wr[i],       acc);
  for (int i = 0; i < 64; ++i) acc = fmaf(nagg[g * 64 + i], wr[64 + i],  acc);
  for (int i = 0; i < 64; ++i) acc = fmaf(eagg[g * 64 + i], wr[128 + i], acc);
  u_out[t] = fmaxf(acc, 0.f);
}

extern "C" void kernel_launch(void* const* d_in, const int* in_sizes, int n_in,
                              void* d_out, int out_size, void* d_ws, size_t ws_size,
                              hipStream_t stream) {
  const float* x   = (const float*)d_in[0];
  const float* ea  = (const float*)d_in[1];
  const float* u   = (const float*)d_in[2];
  const float* We  = (const float*)d_in[3];
  const float* be  = (const float*)d_in[4];
  const float* Wn  = (const float*)d_in[5];
  const float* bn  = (const float*)d_in[6];
  const float* Wg  = (const float*)d_in[7];
  const float* bg  = (const float*)d_in[8];
  const float* W1  = (const float*)d_in[9];
  const float* b1  = (const float*)d_in[10];
  const float* w2  = (const float*)d_in[11];
  const float* W3  = (const float*)d_in[12];
  const float* b3  = (const float*)d_in[13];
  const int* eidx  = (const int*)d_in[14];
  const int* nbat  = (const int*)d_in[15];
  const int* ebat  = (const int*)d_in[16];

  const int N = in_sizes[0] / 64;
  const int E = in_sizes[1] / 64;
  const int G = in_sizes[2] / 64;
  const int* row = eidx;
  const int* col = eidx + E;

  float* out   = (float*)d_out;
  float* x_out = out;
  float* e_out = out + (size_t)N * 64;
  float* u_out = out + (size_t)(N + E) * 64;

  // ---- workspace layout (float units) ----
  float* ws = (float*)d_ws;
  unsigned int* pxx = (unsigned int*)ws;                     // N*64 uint
  unsigned int* hqk = pxx + (size_t)N * 64;                  // N*64 uint
  // after k_edgeattn4, pxx/hqk regions are dead -> reuse for bf16 ss (same byte size)
  unsigned short* ss_s = (unsigned short*)pxx;               // N*128 ushort
  unsigned short* ss_r = (unsigned short*)hqk;               // N*128 ushort
  unsigned short* x_bf = (unsigned short*)(hqk + (size_t)N * 64);  // N*64 ushort
  float* w_s = (float*)(x_bf + (size_t)N * 64);              // E
  float* w_r = w_s + E;                                      // E
  float* pu  = w_r + E;                                      // G*64
  float* pun = pu + (size_t)G * 64;                          // G*64
  int* lst_s = (int*)(pun + (size_t)G * 64);                 // N*64
  int* lst_r = lst_s + (size_t)N * 64;                       // N*64
  int* deg_s = lst_r + (size_t)N * 64;                       // N   (memset from here...)
  int* deg_r = deg_s + N;                                    // N
  float* nagg = (float*)(deg_r + N);                         // G*64
  float* eagg = nagg + (size_t)G * 64;                       // G*64 (...to here)
  float* gam_s = eagg + (size_t)G * 64;                      // N
  float* gam_r = gam_s + N;                                  // N
  float* Ms = gam_r + N;                                     // 64*128
  float* Mr = Ms + 64 * 128;                                 // 64*128
  float* cs = Mr + 64 * 128;                                 // 64
  float* cr = cs + 64;                                       // 64
  unsigned short* BpP = (unsigned short*)(cr + 64);          // 2048*8 ushort
  unsigned short* BpN = BpP + 2048 * 8;                      // 2560*8 ushort
  unsigned short* en_bf = BpN + 2560 * 8;                    // E*64 ushort

  hipMemsetAsync(deg_s, 0, (2 * (size_t)N + 2 * (size_t)G * 64) * sizeof(int), stream);

  const int gE = (E + 255) / 256;
  const int gT = (N / 16 + 3) / 4;   // MFMA node-tile blocks (4 waves x 16 nodes)

  k_fill<<<gE, 256, 0, stream>>>(row, col, deg_s, deg_r, lst_s, lst_r, E);
  k_precomb<<<10, 128, 0, stream>>>(Wn, W3, b3, We, u, Ms, cs, Mr, cr, pu, pun, G);
  k_pack<<<18, 256, 0, stream>>>(We, W1, Wn, Ms, Mr, BpP, BpN);
  k_nodepre4<<<gT, 256, 0, stream>>>(x, BpP, pxx, hqk, x_bf, N);
  k_edgeattn4<<<2048, 256, 0, stream>>>(ea, pxx, hqk, pu, We, be, W1, b1, w2,
                                        row, col, ebat, e_out, en_bf, w_s, w_r, E);
  k_segsum_bf<<<(E + 1023) / 1024, 256, 0, stream>>>(en_bf, ebat, eagg, E);
  // gathers overwrite pxx/hqk regions (dead after k_edgeattn4)
  k_gatherw<<<(N + 3) / 4, 256, 0, stream>>>(x_bf, en_bf, w_s, lst_s, deg_s, col, ss_s, gam_s, N);
  k_gatherw<<<(N + 3) / 4, 256, 0, stream>>>(x_bf, en_bf, w_r, lst_r, deg_r, row, ss_r, gam_r, N);
  k_node4<<<gT, 256, 0, stream>>>(x_bf, ss_s, ss_r, gam_s, gam_r, BpN, bn, cs, cr,
                                  pun, nbat, x_out, N);
  k_segsum<<<(N + 1023) / 1024, 256, 0, stream>>>(x_out, nbat, nagg, N);
  k_glob<<<(G * 64 + 63) / 64, 64, 0, stream>>>(u, nagg, eagg, Wg, bg, u_out, G);
}

// Round 10
// 456.649 us; speedup vs baseline: 13.1007x; 1.3004x over previous
//
#include <hip/hip_runtime.h>

typedef __attribute__((ext_vector_type(8))) short bf16x8;   // 8 bf16 = 4 VGPRs
typedef __attribute__((ext_vector_type(4))) float f32x4;

#define MFMA16(A, B, C) __builtin_amdgcn_mfma_f32_16x16x32_bf16(A, B, C, 0, 0, 0)

__device__ __forceinline__ float4 ld4(const float* p) {
  return *reinterpret_cast<const float4*>(p);
}

__device__ __forceinline__ unsigned short f2bf(float f) {
  unsigned u = __float_as_uint(f);
  unsigned r = u + 0x7FFFu + ((u >> 16) & 1u);   // RNE
  return (unsigned short)(r >> 16);
}

__device__ __forceinline__ float bf2f(unsigned short b) {
  return __uint_as_float(((unsigned)b) << 16);
}
__device__ __forceinline__ float bflo(unsigned u) { return __uint_as_float(u << 16); }
__device__ __forceinline__ float bfhi(unsigned u) { return __uint_as_float(u & 0xFFFF0000u); }
__device__ __forceinline__ unsigned bfpack(float lo, float hi) {
  return (unsigned)f2bf(lo) | ((unsigned)f2bf(hi) << 16);
}

__device__ __forceinline__ bf16x8 cvt8(float4 a, float4 b) {
  bf16x8 v;
  v[0] = (short)f2bf(a.x); v[1] = (short)f2bf(a.y);
  v[2] = (short)f2bf(a.z); v[3] = (short)f2bf(a.w);
  v[4] = (short)f2bf(b.x); v[5] = (short)f2bf(b.y);
  v[6] = (short)f2bf(b.z); v[7] = (short)f2bf(b.w);
  return v;
}

// ---- build padded CSR (both directions), MAXDEG=64 ----
__global__ void __launch_bounds__(256) k_fill(
    const int* __restrict__ row, const int* __restrict__ col,
    int* __restrict__ deg_s, int* __restrict__ deg_r,
    int* __restrict__ lst_s, int* __restrict__ lst_r, int E) {
  int e = blockIdx.x * 256 + threadIdx.x;
  if (e >= E) return;
  int r = row[e], c = col[e];
  int s0 = atomicAdd(deg_s + r, 1);
  if (s0 < 64) lst_s[(size_t)r * 64 + s0] = e;
  int s1 = atomicAdd(deg_r + c, 1);
  if (s1 < 64) lst_r[(size_t)c * 64 + s1] = e;
}

// ---- precombine: Ms=Wn[:,64:128].W3, cs=.b3; Mr/cr for 128:192; pu/pun ----
__global__ void __launch_bounds__(128) k_precomb(
    const float* __restrict__ Wn, const float* __restrict__ W3, const float* __restrict__ b3,
    const float* __restrict__ We, const float* __restrict__ u_,
    float* __restrict__ Ms, float* __restrict__ cs,
    float* __restrict__ Mr, float* __restrict__ cr,
    float* __restrict__ pu, float* __restrict__ pun, int G) {
  int t = threadIdx.x;
  if (blockIdx.x < 8) {
    int dir = t >> 6, o = t & 63;
    const float* wrow = Wn + (size_t)o * 256 + 64 + 64 * dir;
    float* M  = dir ? Mr : Ms;
    float* cv = dir ? cr : cs;
    if (blockIdx.x == 0) {
      float cb = 0.f;
      for (int k = 0; k < 64; ++k) cb = fmaf(wrow[k], b3[k], cb);
      cv[o] = cb;
    }
    int c0 = blockIdx.x * 16;
    for (int c = c0; c < c0 + 16; ++c) {
      float m = 0.f;
      for (int k = 0; k < 64; ++k) m = fmaf(wrow[k], W3[k * 128 + c], m);
      M[(size_t)o * 128 + c] = m;
    }
  } else {
    const float* W = (blockIdx.x == 8) ? We : Wn;
    float* dst = (blockIdx.x == 8) ? pu : pun;
    int o = t & 63;
    const float* wr = W + (size_t)o * 256 + 192;
    for (int g = t >> 6; g < G; g += 2) {
      float a = 0.f;
      const float* uv = u_ + (size_t)g * 64;
      for (int k = 0; k < 64; ++k) a = fmaf(wr[k], uv[k], a);
      dst[(size_t)g * 64 + o] = a;
    }
  }
}

// ---- pack B matrices to bf16 MFMA-frag layout (one-time) ----
__global__ void __launch_bounds__(256) k_pack(
    const float* __restrict__ We, const float* __restrict__ W1, const float* __restrict__ Wn,
    const float* __restrict__ Ms, const float* __restrict__ Mr,
    unsigned short* __restrict__ BpP, unsigned short* __restrict__ BpN) {
  int idx = blockIdx.x * 256 + threadIdx.x;
  if (idx < 2048) {
    int lane = idx & 63, nt = (idx >> 6) & 15, ks = idx >> 10;
    int l15 = lane & 15, lg = lane >> 4;
    int c = nt * 16 + l15, a = c >> 6, o = c & 63;
    bf16x8 v;
    #pragma unroll
    for (int j = 0; j < 8; ++j) {
      int k = ks * 32 + lg * 8 + j;
      float f = (a == 0) ? We[o * 256 + 64 + k]
              : (a == 1) ? We[o * 256 + 128 + k]
              : (a == 2) ? W1[o * 192 + k]
                         : W1[o * 192 + 64 + k];
      v[j] = (short)f2bf(f);
    }
    *(bf16x8*)(BpP + (size_t)idx * 8) = v;
  } else if (idx < 2048 + 2560) {
    int i2 = idx - 2048;
    int lane = i2 & 63, nt = (i2 >> 6) & 3, ks = i2 >> 8;
    int l15 = lane & 15, lg = lane >> 4;
    int col = nt * 16 + l15;
    bf16x8 v;
    #pragma unroll
    for (int j = 0; j < 8; ++j) {
      int k = ks * 32 + lg * 8 + j;
      float f = (k < 64) ? Wn[col * 256 + k]
              : (k < 192) ? Ms[col * 128 + (k - 64)]
                          : Mr[col * 128 + (k - 192)];
      v[j] = (short)f2bf(f);
    }
    *(bf16x8*)(BpN + (size_t)i2 * 8) = v;
  }
}

// ---- nodepre via MFMA; outputs PAIRED bf16 arrays pxx={px1,px2}, hqk={hq,hkv}
//      and x_bf (bf16 copy of x) ----
__global__ void __launch_bounds__(256) k_nodepre4(
    const float* __restrict__ x, const unsigned short* __restrict__ BpP,
    unsigned int* __restrict__ pxx, unsigned int* __restrict__ hqk,
    unsigned short* __restrict__ x_bf, int N) {
  __shared__ unsigned short lB[2048 * 8];   // 32KB
  const int tid = threadIdx.x;
  for (int i = tid; i < 2048; i += 256)
    *(uint4*)(lB + (size_t)i * 8) = *(const uint4*)(BpP + (size_t)i * 8);
  __syncthreads();
  const int lane = tid & 63, wid = tid >> 6, l15 = lane & 15, lg = lane >> 4;
  const int n0 = (blockIdx.x * 4 + wid) * 16;
  if (n0 >= N) return;
  int arow = n0 + l15; if (arow >= N) arow = N - 1;
  const float* src = x + (size_t)arow * 64 + lg * 8;
  bf16x8 A0 = cvt8(ld4(src), ld4(src + 4));
  bf16x8 A1 = cvt8(ld4(src + 32), ld4(src + 36));
  if (n0 + l15 < N) {
    *(bf16x8*)(x_bf + (size_t)(n0 + l15) * 64 + lg * 8) = A0;
    *(bf16x8*)(x_bf + (size_t)(n0 + l15) * 64 + 32 + lg * 8) = A1;
  }
  f32x4 acc[16];
  #pragma unroll
  for (int nt = 0; nt < 16; ++nt) {
    acc[nt] = (f32x4){0.f, 0.f, 0.f, 0.f};
    acc[nt] = MFMA16(A0, *(const bf16x8*)(lB + ((size_t)(0 * 16 + nt) * 64 + lane) * 8), acc[nt]);
    acc[nt] = MFMA16(A1, *(const bf16x8*)(lB + ((size_t)(1 * 16 + nt) * 64 + lane) * 8), acc[nt]);
  }
  // nt = a*4+q, a: 0=px1 1=px2 2=hq 3=hkv ; o = q*16+l15
  #pragma unroll
  for (int q = 0; q < 4; ++q) {
    const int o = q * 16 + l15;
    #pragma unroll
    for (int j = 0; j < 4; ++j) {
      int n = n0 + lg * 4 + j;
      if (n < N) {
        pxx[(size_t)n * 64 + o] = bfpack(acc[q][j],     acc[4 + q][j]);
        hqk[(size_t)n * 64 + o] = bfpack(acc[8 + q][j], acc[12 + q][j]);
      }
    }
  }
}

// ---- MFMA fused edge MLP + attention logits: wave = 16 edges; paired bf16 gathers ----
__global__ void __launch_bounds__(256, 2) k_edgeattn4(
    const float* __restrict__ ea,
    const unsigned int* __restrict__ pxx, const unsigned int* __restrict__ hqk,
    const float* __restrict__ pu,
    const float* __restrict__ We, const float* __restrict__ be,
    const float* __restrict__ W1, const float* __restrict__ b1, const float* __restrict__ w2,
    const int* __restrict__ row, const int* __restrict__ col, const int* __restrict__ ebat,
    float* __restrict__ edge_out, unsigned short* __restrict__ en_bf,
    float* __restrict__ w_s, float* __restrict__ w_r, int E) {
  __shared__ unsigned short enl_all[4][16 * 64];  // per-wave 2KB bf16 tile, swizzled
  const int tid = threadIdx.x, lane = tid & 63, wid = tid >> 6;
  const int l15 = lane & 15, lg = lane >> 4;

  bf16x8 B1[4][2], B2[4][2];
  #pragma unroll
  for (int nt = 0; nt < 4; ++nt) {
    #pragma unroll
    for (int ks = 0; ks < 2; ++ks) {
      const float* s1 = We + (size_t)(nt * 16 + l15) * 256 + ks * 32 + lg * 8;
      B1[nt][ks] = cvt8(ld4(s1), ld4(s1 + 4));
      const float* s2 = W1 + (size_t)(nt * 16 + l15) * 192 + 128 + ks * 32 + lg * 8;
      B2[nt][ks] = cvt8(ld4(s2), ld4(s2 + 4));
    }
  }
  float be_l[4], b1_l[4], w2_l[4];
  #pragma unroll
  for (int nt = 0; nt < 4; ++nt) {
    be_l[nt] = be[nt * 16 + l15];
    b1_l[nt] = b1[nt * 16 + l15];
    w2_l[nt] = w2[nt * 16 + l15];
  }
  unsigned short* enl = enl_all[wid];
  const int nwaves = gridDim.x * 4;
  const int swz_r = (l15 & 7) << 4;

  for (int e0 = (blockIdx.x * 4 + wid) * 16; e0 < E; e0 += nwaves * 16) {
    // ---- indices ----
    int rj[4], cj[4], gj[4];
    if (e0 + 16 <= E) {
      int4 r4 = *(const int4*)(row + e0 + lg * 4);
      int4 c4 = *(const int4*)(col + e0 + lg * 4);
      int4 g4 = *(const int4*)(ebat + e0 + lg * 4);
      rj[0]=r4.x; rj[1]=r4.y; rj[2]=r4.z; rj[3]=r4.w;
      cj[0]=c4.x; cj[1]=c4.y; cj[2]=c4.z; cj[3]=c4.w;
      gj[0]=g4.x; gj[1]=g4.y; gj[2]=g4.z; gj[3]=g4.w;
    } else {
      #pragma unroll
      for (int j = 0; j < 4; ++j) {
        int ee = e0 + lg * 4 + j; if (ee >= E) ee = E - 1;
        rj[j] = row[ee]; cj[j] = col[ee]; gj[j] = ebat[ee];
      }
    }

    // ---- ALL gathers issued before GEMM1 (paired bf16) ----
    unsigned hr_[4][4], hc_[4][4], pr_[4][4], pc_[4][4];
    float puv[4][4];
    #pragma unroll
    for (int j = 0; j < 4; ++j) {
      #pragma unroll
      for (int nt = 0; nt < 4; ++nt) {
        const int o = nt * 16 + l15;
        hr_[j][nt] = hqk[(size_t)rj[j] * 64 + o];
        hc_[j][nt] = hqk[(size_t)cj[j] * 64 + o];
        pr_[j][nt] = pxx[(size_t)rj[j] * 64 + o];
        pc_[j][nt] = pxx[(size_t)cj[j] * 64 + o];
        puv[j][nt] = pu [(size_t)gj[j] * 64 + o];
      }
    }

    // ---- A1-frags from ea ----
    int erow = e0 + l15; if (erow >= E) erow = E - 1;
    const float* arow = ea + (size_t)erow * 64;
    bf16x8 A1[2];
    #pragma unroll
    for (int ks = 0; ks < 2; ++ks) {
      const float* s = arow + ks * 32 + lg * 8;
      A1[ks] = cvt8(ld4(s), ld4(s + 4));
    }

    // ---- GEMM1 ----
    f32x4 acc[4];
    #pragma unroll
    for (int nt = 0; nt < 4; ++nt) acc[nt] = (f32x4){0.f, 0.f, 0.f, 0.f};
    #pragma unroll
    for (int nt = 0; nt < 4; ++nt) {
      acc[nt] = MFMA16(A1[0], B1[nt][0], acc[nt]);
      acc[nt] = MFMA16(A1[1], B1[nt][1], acc[nt]);
    }

    // ---- epilogue1: +bias +px1[r]+px2[c]+pu[g], relu, store f32+bf16, LDS pack ----
    #pragma unroll
    for (int j = 0; j < 4; ++j) {
      const int m = lg * 4 + j;
      const bool st = (e0 + m) < E;
      float* eo = edge_out + (size_t)(e0 + m) * 64 + l15;
      unsigned short* eb = en_bf + (size_t)(e0 + m) * 64 + l15;
      const int rbase = m * 128, sw = (m & 7) << 4;
      #pragma unroll
      for (int nt = 0; nt < 4; ++nt) {
        float v = acc[nt][j] + be_l[nt] + bflo(pr_[j][nt]) + bfhi(pc_[j][nt]) + puv[j][nt];
        v = fmaxf(v, 0.f);
        unsigned short bv = f2bf(v);
        if (st) { eo[nt * 16] = v; eb[nt * 16] = bv; }
        int byte = rbase + ((nt * 32 + l15 * 2) ^ sw);
        *(unsigned short*)((char*)enl + byte) = bv;
      }
    }

    // ---- A2-frags from LDS (swizzled read) ----
    asm volatile("s_waitcnt lgkmcnt(0)" ::: "memory");
    bf16x8 A2[2];
    #pragma unroll
    for (int ks = 0; ks < 2; ++ks) {
      int byte = l15 * 128 + (((ks * 64) + lg * 16) ^ swz_r);
      A2[ks] = *(const bf16x8*)((const char*)enl + byte);
    }

    // ---- GEMM2 ----
    f32x4 tac[4];
    #pragma unroll
    for (int nt = 0; nt < 4; ++nt) tac[nt] = (f32x4){0.f, 0.f, 0.f, 0.f};
    #pragma unroll
    for (int nt = 0; nt < 4; ++nt) {
      tac[nt] = MFMA16(A2[0], B2[nt][0], tac[nt]);
      tac[nt] = MFMA16(A2[1], B2[nt][1], tac[nt]);
    }

    // ---- epilogue2: logits from paired hqk ----
    float as4[4] = {0.f, 0.f, 0.f, 0.f}, ar4[4] = {0.f, 0.f, 0.f, 0.f};
    #pragma unroll
    for (int j = 0; j < 4; ++j) {
      #pragma unroll
      for (int nt = 0; nt < 4; ++nt) {
        float tt = tac[nt][j] + b1_l[nt];
        float hs = tt + bflo(hr_[j][nt]) + bfhi(hc_[j][nt]); hs = (hs >= 0.f) ? hs : 0.01f * hs;
        float hr2 = tt + bflo(hc_[j][nt]) + bfhi(hr_[j][nt]); hr2 = (hr2 >= 0.f) ? hr2 : 0.01f * hr2;
        as4[j] = fmaf(hs, w2_l[nt], as4[j]);
        ar4[j] = fmaf(hr2, w2_l[nt], ar4[j]);
      }
    }
    #pragma unroll
    for (int j = 0; j < 4; ++j) {
      #pragma unroll
      for (int d = 1; d < 16; d <<= 1) {
        as4[j] += __shfl_xor(as4[j], d, 64);
        ar4[j] += __shfl_xor(ar4[j], d, 64);
      }
    }
    if (l15 == 0) {
      #pragma unroll
      for (int j = 0; j < 4; ++j) {
        int e = e0 + lg * 4 + j;
        if (e < E) { w_s[e] = as4[j]; w_r[e] = ar4[j]; }
      }
    }
  }
}

// ---- wave-per-node gather, BOTH directions via blockIdx.y; 8-deep pipeline ----
__global__ void __launch_bounds__(256) k_gatherw2(
    const unsigned short* __restrict__ x_bf, const unsigned short* __restrict__ en_bf,
    const float* __restrict__ w_s, const float* __restrict__ w_r,
    const int* __restrict__ lst_s, const int* __restrict__ lst_r,
    const int* __restrict__ deg_s, const int* __restrict__ deg_r,
    const int* __restrict__ row, const int* __restrict__ col,
    unsigned short* __restrict__ ss_s, unsigned short* __restrict__ ss_r,
    float* __restrict__ gam_s, float* __restrict__ gam_r, int N) {
  const int dir = blockIdx.y;
  const float* w = dir ? w_r : w_s;
  const int* lst = dir ? lst_r : lst_s;
  const int* deg_a = dir ? deg_r : deg_s;
  const int* other_idx = dir ? row : col;
  unsigned short* ss = dir ? ss_r : ss_s;
  float* gam = dir ? gam_r : gam_s;

  int wid = threadIdx.x >> 6, lane = threadIdx.x & 63;
  int n = blockIdx.x * 4 + wid;
  if (n >= N) return;
  int deg = deg_a[n];
  deg = deg < 64 ? deg : 64;
  unsigned short* ssd = ss + (size_t)n * 128;
  if (deg == 0) {
    ssd[lane] = 0; ssd[64 + lane] = 0;
    if (lane == 0) gam[n] = 0.f;
    return;
  }
  int e = 0, oe = 0;
  float wv = -1e30f;
  if (lane < deg) {
    e = lst[(size_t)n * 64 + lane];
    oe = other_idx[e];
    wv = w[e];
  }
  float m = wv;
  #pragma unroll
  for (int d = 32; d; d >>= 1) m = fmaxf(m, __shfl_xor(m, d, 64));
  float p = (lane < deg) ? __expf(wv - m) : 0.f;
  float S = p;
  #pragma unroll
  for (int d = 32; d; d >>= 1) S += __shfl_xor(S, d, 64);
  float sx4[4] = {0.f, 0.f, 0.f, 0.f};
  float se4[4] = {0.f, 0.f, 0.f, 0.f};
  int i = 0;
  for (; i + 8 <= deg; i += 8) {
    float pp[8]; int oo[8], ee[8];
    #pragma unroll
    for (int k = 0; k < 8; ++k) {
      pp[k] = __shfl(p, i + k, 64);
      oo[k] = __shfl(oe, i + k, 64);
      ee[k] = __shfl(e, i + k, 64);
    }
    float xv[8], ev[8];
    #pragma unroll
    for (int k = 0; k < 8; ++k) {
      xv[k] = bf2f(x_bf[(size_t)oo[k] * 64 + lane]);
      ev[k] = bf2f(en_bf[(size_t)ee[k] * 64 + lane]);
    }
    #pragma unroll
    for (int k = 0; k < 8; ++k) {
      sx4[k & 3] = fmaf(pp[k], xv[k], sx4[k & 3]);
      se4[k & 3] = fmaf(pp[k], ev[k], se4[k & 3]);
    }
  }
  for (; i + 4 <= deg; i += 4) {
    float pp[4]; int oo[4], ee[4];
    #pragma unroll
    for (int k = 0; k < 4; ++k) {
      pp[k] = __shfl(p, i + k, 64);
      oo[k] = __shfl(oe, i + k, 64);
      ee[k] = __shfl(e, i + k, 64);
    }
    #pragma unroll
    for (int k = 0; k < 4; ++k) {
      sx4[k] = fmaf(pp[k], bf2f(x_bf[(size_t)oo[k] * 64 + lane]), sx4[k]);
      se4[k] = fmaf(pp[k], bf2f(en_bf[(size_t)ee[k] * 64 + lane]), se4[k]);
    }
  }
  for (; i < deg; ++i) {
    float pi = __shfl(p, i, 64);
    int ei = __shfl(e, i, 64);
    int oi = __shfl(oe, i, 64);
    sx4[0] = fmaf(pi, bf2f(x_bf[(size_t)oi * 64 + lane]), sx4[0]);
    se4[0] = fmaf(pi, bf2f(en_bf[(size_t)ei * 64 + lane]), se4[0]);
  }
  float sx = (sx4[0] + sx4[1]) + (sx4[2] + sx4[3]);
  float se = (se4[0] + se4[1]) + (se4[2] + se4[3]);
  float inv = 1.f / (S + 1e-16f);
  ssd[lane] = f2bf(sx * inv);
  ssd[64 + lane] = f2bf(se * inv);
  if (lane == 0) gam[n] = S * inv;
}

// ---- node MLP via MFMA: A-rows read directly as bf16 (x_bf | ss_s | ss_r) ----
__global__ void __launch_bounds__(256) k_node4(
    const unsigned short* __restrict__ x_bf,
    const unsigned short* __restrict__ ss_s, const unsigned short* __restrict__ ss_r,
    const float* __restrict__ gam_s, const float* __restrict__ gam_r,
    const unsigned short* __restrict__ BpN,
    const float* __restrict__ bn, const float* __restrict__ cs, const float* __restrict__ cr,
    const float* __restrict__ pun, const int* __restrict__ nbat,
    float* __restrict__ x_out, int N) {
  __shared__ unsigned short lB[2560 * 8];   // 40KB
  const int tid = threadIdx.x;
  for (int i = tid; i < 2560; i += 256)
    *(uint4*)(lB + (size_t)i * 8) = *(const uint4*)(BpN + (size_t)i * 8);
  __syncthreads();
  const int lane = tid & 63, wid = tid >> 6, l15 = lane & 15, lg = lane >> 4;
  const int n0 = (blockIdx.x * 4 + wid) * 16;
  if (n0 >= N) return;
  int arow = n0 + l15; if (arow >= N) arow = N - 1;

  f32x4 acc[4];
  #pragma unroll
  for (int nt = 0; nt < 4; ++nt) acc[nt] = (f32x4){0.f, 0.f, 0.f, 0.f};

  #pragma unroll
  for (int ks = 0; ks < 10; ++ks) {
    const unsigned short* s;
    if (ks < 2)      s = x_bf + (size_t)arow * 64  + ks * 32 + lg * 8;
    else if (ks < 6) s = ss_s + (size_t)arow * 128 + (ks - 2) * 32 + lg * 8;
    else             s = ss_r + (size_t)arow * 128 + (ks - 6) * 32 + lg * 8;
    bf16x8 A = *(const bf16x8*)s;
    #pragma unroll
    for (int nt = 0; nt < 4; ++nt)
      acc[nt] = MFMA16(A, *(const bf16x8*)(lB + ((size_t)(ks * 4 + nt) * 64 + lane) * 8), acc[nt]);
  }

  #pragma unroll
  for (int j = 0; j < 4; ++j) {
    int n = n0 + lg * 4 + j;
    int nn = n < N ? n : N - 1;
    int g = nbat[nn];
    float gs = gam_s[nn], gr = gam_r[nn];
    #pragma unroll
    for (int nt = 0; nt < 4; ++nt) {
      int o = nt * 16 + l15;
      float v = acc[nt][j] + bn[o] + pun[(size_t)g * 64 + o] + gs * cs[o] + gr * cr[o];
      v = fmaxf(v, 0.f);
      if (n < N) x_out[(size_t)n * 64 + o] = v;
    }
  }
}

// ---- segment-sum f32 (sorted ids, run-length + atomic flush), CHUNK=64 ----
__global__ void __launch_bounds__(256) k_segsum(
    const float* __restrict__ vals, const int* __restrict__ seg,
    float* __restrict__ out, int n) {
  int d = threadIdx.x & 63;
  int grp = threadIdx.x >> 6;
  long base = (long)blockIdx.x * 256 + (long)grp * 64;
  float sum = 0.f;
  int cur = -1;
  for (int k = 0; k < 64; ++k) {
    long e = base + k;
    if (e >= n) break;
    int gb = seg[e];
    float v = vals[e * 64 + d];
    if (gb != cur) {
      if (cur >= 0) atomicAdd(out + (size_t)cur * 64 + d, sum);
      cur = gb; sum = v;
    } else {
      sum += v;
    }
  }
  if (cur >= 0) atomicAdd(out + (size_t)cur * 64 + d, sum);
}

// ---- segment-sum bf16 input, CHUNK=64 ----
__global__ void __launch_bounds__(256) k_segsum_bf(
    const unsigned short* __restrict__ vals, const int* __restrict__ seg,
    float* __restrict__ out, int n) {
  int d = threadIdx.x & 63;
  int grp = threadIdx.x >> 6;
  long base = (long)blockIdx.x * 256 + (long)grp * 64;
  float sum = 0.f;
  int cur = -1;
  for (int k = 0; k < 64; ++k) {
    long e = base + k;
    if (e >= n) break;
    int gb = seg[e];
    float v = bf2f(vals[e * 64 + d]);
    if (gb != cur) {
      if (cur >= 0) atomicAdd(out + (size_t)cur * 64 + d, sum);
      cur = gb; sum = v;
    } else {
      sum += v;
    }
  }
  if (cur >= 0) atomicAdd(out + (size_t)cur * 64 + d, sum);
}

// ---- global MLP ----
__global__ void __launch_bounds__(64) k_glob(
    const float* __restrict__ u, const float* __restrict__ nagg, const float* __restrict__ eagg,
    const float* __restrict__ Wg, const float* __restrict__ bg,
    float* __restrict__ u_out, int G) {
  int t = blockIdx.x * 64 + threadIdx.x;
  if (t >= G * 64) return;
  int g = t >> 6, o = t & 63;
  float acc = bg[o];
  const float* wr = Wg + (size_t)o * 192;
  for (int i = 0; i < 64; ++i) acc = fmaf(u[g * 64 + i],    wr[i],       acc);
  for (int i = 0; i < 64; ++i) acc = fmaf(nagg[g * 64 + i], wr[64 + i],  acc);
  for (int i = 0; i < 64; ++i) acc = fmaf(eagg[g * 64 + i], wr[128 + i], acc);
  u_out[t] = fmaxf(acc, 0.f);
}

extern "C" void kernel_launch(void* const* d_in, const int* in_sizes, int n_in,
                              void* d_out, int out_size, void* d_ws, size_t ws_size,
                              hipStream_t stream) {
  const float* x   = (const float*)d_in[0];
  const float* ea  = (const float*)d_in[1];
  const float* u   = (const float*)d_in[2];
  const float* We  = (const float*)d_in[3];
  const float* be  = (const float*)d_in[4];
  const float* Wn  = (const float*)d_in[5];
  const float* bn  = (const float*)d_in[6];
  const float* Wg  = (const float*)d_in[7];
  const float* bg  = (const float*)d_in[8];
  const float* W1  = (const float*)d_in[9];
  const float* b1  = (const float*)d_in[10];
  const float* w2  = (const float*)d_in[11];
  const float* W3  = (const float*)d_in[12];
  const float* b3  = (const float*)d_in[13];
  const int* eidx  = (const int*)d_in[14];
  const int* nbat  = (const int*)d_in[15];
  const int* ebat  = (const int*)d_in[16];

  const int N = in_sizes[0] / 64;
  const int E = in_sizes[1] / 64;
  const int G = in_sizes[2] / 64;
  const int* row = eidx;
  const int* col = eidx + E;

  float* out   = (float*)d_out;
  float* x_out = out;
  float* e_out = out + (size_t)N * 64;
  float* u_out = out + (size_t)(N + E) * 64;

  // ---- workspace layout (float units) ----
  float* ws = (float*)d_ws;
  unsigned int* pxx = (unsigned int*)ws;                     // N*64 uint
  unsigned int* hqk = pxx + (size_t)N * 64;                  // N*64 uint
  // after k_edgeattn4, pxx/hqk regions are dead -> reuse for bf16 ss (same byte size)
  unsigned short* ss_s = (unsigned short*)pxx;               // N*128 ushort
  unsigned short* ss_r = (unsigned short*)hqk;               // N*128 ushort
  unsigned short* x_bf = (unsigned short*)(hqk + (size_t)N * 64);  // N*64 ushort
  float* w_s = (float*)(x_bf + (size_t)N * 64);              // E
  float* w_r = w_s + E;                                      // E
  float* pu  = w_r + E;                                      // G*64
  float* pun = pu + (size_t)G * 64;                          // G*64
  int* lst_s = (int*)(pun + (size_t)G * 64);                 // N*64
  int* lst_r = lst_s + (size_t)N * 64;                       // N*64
  int* deg_s = lst_r + (size_t)N * 64;                       // N   (memset from here...)
  int* deg_r = deg_s + N;                                    // N
  float* nagg = (float*)(deg_r + N);                         // G*64
  float* eagg = nagg + (size_t)G * 64;                       // G*64 (...to here)
  float* gam_s = eagg + (size_t)G * 64;                      // N
  float* gam_r = gam_s + N;                                  // N
  float* Ms = gam_r + N;                                     // 64*128
  float* Mr = Ms + 64 * 128;                                 // 64*128
  float* cs = Mr + 64 * 128;                                 // 64
  float* cr = cs + 64;                                       // 64
  unsigned short* BpP = (unsigned short*)(cr + 64);          // 2048*8 ushort
  unsigned short* BpN = BpP + 2048 * 8;                      // 2560*8 ushort
  unsigned short* en_bf = BpN + 2560 * 8;                    // E*64 ushort

  hipMemsetAsync(deg_s, 0, (2 * (size_t)N + 2 * (size_t)G * 64) * sizeof(int), stream);

  const int gE = (E + 255) / 256;
  const int gT = (N / 16 + 3) / 4;   // MFMA node-tile blocks (4 waves x 16 nodes)

  k_fill<<<gE, 256, 0, stream>>>(row, col, deg_s, deg_r, lst_s, lst_r, E);
  k_precomb<<<10, 128, 0, stream>>>(Wn, W3, b3, We, u, Ms, cs, Mr, cr, pu, pun, G);
  k_pack<<<18, 256, 0, stream>>>(We, W1, Wn, Ms, Mr, BpP, BpN);
  k_nodepre4<<<gT, 256, 0, stream>>>(x, BpP, pxx, hqk, x_bf, N);
  k_edgeattn4<<<2048, 256, 0, stream>>>(ea, pxx, hqk, pu, We, be, W1, b1, w2,
                                        row, col, ebat, e_out, en_bf, w_s, w_r, E);
  k_segsum_bf<<<(E + 255) / 256, 256, 0, stream>>>(en_bf, ebat, eagg, E);
  // gathers overwrite pxx/hqk regions (dead after k_edgeattn4)
  k_gatherw2<<<dim3((N + 3) / 4, 2), 256, 0, stream>>>(
      x_bf, en_bf, w_s, w_r, lst_s, lst_r, deg_s, deg_r, row, col,
      ss_s, ss_r, gam_s, gam_r, N);
  k_node4<<<gT, 256, 0, stream>>>(x_bf, ss_s, ss_r, gam_s, gam_r, BpN, bn, cs, cr,
                                  pun, nbat, x_out, N);
  k_segsum<<<(N + 255) / 256, 256, 0, stream>>>(x_out, nbat, nagg, N);
  k_glob<<<(G * 64 + 63) / 64, 64, 0, stream>>>(u, nagg, eagg, Wg, bg, u_out, G);
}